// Round 1
// baseline (2316.799 us; speedup 1.0000x reference)
//
#include <hip/hip_runtime.h>
#include <math.h>

#define NPTS 16384
#define PPB  2048
#define KNN  20

// ---------------- workspace layout (bytes), total 64 MB ----------------
#define OFF_X0P   0u           // 16384*16*4   = 1,048,576  (pos zero-padded to 16 cols)
#define OFF_N2    1048576u     // 16384*4      = 65,536     (sq norms, reused per stage)
#define OFF_IDX   1114112u     // 16384*20*4   = 1,310,720  (knn indices, reused)
#define OFF_WUV1  2424832u     // 16*128*4
#define OFF_WUV2  2433024u     // 64*256*4
#define OFF_WUV3  2498560u     // 128*512*4
#define OFF_POOL  2760704u     // 8192*4 (ordered-uint max pool)
#define OFF_C1    2793472u     // 8*512*4
#define OFF_C2    2809856u     // 8*256*4
#define OFF_X1    4194304u     // 16384*64*4   = 4 MB
#define OFF_X2    8388608u     // 16384*128*4  = 8 MB
#define OFF_X3    16777216u    // 16384*256*4  = 16 MB
#define OFF_UV    33554432u    // 16384*512*4  = 32 MB (per-stage U|V, stride 2*out)

// order-preserving float<->uint for atomicMax-based pooling
__device__ __forceinline__ unsigned f2o(float f) {
    unsigned u = __float_as_uint(f);
    return (u & 0x80000000u) ? ~u : (u | 0x80000000u);
}
__device__ __forceinline__ float o2f(unsigned u) {
    return (u & 0x80000000u) ? __uint_as_float(u & 0x7fffffffu) : __uint_as_float(~u);
}

// ---------------- prep kernels ----------------
__global__ void build_x0p_kernel(const float* __restrict__ pos, float* __restrict__ x0p) {
    int e = blockIdx.x * 256 + threadIdx.x;           // < 16384*16
    int p = e >> 4, k = e & 15;
    x0p[e] = (k < 3) ? pos[p * 3 + k] : 0.f;
}

// W [2d][od] -> Wuv [dpad][2*od]:  cols [0,od): W_top - W_bot (U),  cols [od,2od): W_bot (V)
__global__ void wuv_build_kernel(const float* __restrict__ W, float* __restrict__ Wuv,
                                 int d, int dpad, int od) {
    int tot = dpad * 2 * od;
    for (int e = blockIdx.x * 256 + threadIdx.x; e < tot; e += gridDim.x * 256) {
        int r = e / (2 * od), c = e - r * (2 * od);
        float v = 0.f;
        if (r < d) v = (c < od) ? (W[r * od + c] - W[(d + r) * od + c])
                                : W[(d + r) * od + (c - od)];
        Wuv[e] = v;
    }
}

__global__ void init_pool_kernel(unsigned* __restrict__ pool) {
    pool[blockIdx.x * 256 + threadIdx.x] = 0u;        // below f2o(-inf)=0x007FFFFF
}

template<int D>
__global__ void sqnorm_kernel(const float* __restrict__ X, float* __restrict__ n2) {
    int p = blockIdx.x * 256 + threadIdx.x;
    float s = 0.f;
    #pragma unroll
    for (int k = 0; k < D; k += 4) {
        float4 v = *(const float4*)&X[(size_t)p * D + k];
        s += v.x * v.x + v.y * v.y + v.z * v.z + v.w * v.w;
    }
    n2[p] = s;
}

// ---------------- kNN: fused distance-GEMM + top-20 selection ----------------
// dist ordering uses n2[q] - 2*dot  (row-constant n2[p] dropped -> same top-k set)
__device__ __forceinline__ void topk_insert(float (&bd)[KNN], int (&bi)[KNN],
                                            float& worst, int& wslot, float v, int q) {
    #pragma unroll
    for (int s = 0; s < KNN; ++s) if (s == wslot) { bd[s] = v; bi[s] = q; }
    float w = bd[0]; int sl = 0;
    #pragma unroll
    for (int s = 1; s < KNN; ++s) if (bd[s] > w) { w = bd[s]; sl = s; }
    worst = w; wslot = sl;
}

template<int D, int DK>
__global__ __launch_bounds__(256)
void knn_kernel(const float* __restrict__ X, const float* __restrict__ n2,
                int* __restrict__ idxout) {
    __shared__ float As[D][32];       // row tile, k-major
    __shared__ float Bs[DK][128];     // candidate k-chunk, k-major
    __shared__ float n2s[128];
    __shared__ float Ds[32][129];     // distance tile (+1 pad)

    const int t = threadIdx.x;
    const int pbase = blockIdx.x * 32;
    const int qbase = (pbase / PPB) * PPB;            // batch-local candidates
    const int tx = t & 15, ty = t >> 4;
    const bool ins = (t & 7) == 0;                    // 32 insertion threads, 8/wave
    const int irow = t >> 3;

    { // stage A tile once (32 rows x D), transpose into As[k][r]
        const int nf4 = D / 4;
        for (int e = t; e < 32 * nf4; e += 256) {
            int r = e / nf4, k4 = e - r * nf4;
            float4 v = *(const float4*)&X[(size_t)(pbase + r) * D + 4 * k4];
            As[4 * k4 + 0][r] = v.x; As[4 * k4 + 1][r] = v.y;
            As[4 * k4 + 2][r] = v.z; As[4 * k4 + 3][r] = v.w;
        }
    }

    float bd[KNN]; int bi[KNN];
    #pragma unroll
    for (int s = 0; s < KNN; ++s) { bd[s] = 3.4e38f; bi[s] = 0; }
    float worst = 3.4e38f; int wslot = 0;

    for (int qt = 0; qt < PPB / 128; ++qt) {
        const int qb = qbase + qt * 128;
        float acc[2][8];
        #pragma unroll
        for (int i = 0; i < 2; ++i)
            #pragma unroll
            for (int j = 0; j < 8; ++j) acc[i][j] = 0.f;

        if (t < 128) n2s[t] = n2[qb + t];

        for (int kc = 0; kc < D / DK; ++kc) {
            __syncthreads();                          // Bs/Ds consumers done
            const int nf4 = DK / 4;
            for (int e = t; e < 128 * nf4; e += 256) {
                int q = e / nf4, k4 = e - q * nf4;
                float4 v = *(const float4*)&X[(size_t)(qb + q) * D + kc * DK + 4 * k4];
                Bs[4 * k4 + 0][q] = v.x; Bs[4 * k4 + 1][q] = v.y;
                Bs[4 * k4 + 2][q] = v.z; Bs[4 * k4 + 3][q] = v.w;
            }
            __syncthreads();
            #pragma unroll
            for (int kk = 0; kk < DK; ++kk) {
                float2 a = *(const float2*)&As[kc * DK + kk][2 * ty];
                float4 b0 = *(const float4*)&Bs[kk][8 * tx];
                float4 b1 = *(const float4*)&Bs[kk][8 * tx + 4];
                float av[2] = {a.x, a.y};
                float bv[8] = {b0.x, b0.y, b0.z, b0.w, b1.x, b1.y, b1.z, b1.w};
                #pragma unroll
                for (int i = 0; i < 2; ++i)
                    #pragma unroll
                    for (int j = 0; j < 8; ++j) acc[i][j] += av[i] * bv[j];
            }
        }
        __syncthreads();
        #pragma unroll
        for (int i = 0; i < 2; ++i) {
            int r = 2 * ty + i;
            #pragma unroll
            for (int j = 0; j < 8; ++j)
                Ds[r][8 * tx + j] = n2s[8 * tx + j] - 2.f * acc[i][j];
        }
        __syncthreads();
        if (ins) {
            #pragma unroll 4
            for (int j = 0; j < 128; ++j) {
                float v = Ds[irow][j];
                if (v < worst) topk_insert(bd, bi, worst, wslot, v, qb + j);
            }
        }
        // next iteration's first __syncthreads() protects Ds/Bs reuse
    }
    if (ins) {
        #pragma unroll
        for (int s = 0; s < KNN; ++s)
            idxout[(size_t)(pbase + irow) * KNN + s] = bi[s];
    }
}

// ---------------- fp32 tiled GEMM 128x128, 8x8 micro-tile ----------------
__global__ __launch_bounds__(256)
void gemm_uv_kernel(const float* __restrict__ A, const float* __restrict__ B,
                    float* __restrict__ C, int M, int N, int K) {
    __shared__ float As[16][128];
    __shared__ float Bs[16][128];
    const int t = threadIdx.x;
    const int tx = t & 15, ty = t >> 4;
    const int nb = blockIdx.x * 128;
    const int mb = blockIdx.y * 128;
    float acc[8][8];
    #pragma unroll
    for (int i = 0; i < 8; ++i)
        #pragma unroll
        for (int j = 0; j < 8; ++j) acc[i][j] = 0.f;

    for (int kc = 0; kc < K; kc += 16) {
        __syncthreads();
        for (int e = t; e < 512; e += 256) {          // A: 128 rows x 16 k -> As[k][m]
            int m = e >> 2, kq = e & 3;
            float4 v = *(const float4*)&A[(size_t)(mb + m) * K + kc + 4 * kq];
            As[4 * kq + 0][m] = v.x; As[4 * kq + 1][m] = v.y;
            As[4 * kq + 2][m] = v.z; As[4 * kq + 3][m] = v.w;
        }
        for (int e = t; e < 512; e += 256) {          // B: 16 k x 128 n
            int kr = e >> 5, nq = e & 31;
            *(float4*)&Bs[kr][4 * nq] = *(const float4*)&B[(size_t)(kc + kr) * N + nb + 4 * nq];
        }
        __syncthreads();
        #pragma unroll
        for (int kk = 0; kk < 16; ++kk) {
            float4 a0 = *(const float4*)&As[kk][8 * ty];
            float4 a1 = *(const float4*)&As[kk][8 * ty + 4];
            float4 b0 = *(const float4*)&Bs[kk][8 * tx];
            float4 b1 = *(const float4*)&Bs[kk][8 * tx + 4];
            float av[8] = {a0.x, a0.y, a0.z, a0.w, a1.x, a1.y, a1.z, a1.w};
            float bv[8] = {b0.x, b0.y, b0.z, b0.w, b1.x, b1.y, b1.z, b1.w};
            #pragma unroll
            for (int i = 0; i < 8; ++i)
                #pragma unroll
                for (int j = 0; j < 8; ++j) acc[i][j] += av[i] * bv[j];
        }
    }
    #pragma unroll
    for (int i = 0; i < 8; ++i) {
        float4 v0 = {acc[i][0], acc[i][1], acc[i][2], acc[i][3]};
        float4 v1 = {acc[i][4], acc[i][5], acc[i][6], acc[i][7]};
        *(float4*)&C[(size_t)(mb + 8 * ty + i) * N + nb + 8 * tx] = v0;
        *(float4*)&C[(size_t)(mb + 8 * ty + i) * N + nb + 8 * tx + 4] = v1;
    }
}

// fc1 GEMM: A = concat(x1,x2,x3) on the fly, fused per-batch max-pool epilogue
__global__ __launch_bounds__(256)
void gemm_fc1_kernel(const float* __restrict__ x1, const float* __restrict__ x2,
                     const float* __restrict__ x3, const float* __restrict__ B,
                     const float* __restrict__ bias, unsigned* __restrict__ pool) {
    const int N = 1024, K = 448;
    __shared__ float As[16][128];
    __shared__ float Bs[16][128];
    const int t = threadIdx.x;
    const int tx = t & 15, ty = t >> 4;
    const int nb = blockIdx.x * 128;
    const int mb = blockIdx.y * 128;
    float acc[8][8];
    #pragma unroll
    for (int i = 0; i < 8; ++i)
        #pragma unroll
        for (int j = 0; j < 8; ++j) acc[i][j] = 0.f;

    for (int kc = 0; kc < K; kc += 16) {
        __syncthreads();
        for (int e = t; e < 512; e += 256) {
            int m = e >> 2, kq = e & 3;
            int k = kc + 4 * kq;
            int row = mb + m;
            float4 v;
            if (k < 64)       v = *(const float4*)&x1[(size_t)row * 64 + k];
            else if (k < 192) v = *(const float4*)&x2[(size_t)row * 128 + (k - 64)];
            else              v = *(const float4*)&x3[(size_t)row * 256 + (k - 192)];
            As[4 * kq + 0][m] = v.x; As[4 * kq + 1][m] = v.y;
            As[4 * kq + 2][m] = v.z; As[4 * kq + 3][m] = v.w;
        }
        for (int e = t; e < 512; e += 256) {
            int kr = e >> 5, nq = e & 31;
            *(float4*)&Bs[kr][4 * nq] = *(const float4*)&B[(size_t)(kc + kr) * N + nb + 4 * nq];
        }
        __syncthreads();
        #pragma unroll
        for (int kk = 0; kk < 16; ++kk) {
            float4 a0 = *(const float4*)&As[kk][8 * ty];
            float4 a1 = *(const float4*)&As[kk][8 * ty + 4];
            float4 b0 = *(const float4*)&Bs[kk][8 * tx];
            float4 b1 = *(const float4*)&Bs[kk][8 * tx + 4];
            float av[8] = {a0.x, a0.y, a0.z, a0.w, a1.x, a1.y, a1.z, a1.w};
            float bv[8] = {b0.x, b0.y, b0.z, b0.w, b1.x, b1.y, b1.z, b1.w};
            #pragma unroll
            for (int i = 0; i < 8; ++i)
                #pragma unroll
                for (int j = 0; j < 8; ++j) acc[i][j] += av[i] * bv[j];
        }
    }
    // max over 8 local rows -> LDS -> max over 16 ty -> atomicMax per batch
    float cm[8];
    #pragma unroll
    for (int j = 0; j < 8; ++j) {
        float m0 = acc[0][j];
        #pragma unroll
        for (int i = 1; i < 8; ++i) m0 = fmaxf(m0, acc[i][j]);
        cm[j] = m0;
    }
    __syncthreads();
    float* scr = &As[0][0];                            // 16x128 reuse
    #pragma unroll
    for (int j = 0; j < 8; ++j) scr[ty * 128 + 8 * tx + j] = cm[j];
    __syncthreads();
    if (t < 128) {
        float m0 = scr[t];
        #pragma unroll
        for (int y = 1; y < 16; ++y) m0 = fmaxf(m0, scr[y * 128 + t]);
        m0 += bias[nb + t];                            // max(x)+b == max(x+b)
        atomicMax(&pool[(mb / PPB) * 1024 + nb + t], f2o(m0));
    }
}

// ---------------- edge-conv aggregate: x[p] = U[p] + b + max_k V[idx] ----------------
__global__ void agg_kernel(const float* __restrict__ UV, const int* __restrict__ idx,
                           const float* __restrict__ bias, float* __restrict__ xo, int od) {
    const int p = blockIdx.x, c = threadIdx.x;
    const float u = UV[(size_t)p * 2 * od + c];
    float m = -3.4e38f;
    #pragma unroll
    for (int k = 0; k < KNN; ++k) {
        int j = idx[p * KNN + k];
        m = fmaxf(m, UV[(size_t)j * 2 * od + od + c]);
    }
    xo[(size_t)p * od + c] = u + bias[c] + m;
}

// ---------------- head: Lin + BN + ReLU (all 8 rows per block) ----------------
template<int IND, bool UNMAP>
__global__ __launch_bounds__(256)
void head_bn_kernel(const float* __restrict__ in, const float* __restrict__ W,
                    const float* __restrict__ bias, const float* __restrict__ g,
                    const float* __restrict__ be, float* __restrict__ out, int OD) {
    __shared__ float xs[8 * IND];
    __shared__ float sc[8][33];
    const int t = threadIdx.x;
    for (int e = t; e < 8 * IND; e += 256)
        xs[e] = UNMAP ? o2f(((const unsigned*)in)[e]) : in[e];
    __syncthreads();
    const int c = t & 31, r = t >> 5;
    const int cb = blockIdx.x * 32;
    float a = bias[cb + c];
    const float* xr = &xs[r * IND];
    #pragma unroll 4
    for (int k = 0; k < IND; ++k) a += xr[k] * W[(size_t)k * OD + cb + c];
    sc[r][c] = a;
    __syncthreads();
    float mu = 0.f;
    #pragma unroll
    for (int y = 0; y < 8; ++y) mu += sc[y][c];
    mu *= 0.125f;
    float vr = 0.f;
    #pragma unroll
    for (int y = 0; y < 8; ++y) { float d = sc[y][c] - mu; vr += d * d; }
    vr *= 0.125f;
    float o = g[cb + c] * (a - mu) * rsqrtf(vr + 1e-5f) + be[cb + c];
    out[r * OD + cb + c] = fmaxf(o, 0.f);
}

// final Lin [8,256]@[256,23] + log_softmax
__global__ void head3_kernel(const float* __restrict__ x, const float* __restrict__ W,
                             const float* __restrict__ b, float* __restrict__ out) {
    __shared__ float xs[8 * 256];
    __shared__ float lg[8][23];
    __shared__ float red[8][2];
    const int t = threadIdx.x;
    for (int e = t; e < 2048; e += 256) xs[e] = x[e];
    __syncthreads();
    if (t < 184) {
        int r = t / 23, c = t - 23 * r;
        float a = b[c];
        for (int k = 0; k < 256; ++k) a += xs[r * 256 + k] * W[k * 23 + c];
        lg[r][c] = a;
    }
    __syncthreads();
    if (t < 8) {
        float mx = -3.4e38f;
        for (int c = 0; c < 23; ++c) mx = fmaxf(mx, lg[t][c]);
        float s = 0.f;
        for (int c = 0; c < 23; ++c) s += expf(lg[t][c] - mx);
        red[t][0] = mx; red[t][1] = logf(s);
    }
    __syncthreads();
    if (t < 184) {
        int r = t / 23, c = t - 23 * r;
        out[t] = lg[r][c] - red[r][0] - red[r][1];
    }
}

// ---------------- launcher ----------------
extern "C" void kernel_launch(void* const* d_in, const int* in_sizes, int n_in,
                              void* d_out, int out_size, void* d_ws, size_t ws_size,
                              hipStream_t stream) {
    (void)in_sizes; (void)n_in; (void)out_size; (void)ws_size;
    const float* pos = (const float*)d_in[0];
    // d_in[1] = batch (repeat(arange(8),2048)) -> contiguous, unused
    const float* W1  = (const float*)d_in[2];  const float* b1  = (const float*)d_in[3];
    const float* W2  = (const float*)d_in[4];  const float* b2  = (const float*)d_in[5];
    const float* W3  = (const float*)d_in[6];  const float* b3  = (const float*)d_in[7];
    const float* Wf1 = (const float*)d_in[8];  const float* bf1 = (const float*)d_in[9];
    const float* Wa  = (const float*)d_in[10]; const float* ba  = (const float*)d_in[11];
    const float* ga  = (const float*)d_in[12]; const float* bea = (const float*)d_in[13];
    const float* Wb  = (const float*)d_in[14]; const float* bb  = (const float*)d_in[15];
    const float* gb  = (const float*)d_in[16]; const float* beb = (const float*)d_in[17];
    const float* Wc  = (const float*)d_in[18]; const float* bc  = (const float*)d_in[19];

    char* ws = (char*)d_ws;
    float*    x0p  = (float*)(ws + OFF_X0P);
    float*    n2   = (float*)(ws + OFF_N2);
    int*      idx  = (int*)(ws + OFF_IDX);
    float*    wuv1 = (float*)(ws + OFF_WUV1);
    float*    wuv2 = (float*)(ws + OFF_WUV2);
    float*    wuv3 = (float*)(ws + OFF_WUV3);
    unsigned* pool = (unsigned*)(ws + OFF_POOL);
    float*    C1   = (float*)(ws + OFF_C1);
    float*    C2   = (float*)(ws + OFF_C2);
    float*    x1   = (float*)(ws + OFF_X1);
    float*    x2   = (float*)(ws + OFF_X2);
    float*    x3   = (float*)(ws + OFF_X3);
    float*    UV   = (float*)(ws + OFF_UV);

    // prep
    build_x0p_kernel<<<1024, 256, 0, stream>>>(pos, x0p);
    wuv_build_kernel<<<8,   256, 0, stream>>>(W1, wuv1, 3,   16,  64);
    wuv_build_kernel<<<64,  256, 0, stream>>>(W2, wuv2, 64,  64,  128);
    wuv_build_kernel<<<256, 256, 0, stream>>>(W3, wuv3, 128, 128, 256);
    init_pool_kernel<<<32,  256, 0, stream>>>(pool);

    // edge conv 1 (d=3 padded to 16 -> 64)
    sqnorm_kernel<16><<<64, 256, 0, stream>>>(x0p, n2);
    knn_kernel<16, 16><<<512, 256, 0, stream>>>(x0p, n2, idx);
    gemm_uv_kernel<<<dim3(1, 128), 256, 0, stream>>>(x0p, wuv1, UV, NPTS, 128, 16);
    agg_kernel<<<NPTS, 64, 0, stream>>>(UV, idx, b1, x1, 64);

    // edge conv 2 (64 -> 128)
    sqnorm_kernel<64><<<64, 256, 0, stream>>>(x1, n2);
    knn_kernel<64, 32><<<512, 256, 0, stream>>>(x1, n2, idx);
    gemm_uv_kernel<<<dim3(2, 128), 256, 0, stream>>>(x1, wuv2, UV, NPTS, 256, 64);
    agg_kernel<<<NPTS, 128, 0, stream>>>(UV, idx, b2, x2, 128);

    // edge conv 3 (128 -> 256)
    sqnorm_kernel<128><<<64, 256, 0, stream>>>(x2, n2);
    knn_kernel<128, 32><<<512, 256, 0, stream>>>(x2, n2, idx);
    gemm_uv_kernel<<<dim3(4, 128), 256, 0, stream>>>(x2, wuv3, UV, NPTS, 512, 128);
    agg_kernel<<<NPTS, 256, 0, stream>>>(UV, idx, b3, x3, 256);

    // fc1 + fused global max pool
    gemm_fc1_kernel<<<dim3(8, 128), 256, 0, stream>>>(x1, x2, x3, Wf1, bf1, pool);

    // head
    head_bn_kernel<1024, true ><<<16, 256, 0, stream>>>((const float*)pool, Wa, ba, ga, bea, C1, 512);
    head_bn_kernel<512,  false><<<8,  256, 0, stream>>>(C1, Wb, bb, gb, beb, C2, 256);
    head3_kernel<<<1, 256, 0, stream>>>(C2, Wc, bc, (float*)d_out);
}

// Round 2
// 1547.808 us; speedup vs baseline: 1.4968x; 1.4968x over previous
//
#include <hip/hip_runtime.h>
#include <math.h>

#define NPTS 16384
#define PPB  2048
#define KNN  20

// ---------------- workspace layout (bytes), total 64 MB ----------------
#define OFF_X0P   0u           // 16384*16*4   = 1,048,576  (pos zero-padded to 16 cols)
#define OFF_N2    1048576u     // 16384*4      = 65,536     (sq norms, reused per stage)
#define OFF_IDX   1114112u     // 16384*20*4   = 1,310,720  (knn indices, reused)
#define OFF_WUV1  2424832u     // 16*128*4
#define OFF_WUV2  2433024u     // 64*256*4
#define OFF_WUV3  2498560u     // 128*512*4
#define OFF_POOL  2760704u     // 8192*4 (ordered-uint max pool)
#define OFF_C1    2793472u     // 8*512*4
#define OFF_C2    2809856u     // 8*256*4
#define OFF_X1    4194304u     // 16384*64*4   = 4 MB
#define OFF_X2    8388608u     // 16384*128*4  = 8 MB
#define OFF_X3    16777216u    // 16384*256*4  = 16 MB
#define OFF_UV    33554432u    // 16384*512*4  = 32 MB (per-stage U|V, stride 2*out)

// order-preserving float<->uint for atomicMax-based pooling
__device__ __forceinline__ unsigned f2o(float f) {
    unsigned u = __float_as_uint(f);
    return (u & 0x80000000u) ? ~u : (u | 0x80000000u);
}
__device__ __forceinline__ float o2f(unsigned u) {
    return (u & 0x80000000u) ? __uint_as_float(u & 0x7fffffffu) : __uint_as_float(~u);
}

// ---------------- prep kernels ----------------
__global__ void build_x0p_kernel(const float* __restrict__ pos, float* __restrict__ x0p) {
    int e = blockIdx.x * 256 + threadIdx.x;           // < 16384*16
    int p = e >> 4, k = e & 15;
    x0p[e] = (k < 3) ? pos[p * 3 + k] : 0.f;
}

// W [2d][od] -> Wuv [dpad][2*od]:  cols [0,od): W_top - W_bot (U),  cols [od,2od): W_bot (V)
__global__ void wuv_build_kernel(const float* __restrict__ W, float* __restrict__ Wuv,
                                 int d, int dpad, int od) {
    int tot = dpad * 2 * od;
    for (int e = blockIdx.x * 256 + threadIdx.x; e < tot; e += gridDim.x * 256) {
        int r = e / (2 * od), c = e - r * (2 * od);
        float v = 0.f;
        if (r < d) v = (c < od) ? (W[r * od + c] - W[(d + r) * od + c])
                                : W[(d + r) * od + (c - od)];
        Wuv[e] = v;
    }
}

__global__ void init_pool_kernel(unsigned* __restrict__ pool) {
    pool[blockIdx.x * 256 + threadIdx.x] = 0u;
}

template<int D>
__global__ void sqnorm_kernel(const float* __restrict__ X, float* __restrict__ n2) {
    int p = blockIdx.x * 256 + threadIdx.x;
    float s = 0.f;
    #pragma unroll
    for (int k = 0; k < D; k += 4) {
        float4 v = *(const float4*)&X[(size_t)p * D + k];
        s += v.x * v.x + v.y * v.y + v.z * v.z + v.w * v.w;
    }
    n2[p] = s;
}

// ---------------- kNN v2: fused distance-GEMM + fully-parallel top-20 ----------------
// 32 query rows per block, candidate chunks of 128. GEMM: 16x16 thread grid,
// 2x8 micro-tile. Selection: 8 threads/row, each keeps exact top-20 of its
// 256-candidate stream in LDS lists; final 8-way shuffle-butterfly merge.
template<int D>
__global__ __launch_bounds__(256)
void knn2_kernel(const float* __restrict__ X, const float* __restrict__ n2,
                 int* __restrict__ idxout) {
    __shared__ float As[D][32];                 // A tile, k-major (2-way free)
    __shared__ float Bs[16][128];               // candidate k-chunk, k-major
    __shared__ float Ds[32][132];               // distance tile (+4 pad)
    __shared__ float bd[KNN][256];              // per-thread top-20 dists (slot-major)
    __shared__ unsigned short bi[KNN][256];     // per-thread top-20 local idx
    __shared__ float n2s[128];

    const int t = threadIdx.x;
    const int pbase = blockIdx.x * 32;
    const int qbase = (pbase / PPB) * PPB;      // batch-local candidates
    const int tx = t & 15, ty = t >> 4;         // gemm layout
    const int r  = t >> 3, sub = t & 7;         // select layout: 8 threads/row

    // stage A tile (32 rows x D), transposed
    {
        const int nf4 = D / 4;
        for (int e = t; e < 32 * nf4; e += 256) {
            int m = e / nf4, k4 = e % nf4;
            float4 v = *(const float4*)&X[(size_t)(pbase + m) * D + 4 * k4];
            As[4 * k4 + 0][m] = v.x; As[4 * k4 + 1][m] = v.y;
            As[4 * k4 + 2][m] = v.z; As[4 * k4 + 3][m] = v.w;
        }
    }
    #pragma unroll
    for (int s = 0; s < KNN; ++s) { bd[s][t] = 3.0e38f; bi[s][t] = 0; }
    float worst = 3.0e38f; int wslot = 0;
    __syncthreads();

    for (int qt = 0; qt < PPB / 128; ++qt) {
        const int qb = qbase + qt * 128;
        if (t < 128) n2s[t] = n2[qb + t];
        float acc[2][8];
        #pragma unroll
        for (int i = 0; i < 2; ++i)
            #pragma unroll
            for (int j = 0; j < 8; ++j) acc[i][j] = 0.f;

        for (int kc = 0; kc < D; kc += 16) {
            __syncthreads();                    // Bs consumers done (also n2s/Ds prev)
            for (int e = t; e < 512; e += 256) {
                int q = e >> 2, k4 = e & 3;
                float4 v = *(const float4*)&X[(size_t)(qb + q) * D + kc + 4 * k4];
                Bs[4 * k4 + 0][q] = v.x; Bs[4 * k4 + 1][q] = v.y;
                Bs[4 * k4 + 2][q] = v.z; Bs[4 * k4 + 3][q] = v.w;
            }
            __syncthreads();
            #pragma unroll
            for (int kk = 0; kk < 16; ++kk) {
                float2 a  = *(const float2*)&As[kc + kk][2 * ty];
                float4 b0 = *(const float4*)&Bs[kk][8 * tx];
                float4 b1 = *(const float4*)&Bs[kk][8 * tx + 4];
                float av[2] = {a.x, a.y};
                float bv[8] = {b0.x, b0.y, b0.z, b0.w, b1.x, b1.y, b1.z, b1.w};
                #pragma unroll
                for (int i = 0; i < 2; ++i)
                    #pragma unroll
                    for (int j = 0; j < 8; ++j) acc[i][j] += av[i] * bv[j];
            }
        }
        __syncthreads();                        // prev select done; n2s ready
        #pragma unroll
        for (int i = 0; i < 2; ++i) {
            int row = 2 * ty + i;
            float4 nA = *(const float4*)&n2s[8 * tx];
            float4 nB = *(const float4*)&n2s[8 * tx + 4];
            float4 w0 = {nA.x - 2.f * acc[i][0], nA.y - 2.f * acc[i][1],
                         nA.z - 2.f * acc[i][2], nA.w - 2.f * acc[i][3]};
            float4 w1 = {nB.x - 2.f * acc[i][4], nB.y - 2.f * acc[i][5],
                         nB.z - 2.f * acc[i][6], nB.w - 2.f * acc[i][7]};
            *(float4*)&Ds[row][8 * tx]     = w0;
            *(float4*)&Ds[row][8 * tx + 4] = w1;
        }
        __syncthreads();
        // select: this thread scans cols [16*sub, 16*sub+16) of row r
        const int cb = 16 * sub;
        #pragma unroll
        for (int c4 = 0; c4 < 4; ++c4) {
            float4 v = *(const float4*)&Ds[r][cb + 4 * c4];
            int q0 = qt * 128 + cb + 4 * c4;    // batch-local candidate index
            float vv[4] = {v.x, v.y, v.z, v.w};
            #pragma unroll
            for (int j = 0; j < 4; ++j) {
                if (vv[j] < worst) {
                    bd[wslot][t] = vv[j];
                    bi[wslot][t] = (unsigned short)(q0 + j);
                    float w = bd[0][t]; int sl = 0;
                    #pragma unroll
                    for (int s = 1; s < KNN; ++s) {
                        float x = bd[s][t];
                        if (x > w) { w = x; sl = s; }
                    }
                    worst = w; wslot = sl;
                }
            }
        }
    }

    // merge 8 lists of 20 -> top-20 per row, via 20 rounds of 8-lane argmin
    __syncthreads();                            // all selects done; Ds reusable
    int* DsI = (int*)&Ds[0][0];                 // row stride 132 ints
    float mv = 3.3e38f; int mq = 1 << 20, ms = 0;
    #pragma unroll
    for (int s = 0; s < KNN; ++s) {
        float x = bd[s][t]; int q = bi[s][t];
        if (x < mv || (x == mv && q < mq)) { mv = x; mq = q; ms = s; }
    }
    for (int round = 0; round < KNN; ++round) {
        float rv = mv; int rq = mq;
        #pragma unroll
        for (int m = 1; m < 8; m <<= 1) {
            float ov = __shfl_xor(rv, m, 64);
            int   oq = __shfl_xor(rq, m, 64);
            if (ov < rv || (ov == rv && oq < rq)) { rv = ov; rq = oq; }
        }
        if (sub == 0) DsI[r * 132 + round] = rq;
        if (mv == rv && mq == rq) {             // I own the winner: consume + rescan
            bd[ms][t] = 3.3e38f;
            mv = 3.3e38f; mq = 1 << 20; ms = 0;
            #pragma unroll
            for (int s = 0; s < KNN; ++s) {
                float x = bd[s][t]; int q = bi[s][t];
                if (x < mv || (x == mv && q < mq)) { mv = x; mq = q; ms = s; }
            }
        }
    }
    // same-wave LDS visibility within the 8-lane row group: no barrier needed
    for (int s = sub; s < KNN; s += 8)
        idxout[(size_t)(pbase + r) * KNN + s] = qbase + DsI[r * 132 + s];
}

// ---------------- fp32 tiled GEMM 128x128, 8x8 micro-tile ----------------
__global__ __launch_bounds__(256)
void gemm_uv_kernel(const float* __restrict__ A, const float* __restrict__ B,
                    float* __restrict__ C, int M, int N, int K) {
    __shared__ float As[16][128];
    __shared__ float Bs[16][128];
    const int t = threadIdx.x;
    const int tx = t & 15, ty = t >> 4;
    const int nb = blockIdx.x * 128;
    const int mb = blockIdx.y * 128;
    float acc[8][8];
    #pragma unroll
    for (int i = 0; i < 8; ++i)
        #pragma unroll
        for (int j = 0; j < 8; ++j) acc[i][j] = 0.f;

    for (int kc = 0; kc < K; kc += 16) {
        __syncthreads();
        for (int e = t; e < 512; e += 256) {          // A: 128 rows x 16 k -> As[k][m]
            int m = e >> 2, kq = e & 3;
            float4 v = *(const float4*)&A[(size_t)(mb + m) * K + kc + 4 * kq];
            As[4 * kq + 0][m] = v.x; As[4 * kq + 1][m] = v.y;
            As[4 * kq + 2][m] = v.z; As[4 * kq + 3][m] = v.w;
        }
        for (int e = t; e < 512; e += 256) {          // B: 16 k x 128 n
            int kr = e >> 5, nq = e & 31;
            *(float4*)&Bs[kr][4 * nq] = *(const float4*)&B[(size_t)(kc + kr) * N + nb + 4 * nq];
        }
        __syncthreads();
        #pragma unroll
        for (int kk = 0; kk < 16; ++kk) {
            float4 a0 = *(const float4*)&As[kk][8 * ty];
            float4 a1 = *(const float4*)&As[kk][8 * ty + 4];
            float4 b0 = *(const float4*)&Bs[kk][8 * tx];
            float4 b1 = *(const float4*)&Bs[kk][8 * tx + 4];
            float av[8] = {a0.x, a0.y, a0.z, a0.w, a1.x, a1.y, a1.z, a1.w};
            float bv[8] = {b0.x, b0.y, b0.z, b0.w, b1.x, b1.y, b1.z, b1.w};
            #pragma unroll
            for (int i = 0; i < 8; ++i)
                #pragma unroll
                for (int j = 0; j < 8; ++j) acc[i][j] += av[i] * bv[j];
        }
    }
    #pragma unroll
    for (int i = 0; i < 8; ++i) {
        float4 v0 = {acc[i][0], acc[i][1], acc[i][2], acc[i][3]};
        float4 v1 = {acc[i][4], acc[i][5], acc[i][6], acc[i][7]};
        *(float4*)&C[(size_t)(mb + 8 * ty + i) * N + nb + 8 * tx] = v0;
        *(float4*)&C[(size_t)(mb + 8 * ty + i) * N + nb + 8 * tx + 4] = v1;
    }
}

// fc1 GEMM: A = concat(x1,x2,x3) on the fly, fused per-batch max-pool epilogue
__global__ __launch_bounds__(256)
void gemm_fc1_kernel(const float* __restrict__ x1, const float* __restrict__ x2,
                     const float* __restrict__ x3, const float* __restrict__ B,
                     const float* __restrict__ bias, unsigned* __restrict__ pool) {
    const int N = 1024, K = 448;
    __shared__ float As[16][128];
    __shared__ float Bs[16][128];
    const int t = threadIdx.x;
    const int tx = t & 15, ty = t >> 4;
    const int nb = blockIdx.x * 128;
    const int mb = blockIdx.y * 128;
    float acc[8][8];
    #pragma unroll
    for (int i = 0; i < 8; ++i)
        #pragma unroll
        for (int j = 0; j < 8; ++j) acc[i][j] = 0.f;

    for (int kc = 0; kc < K; kc += 16) {
        __syncthreads();
        for (int e = t; e < 512; e += 256) {
            int m = e >> 2, kq = e & 3;
            int k = kc + 4 * kq;
            int row = mb + m;
            float4 v;
            if (k < 64)       v = *(const float4*)&x1[(size_t)row * 64 + k];
            else if (k < 192) v = *(const float4*)&x2[(size_t)row * 128 + (k - 64)];
            else              v = *(const float4*)&x3[(size_t)row * 256 + (k - 192)];
            As[4 * kq + 0][m] = v.x; As[4 * kq + 1][m] = v.y;
            As[4 * kq + 2][m] = v.z; As[4 * kq + 3][m] = v.w;
        }
        for (int e = t; e < 512; e += 256) {
            int kr = e >> 5, nq = e & 31;
            *(float4*)&Bs[kr][4 * nq] = *(const float4*)&B[(size_t)(kc + kr) * N + nb + 4 * nq];
        }
        __syncthreads();
        #pragma unroll
        for (int kk = 0; kk < 16; ++kk) {
            float4 a0 = *(const float4*)&As[kk][8 * ty];
            float4 a1 = *(const float4*)&As[kk][8 * ty + 4];
            float4 b0 = *(const float4*)&Bs[kk][8 * tx];
            float4 b1 = *(const float4*)&Bs[kk][8 * tx + 4];
            float av[8] = {a0.x, a0.y, a0.z, a0.w, a1.x, a1.y, a1.z, a1.w};
            float bv[8] = {b0.x, b0.y, b0.z, b0.w, b1.x, b1.y, b1.z, b1.w};
            #pragma unroll
            for (int i = 0; i < 8; ++i)
                #pragma unroll
                for (int j = 0; j < 8; ++j) acc[i][j] += av[i] * bv[j];
        }
    }
    float cm[8];
    #pragma unroll
    for (int j = 0; j < 8; ++j) {
        float m0 = acc[0][j];
        #pragma unroll
        for (int i = 1; i < 8; ++i) m0 = fmaxf(m0, acc[i][j]);
        cm[j] = m0;
    }
    __syncthreads();
    float* scr = &As[0][0];
    #pragma unroll
    for (int j = 0; j < 8; ++j) scr[ty * 128 + 8 * tx + j] = cm[j];
    __syncthreads();
    if (t < 128) {
        float m0 = scr[t];
        #pragma unroll
        for (int y = 1; y < 16; ++y) m0 = fmaxf(m0, scr[y * 128 + t]);
        m0 += bias[nb + t];
        atomicMax(&pool[(mb / PPB) * 1024 + nb + t], f2o(m0));
    }
}

// ---------------- edge-conv aggregate: x[p] = U[p] + b + max_k V[idx] ----------------
__global__ void agg_kernel(const float* __restrict__ UV, const int* __restrict__ idx,
                           const float* __restrict__ bias, float* __restrict__ xo, int od) {
    const int p = blockIdx.x, c = threadIdx.x;
    const float u = UV[(size_t)p * 2 * od + c];
    float m = -3.4e38f;
    #pragma unroll
    for (int k = 0; k < KNN; ++k) {
        int j = idx[p * KNN + k];
        m = fmaxf(m, UV[(size_t)j * 2 * od + od + c]);
    }
    xo[(size_t)p * od + c] = u + bias[c] + m;
}

// ---------------- head: Lin + BN + ReLU (all 8 rows per block) ----------------
template<int IND, bool UNMAP>
__global__ __launch_bounds__(256)
void head_bn_kernel(const float* __restrict__ in, const float* __restrict__ W,
                    const float* __restrict__ bias, const float* __restrict__ g,
                    const float* __restrict__ be, float* __restrict__ out, int OD) {
    __shared__ float xs[8 * IND];
    __shared__ float sc[8][33];
    const int t = threadIdx.x;
    for (int e = t; e < 8 * IND; e += 256)
        xs[e] = UNMAP ? o2f(((const unsigned*)in)[e]) : in[e];
    __syncthreads();
    const int c = t & 31, r = t >> 5;
    const int cb = blockIdx.x * 32;
    float a = bias[cb + c];
    const float* xr = &xs[r * IND];
    #pragma unroll 4
    for (int k = 0; k < IND; ++k) a += xr[k] * W[(size_t)k * OD + cb + c];
    sc[r][c] = a;
    __syncthreads();
    float mu = 0.f;
    #pragma unroll
    for (int y = 0; y < 8; ++y) mu += sc[y][c];
    mu *= 0.125f;
    float vr = 0.f;
    #pragma unroll
    for (int y = 0; y < 8; ++y) { float d = sc[y][c] - mu; vr += d * d; }
    vr *= 0.125f;
    float o = g[cb + c] * (a - mu) * rsqrtf(vr + 1e-5f) + be[cb + c];
    out[r * OD + cb + c] = fmaxf(o, 0.f);
}

// final Lin [8,256]@[256,23] + log_softmax
__global__ void head3_kernel(const float* __restrict__ x, const float* __restrict__ W,
                             const float* __restrict__ b, float* __restrict__ out) {
    __shared__ float xs[8 * 256];
    __shared__ float lg[8][23];
    __shared__ float red[8][2];
    const int t = threadIdx.x;
    for (int e = t; e < 2048; e += 256) xs[e] = x[e];
    __syncthreads();
    if (t < 184) {
        int r = t / 23, c = t - 23 * r;
        float a = b[c];
        for (int k = 0; k < 256; ++k) a += xs[r * 256 + k] * W[k * 23 + c];
        lg[r][c] = a;
    }
    __syncthreads();
    if (t < 8) {
        float mx = -3.4e38f;
        for (int c = 0; c < 23; ++c) mx = fmaxf(mx, lg[t][c]);
        float s = 0.f;
        for (int c = 0; c < 23; ++c) s += expf(lg[t][c] - mx);
        red[t][0] = mx; red[t][1] = logf(s);
    }
    __syncthreads();
    if (t < 184) {
        int r = t / 23, c = t - 23 * r;
        out[t] = lg[r][c] - red[r][0] - red[r][1];
    }
}

// ---------------- launcher ----------------
extern "C" void kernel_launch(void* const* d_in, const int* in_sizes, int n_in,
                              void* d_out, int out_size, void* d_ws, size_t ws_size,
                              hipStream_t stream) {
    (void)in_sizes; (void)n_in; (void)out_size; (void)ws_size;
    const float* pos = (const float*)d_in[0];
    const float* W1  = (const float*)d_in[2];  const float* b1  = (const float*)d_in[3];
    const float* W2  = (const float*)d_in[4];  const float* b2  = (const float*)d_in[5];
    const float* W3  = (const float*)d_in[6];  const float* b3  = (const float*)d_in[7];
    const float* Wf1 = (const float*)d_in[8];  const float* bf1 = (const float*)d_in[9];
    const float* Wa  = (const float*)d_in[10]; const float* ba  = (const float*)d_in[11];
    const float* ga  = (const float*)d_in[12]; const float* bea = (const float*)d_in[13];
    const float* Wb  = (const float*)d_in[14]; const float* bb  = (const float*)d_in[15];
    const float* gb  = (const float*)d_in[16]; const float* beb = (const float*)d_in[17];
    const float* Wc  = (const float*)d_in[18]; const float* bc  = (const float*)d_in[19];

    char* ws = (char*)d_ws;
    float*    x0p  = (float*)(ws + OFF_X0P);
    float*    n2   = (float*)(ws + OFF_N2);
    int*      idx  = (int*)(ws + OFF_IDX);
    float*    wuv1 = (float*)(ws + OFF_WUV1);
    float*    wuv2 = (float*)(ws + OFF_WUV2);
    float*    wuv3 = (float*)(ws + OFF_WUV3);
    unsigned* pool = (unsigned*)(ws + OFF_POOL);
    float*    C1   = (float*)(ws + OFF_C1);
    float*    C2   = (float*)(ws + OFF_C2);
    float*    x1   = (float*)(ws + OFF_X1);
    float*    x2   = (float*)(ws + OFF_X2);
    float*    x3   = (float*)(ws + OFF_X3);
    float*    UV   = (float*)(ws + OFF_UV);

    // prep
    build_x0p_kernel<<<1024, 256, 0, stream>>>(pos, x0p);
    wuv_build_kernel<<<8,   256, 0, stream>>>(W1, wuv1, 3,   16,  64);
    wuv_build_kernel<<<64,  256, 0, stream>>>(W2, wuv2, 64,  64,  128);
    wuv_build_kernel<<<256, 256, 0, stream>>>(W3, wuv3, 128, 128, 256);
    init_pool_kernel<<<32,  256, 0, stream>>>(pool);

    // edge conv 1 (d=3 padded to 16 -> 64)
    sqnorm_kernel<16><<<64, 256, 0, stream>>>(x0p, n2);
    knn2_kernel<16><<<512, 256, 0, stream>>>(x0p, n2, idx);
    gemm_uv_kernel<<<dim3(1, 128), 256, 0, stream>>>(x0p, wuv1, UV, NPTS, 128, 16);
    agg_kernel<<<NPTS, 64, 0, stream>>>(UV, idx, b1, x1, 64);

    // edge conv 2 (64 -> 128)
    sqnorm_kernel<64><<<64, 256, 0, stream>>>(x1, n2);
    knn2_kernel<64><<<512, 256, 0, stream>>>(x1, n2, idx);
    gemm_uv_kernel<<<dim3(2, 128), 256, 0, stream>>>(x1, wuv2, UV, NPTS, 256, 64);
    agg_kernel<<<NPTS, 128, 0, stream>>>(UV, idx, b2, x2, 128);

    // edge conv 3 (128 -> 256)
    sqnorm_kernel<128><<<64, 256, 0, stream>>>(x2, n2);
    knn2_kernel<128><<<512, 256, 0, stream>>>(x2, n2, idx);
    gemm_uv_kernel<<<dim3(4, 128), 256, 0, stream>>>(x2, wuv3, UV, NPTS, 512, 128);
    agg_kernel<<<NPTS, 256, 0, stream>>>(UV, idx, b3, x3, 256);

    // fc1 + fused global max pool
    gemm_fc1_kernel<<<dim3(8, 128), 256, 0, stream>>>(x1, x2, x3, Wf1, bf1, pool);

    // head
    head_bn_kernel<1024, true ><<<16, 256, 0, stream>>>((const float*)pool, Wa, ba, ga, bea, C1, 512);
    head_bn_kernel<512,  false><<<8,  256, 0, stream>>>(C1, Wb, bb, gb, beb, C2, 256);
    head3_kernel<<<1, 256, 0, stream>>>(C2, Wc, bc, (float*)d_out);
}

// Round 3
// 1305.234 us; speedup vs baseline: 1.7750x; 1.1858x over previous
//
#include <hip/hip_runtime.h>
#include <math.h>

#define NPTS 16384
#define PPB  2048
#define KNN  20

// ---------------- workspace layout (bytes), total 64 MiB ----------------
#define OFF_X0P   0u           // 16384*16*4
#define OFF_N2    1048576u     // 16384*4
#define OFF_IDX   1114112u     // 16384*20*4
#define OFF_WUV1  2424832u     // 16*128*4
#define OFF_WUV2  2433024u     // 64*256*4
#define OFF_WUV3  2498560u     // 128*512*4
#define OFF_POOL  2760704u     // 8192*4
#define OFF_C1    2793472u     // 8*512*4
#define OFF_C2    2809856u     // 8*256*4
#define OFF_X1    4194304u     // 16384*64*4
#define OFF_X2    8388608u     // 16384*128*4
#define OFF_X3    16777216u    // 16384*256*4
#define OFF_UV    33554432u    // 32 MiB: per-stage U|V; ALSO 2-batch dist-matrix scratch
                               // (disjoint in time: Dm used in knn phase, UV after)

// order-preserving float<->uint for atomicMax-based pooling
__device__ __forceinline__ unsigned f2o(float f) {
    unsigned u = __float_as_uint(f);
    return (u & 0x80000000u) ? ~u : (u | 0x80000000u);
}
__device__ __forceinline__ float o2f(unsigned u) {
    return (u & 0x80000000u) ? __uint_as_float(u & 0x7fffffffu) : __uint_as_float(~u);
}

// ---------------- prep kernels ----------------
__global__ void build_x0p_kernel(const float* __restrict__ pos, float* __restrict__ x0p) {
    int e = blockIdx.x * 256 + threadIdx.x;
    int p = e >> 4, k = e & 15;
    x0p[e] = (k < 3) ? pos[p * 3 + k] : 0.f;
}

__global__ void wuv_build_kernel(const float* __restrict__ W, float* __restrict__ Wuv,
                                 int d, int dpad, int od) {
    int tot = dpad * 2 * od;
    for (int e = blockIdx.x * 256 + threadIdx.x; e < tot; e += gridDim.x * 256) {
        int r = e / (2 * od), c = e - r * (2 * od);
        float v = 0.f;
        if (r < d) v = (c < od) ? (W[r * od + c] - W[(d + r) * od + c])
                                : W[(d + r) * od + (c - od)];
        Wuv[e] = v;
    }
}

__global__ void init_pool_kernel(unsigned* __restrict__ pool) {
    pool[blockIdx.x * 256 + threadIdx.x] = 0u;
}

template<int D>
__global__ void sqnorm_kernel(const float* __restrict__ X, float* __restrict__ n2) {
    int p = blockIdx.x * 256 + threadIdx.x;
    float s = 0.f;
    #pragma unroll
    for (int k = 0; k < D; k += 4) {
        float4 v = *(const float4*)&X[(size_t)p * D + k];
        s += v.x * v.x + v.y * v.y + v.z * v.z + v.w * v.w;
    }
    n2[p] = s;
}

// ---------------- distance GEMM: Dm[z][r][c] = n2[c] - 2*dot(x_r, x_c) ----------------
// grid (16,16,2): x=col tile, y=row tile, z=batch-in-round. 128x128 tile, 8x8 micro.
// B-fragment split 4tx / 64+4tx -> 2-way (free) LDS reads; pad-132 staging conflict-free.
template<int K>
__global__ __launch_bounds__(256)
void gemm_d_kernel(const float* __restrict__ X, const float* __restrict__ n2,
                   float* __restrict__ Dm, int batch0) {
    __shared__ float As[16][132];
    __shared__ float Bs[16][132];
    const int t = threadIdx.x;
    const int tx = t & 15, ty = t >> 4;
    const int bb = batch0 + blockIdx.z;
    const int rb = blockIdx.y * 128;               // row-local base
    const int cb = blockIdx.x * 128;               // col-local base
    const float* Xr = X + (size_t)(bb * PPB + rb) * K;
    const float* Xc = X + (size_t)(bb * PPB + cb) * K;

    float acc[8][8];
    #pragma unroll
    for (int i = 0; i < 8; ++i)
        #pragma unroll
        for (int j = 0; j < 8; ++j) acc[i][j] = 0.f;

    for (int kc = 0; kc < K; kc += 16) {
        __syncthreads();
        for (int e = t; e < 512; e += 256) {       // rows: transpose to k-major
            int m = e >> 2, kq = e & 3;
            float4 v = *(const float4*)&Xr[(size_t)m * K + kc + 4 * kq];
            As[4 * kq + 0][m] = v.x; As[4 * kq + 1][m] = v.y;
            As[4 * kq + 2][m] = v.z; As[4 * kq + 3][m] = v.w;
        }
        for (int e = t; e < 512; e += 256) {       // cols: transpose to k-major
            int m = e >> 2, kq = e & 3;
            float4 v = *(const float4*)&Xc[(size_t)m * K + kc + 4 * kq];
            Bs[4 * kq + 0][m] = v.x; Bs[4 * kq + 1][m] = v.y;
            Bs[4 * kq + 2][m] = v.z; Bs[4 * kq + 3][m] = v.w;
        }
        __syncthreads();
        #pragma unroll
        for (int kk = 0; kk < 16; ++kk) {
            float4 a0 = *(const float4*)&As[kk][8 * ty];
            float4 a1 = *(const float4*)&As[kk][8 * ty + 4];
            float4 b0 = *(const float4*)&Bs[kk][4 * tx];
            float4 b1 = *(const float4*)&Bs[kk][64 + 4 * tx];
            float av[8] = {a0.x, a0.y, a0.z, a0.w, a1.x, a1.y, a1.z, a1.w};
            float bv[8] = {b0.x, b0.y, b0.z, b0.w, b1.x, b1.y, b1.z, b1.w};
            #pragma unroll
            for (int i = 0; i < 8; ++i)
                #pragma unroll
                for (int j = 0; j < 8; ++j) acc[i][j] += av[i] * bv[j];
        }
    }
    const float* n2c = n2 + bb * PPB + cb;
    float nq0[4], nq1[4];
    #pragma unroll
    for (int j = 0; j < 4; ++j) { nq0[j] = n2c[4 * tx + j]; nq1[j] = n2c[64 + 4 * tx + j]; }
    float* Dz = Dm + (size_t)blockIdx.z * PPB * PPB;
    #pragma unroll
    for (int i = 0; i < 8; ++i) {
        int r = rb + 8 * ty + i;
        float4 v0 = {nq0[0] - 2.f * acc[i][0], nq0[1] - 2.f * acc[i][1],
                     nq0[2] - 2.f * acc[i][2], nq0[3] - 2.f * acc[i][3]};
        float4 v1 = {nq1[0] - 2.f * acc[i][4], nq1[1] - 2.f * acc[i][5],
                     nq1[2] - 2.f * acc[i][6], nq1[3] - 2.f * acc[i][7]};
        *(float4*)&Dz[(size_t)r * PPB + cb + 4 * tx]      = v0;
        *(float4*)&Dz[(size_t)r * PPB + cb + 64 + 4 * tx] = v1;
    }
}

// ---------------- top-20 select: one wave per row, candidates in registers ----------------
__global__ __launch_bounds__(256)
void knn_select_kernel(const float* __restrict__ Dm, int* __restrict__ idxout, int batch0) {
    const int lane = threadIdx.x & 63;
    const int wid  = threadIdx.x >> 6;
    const int rowg = blockIdx.x * 4 + wid;          // 0..4095 this round
    const int z  = rowg >> 11, rl = rowg & 2047;
    const float* drow = Dm + (size_t)z * PPB * PPB + (size_t)rl * PPB;

    float c[32];
    #pragma unroll
    for (int j = 0; j < 8; ++j) {
        float4 v = *(const float4*)&drow[j * 256 + 4 * lane];
        c[4 * j + 0] = v.x; c[4 * j + 1] = v.y; c[4 * j + 2] = v.z; c[4 * j + 3] = v.w;
    }
    // lane-local argmin (ascending j => ascending col => lowest-index tie-break)
    float mv = c[0]; int mj = 0;
    #pragma unroll
    for (int j = 1; j < 32; ++j) if (c[j] < mv) { mv = c[j]; mj = j; }
    int mq = ((mj >> 2) << 8) + 4 * lane + (mj & 3);

    int keep = 0;
    for (int round = 0; round < KNN; ++round) {
        float rv = mv; int rq = mq;
        #pragma unroll
        for (int m = 1; m < 64; m <<= 1) {
            float ov = __shfl_xor(rv, m, 64);
            int   oq = __shfl_xor(rq, m, 64);
            if (ov < rv || (ov == rv && oq < rq)) { rv = ov; rq = oq; }
        }
        if (lane == round) keep = rq;
        if (rv == mv && rq == mq) {                 // unique winner (mq unique per lane)
            #pragma unroll
            for (int j = 0; j < 32; ++j) if (j == mj) c[j] = 3.4e38f;
            mv = c[0]; mj = 0;
            #pragma unroll
            for (int j = 1; j < 32; ++j) if (c[j] < mv) { mv = c[j]; mj = j; }
            mq = ((mj >> 2) << 8) + 4 * lane + (mj & 3);
        }
    }
    const int pbase = (batch0 + z) * PPB;
    if (lane < KNN)
        idxout[(size_t)(pbase + rl) * KNN + lane] = pbase + keep;
}

// ---------------- fp32 tiled GEMM 128x128, 8x8 micro-tile (conflict-fixed frags) ----------------
__global__ __launch_bounds__(256)
void gemm_uv_kernel(const float* __restrict__ A, const float* __restrict__ B,
                    float* __restrict__ C, int M, int N, int K) {
    __shared__ float As[16][132];
    __shared__ float Bs[16][132];
    const int t = threadIdx.x;
    const int tx = t & 15, ty = t >> 4;
    const int nb = blockIdx.x * 128;
    const int mb = blockIdx.y * 128;
    float acc[8][8];
    #pragma unroll
    for (int i = 0; i < 8; ++i)
        #pragma unroll
        for (int j = 0; j < 8; ++j) acc[i][j] = 0.f;

    for (int kc = 0; kc < K; kc += 16) {
        __syncthreads();
        for (int e = t; e < 512; e += 256) {
            int m = e >> 2, kq = e & 3;
            float4 v = *(const float4*)&A[(size_t)(mb + m) * K + kc + 4 * kq];
            As[4 * kq + 0][m] = v.x; As[4 * kq + 1][m] = v.y;
            As[4 * kq + 2][m] = v.z; As[4 * kq + 3][m] = v.w;
        }
        for (int e = t; e < 512; e += 256) {
            int kr = e >> 5, nq = e & 31;
            *(float4*)&Bs[kr][4 * nq] = *(const float4*)&B[(size_t)(kc + kr) * N + nb + 4 * nq];
        }
        __syncthreads();
        #pragma unroll
        for (int kk = 0; kk < 16; ++kk) {
            float4 a0 = *(const float4*)&As[kk][8 * ty];
            float4 a1 = *(const float4*)&As[kk][8 * ty + 4];
            float4 b0 = *(const float4*)&Bs[kk][4 * tx];
            float4 b1 = *(const float4*)&Bs[kk][64 + 4 * tx];
            float av[8] = {a0.x, a0.y, a0.z, a0.w, a1.x, a1.y, a1.z, a1.w};
            float bv[8] = {b0.x, b0.y, b0.z, b0.w, b1.x, b1.y, b1.z, b1.w};
            #pragma unroll
            for (int i = 0; i < 8; ++i)
                #pragma unroll
                for (int j = 0; j < 8; ++j) acc[i][j] += av[i] * bv[j];
        }
    }
    #pragma unroll
    for (int i = 0; i < 8; ++i) {
        float4 v0 = {acc[i][0], acc[i][1], acc[i][2], acc[i][3]};
        float4 v1 = {acc[i][4], acc[i][5], acc[i][6], acc[i][7]};
        *(float4*)&C[(size_t)(mb + 8 * ty + i) * N + nb + 4 * tx] = v0;
        *(float4*)&C[(size_t)(mb + 8 * ty + i) * N + nb + 64 + 4 * tx] = v1;
    }
}

// fc1 GEMM: A = concat(x1,x2,x3) on the fly, fused per-batch max-pool epilogue
__global__ __launch_bounds__(256)
void gemm_fc1_kernel(const float* __restrict__ x1, const float* __restrict__ x2,
                     const float* __restrict__ x3, const float* __restrict__ B,
                     const float* __restrict__ bias, unsigned* __restrict__ pool) {
    const int N = 1024, K = 448;
    __shared__ float As[16][132];
    __shared__ float Bs[16][132];
    const int t = threadIdx.x;
    const int tx = t & 15, ty = t >> 4;
    const int nb = blockIdx.x * 128;
    const int mb = blockIdx.y * 128;
    float acc[8][8];
    #pragma unroll
    for (int i = 0; i < 8; ++i)
        #pragma unroll
        for (int j = 0; j < 8; ++j) acc[i][j] = 0.f;

    for (int kc = 0; kc < K; kc += 16) {
        __syncthreads();
        for (int e = t; e < 512; e += 256) {
            int m = e >> 2, kq = e & 3;
            int k = kc + 4 * kq;
            int row = mb + m;
            float4 v;
            if (k < 64)       v = *(const float4*)&x1[(size_t)row * 64 + k];
            else if (k < 192) v = *(const float4*)&x2[(size_t)row * 128 + (k - 64)];
            else              v = *(const float4*)&x3[(size_t)row * 256 + (k - 192)];
            As[4 * kq + 0][m] = v.x; As[4 * kq + 1][m] = v.y;
            As[4 * kq + 2][m] = v.z; As[4 * kq + 3][m] = v.w;
        }
        for (int e = t; e < 512; e += 256) {
            int kr = e >> 5, nq = e & 31;
            *(float4*)&Bs[kr][4 * nq] = *(const float4*)&B[(size_t)(kc + kr) * N + nb + 4 * nq];
        }
        __syncthreads();
        #pragma unroll
        for (int kk = 0; kk < 16; ++kk) {
            float4 a0 = *(const float4*)&As[kk][8 * ty];
            float4 a1 = *(const float4*)&As[kk][8 * ty + 4];
            float4 b0 = *(const float4*)&Bs[kk][4 * tx];
            float4 b1 = *(const float4*)&Bs[kk][64 + 4 * tx];
            float av[8] = {a0.x, a0.y, a0.z, a0.w, a1.x, a1.y, a1.z, a1.w};
            float bv[8] = {b0.x, b0.y, b0.z, b0.w, b1.x, b1.y, b1.z, b1.w};
            #pragma unroll
            for (int i = 0; i < 8; ++i)
                #pragma unroll
                for (int j = 0; j < 8; ++j) acc[i][j] += av[i] * bv[j];
        }
    }
    float cm[8];
    #pragma unroll
    for (int j = 0; j < 8; ++j) {
        float m0 = acc[0][j];
        #pragma unroll
        for (int i = 1; i < 8; ++i) m0 = fmaxf(m0, acc[i][j]);
        cm[j] = m0;
    }
    __syncthreads();
    float* scr = &As[0][0];
    #pragma unroll
    for (int j = 0; j < 4; ++j) scr[ty * 128 + 4 * tx + j]      = cm[j];
    #pragma unroll
    for (int j = 4; j < 8; ++j) scr[ty * 128 + 64 + 4 * tx + (j - 4)] = cm[j];
    __syncthreads();
    if (t < 128) {
        float m0 = scr[t];
        #pragma unroll
        for (int y = 1; y < 16; ++y) m0 = fmaxf(m0, scr[y * 128 + t]);
        m0 += bias[nb + t];
        atomicMax(&pool[(mb / PPB) * 1024 + nb + t], f2o(m0));
    }
}

// ---------------- edge-conv aggregate: x[p] = U[p] + b + max_k V[idx] ----------------
__global__ void agg_kernel(const float* __restrict__ UV, const int* __restrict__ idx,
                           const float* __restrict__ bias, float* __restrict__ xo, int od) {
    const int p = blockIdx.x, c = threadIdx.x;
    const float u = UV[(size_t)p * 2 * od + c];
    float m = -3.4e38f;
    #pragma unroll
    for (int k = 0; k < KNN; ++k) {
        int j = idx[p * KNN + k];
        m = fmaxf(m, UV[(size_t)j * 2 * od + od + c]);
    }
    xo[(size_t)p * od + c] = u + bias[c] + m;
}

// ---------------- head: Lin + BN + ReLU (all 8 rows per block) ----------------
template<int IND, bool UNMAP>
__global__ __launch_bounds__(256)
void head_bn_kernel(const float* __restrict__ in, const float* __restrict__ W,
                    const float* __restrict__ bias, const float* __restrict__ g,
                    const float* __restrict__ be, float* __restrict__ out, int OD) {
    __shared__ float xs[8 * IND];
    __shared__ float sc[8][33];
    const int t = threadIdx.x;
    for (int e = t; e < 8 * IND; e += 256)
        xs[e] = UNMAP ? o2f(((const unsigned*)in)[e]) : in[e];
    __syncthreads();
    const int c = t & 31, r = t >> 5;
    const int cb = blockIdx.x * 32;
    float a = bias[cb + c];
    const float* xr = &xs[r * IND];
    #pragma unroll 4
    for (int k = 0; k < IND; ++k) a += xr[k] * W[(size_t)k * OD + cb + c];
    sc[r][c] = a;
    __syncthreads();
    float mu = 0.f;
    #pragma unroll
    for (int y = 0; y < 8; ++y) mu += sc[y][c];
    mu *= 0.125f;
    float vr = 0.f;
    #pragma unroll
    for (int y = 0; y < 8; ++y) { float d = sc[y][c] - mu; vr += d * d; }
    vr *= 0.125f;
    float o = g[cb + c] * (a - mu) * rsqrtf(vr + 1e-5f) + be[cb + c];
    out[r * OD + cb + c] = fmaxf(o, 0.f);
}

// final Lin [8,256]@[256,23] + log_softmax
__global__ void head3_kernel(const float* __restrict__ x, const float* __restrict__ W,
                             const float* __restrict__ b, float* __restrict__ out) {
    __shared__ float xs[8 * 256];
    __shared__ float lg[8][23];
    __shared__ float red[8][2];
    const int t = threadIdx.x;
    for (int e = t; e < 2048; e += 256) xs[e] = x[e];
    __syncthreads();
    if (t < 184) {
        int r = t / 23, c = t - 23 * r;
        float a = b[c];
        for (int k = 0; k < 256; ++k) a += xs[r * 256 + k] * W[k * 23 + c];
        lg[r][c] = a;
    }
    __syncthreads();
    if (t < 8) {
        float mx = -3.4e38f;
        for (int c = 0; c < 23; ++c) mx = fmaxf(mx, lg[t][c]);
        float s = 0.f;
        for (int c = 0; c < 23; ++c) s += expf(lg[t][c] - mx);
        red[t][0] = mx; red[t][1] = logf(s);
    }
    __syncthreads();
    if (t < 184) {
        int r = t / 23, c = t - 23 * r;
        out[t] = lg[r][c] - red[r][0] - red[r][1];
    }
}

// ---------------- launcher ----------------
extern "C" void kernel_launch(void* const* d_in, const int* in_sizes, int n_in,
                              void* d_out, int out_size, void* d_ws, size_t ws_size,
                              hipStream_t stream) {
    (void)in_sizes; (void)n_in; (void)out_size; (void)ws_size;
    const float* pos = (const float*)d_in[0];
    const float* W1  = (const float*)d_in[2];  const float* b1  = (const float*)d_in[3];
    const float* W2  = (const float*)d_in[4];  const float* b2  = (const float*)d_in[5];
    const float* W3  = (const float*)d_in[6];  const float* b3  = (const float*)d_in[7];
    const float* Wf1 = (const float*)d_in[8];  const float* bf1 = (const float*)d_in[9];
    const float* Wa  = (const float*)d_in[10]; const float* ba  = (const float*)d_in[11];
    const float* ga  = (const float*)d_in[12]; const float* bea = (const float*)d_in[13];
    const float* Wb  = (const float*)d_in[14]; const float* bb  = (const float*)d_in[15];
    const float* gb  = (const float*)d_in[16]; const float* beb = (const float*)d_in[17];
    const float* Wc  = (const float*)d_in[18]; const float* bc  = (const float*)d_in[19];

    char* ws = (char*)d_ws;
    float*    x0p  = (float*)(ws + OFF_X0P);
    float*    n2   = (float*)(ws + OFF_N2);
    int*      idx  = (int*)(ws + OFF_IDX);
    float*    wuv1 = (float*)(ws + OFF_WUV1);
    float*    wuv2 = (float*)(ws + OFF_WUV2);
    float*    wuv3 = (float*)(ws + OFF_WUV3);
    unsigned* pool = (unsigned*)(ws + OFF_POOL);
    float*    C1   = (float*)(ws + OFF_C1);
    float*    C2   = (float*)(ws + OFF_C2);
    float*    x1   = (float*)(ws + OFF_X1);
    float*    x2   = (float*)(ws + OFF_X2);
    float*    x3   = (float*)(ws + OFF_X3);
    float*    UV   = (float*)(ws + OFF_UV);
    float*    Dm   = (float*)(ws + OFF_UV);    // time-shared with UV

    // prep
    build_x0p_kernel<<<1024, 256, 0, stream>>>(pos, x0p);
    wuv_build_kernel<<<8,   256, 0, stream>>>(W1, wuv1, 3,   16,  64);
    wuv_build_kernel<<<64,  256, 0, stream>>>(W2, wuv2, 64,  64,  128);
    wuv_build_kernel<<<256, 256, 0, stream>>>(W3, wuv3, 128, 128, 256);
    init_pool_kernel<<<32,  256, 0, stream>>>(pool);

    // edge conv 1 (d=3 padded to 16 -> 64)
    sqnorm_kernel<16><<<64, 256, 0, stream>>>(x0p, n2);
    for (int r0 = 0; r0 < 8; r0 += 2) {
        gemm_d_kernel<16><<<dim3(16, 16, 2), 256, 0, stream>>>(x0p, n2, Dm, r0);
        knn_select_kernel<<<1024, 256, 0, stream>>>(Dm, idx, r0);
    }
    gemm_uv_kernel<<<dim3(1, 128), 256, 0, stream>>>(x0p, wuv1, UV, NPTS, 128, 16);
    agg_kernel<<<NPTS, 64, 0, stream>>>(UV, idx, b1, x1, 64);

    // edge conv 2 (64 -> 128)
    sqnorm_kernel<64><<<64, 256, 0, stream>>>(x1, n2);
    for (int r0 = 0; r0 < 8; r0 += 2) {
        gemm_d_kernel<64><<<dim3(16, 16, 2), 256, 0, stream>>>(x1, n2, Dm, r0);
        knn_select_kernel<<<1024, 256, 0, stream>>>(Dm, idx, r0);
    }
    gemm_uv_kernel<<<dim3(2, 128), 256, 0, stream>>>(x1, wuv2, UV, NPTS, 256, 64);
    agg_kernel<<<NPTS, 128, 0, stream>>>(UV, idx, b2, x2, 128);

    // edge conv 3 (128 -> 256)
    sqnorm_kernel<128><<<64, 256, 0, stream>>>(x2, n2);
    for (int r0 = 0; r0 < 8; r0 += 2) {
        gemm_d_kernel<128><<<dim3(16, 16, 2), 256, 0, stream>>>(x2, n2, Dm, r0);
        knn_select_kernel<<<1024, 256, 0, stream>>>(Dm, idx, r0);
    }
    gemm_uv_kernel<<<dim3(4, 128), 256, 0, stream>>>(x2, wuv3, UV, NPTS, 512, 128);
    agg_kernel<<<NPTS, 256, 0, stream>>>(UV, idx, b3, x3, 256);

    // fc1 + fused global max pool
    gemm_fc1_kernel<<<dim3(8, 128), 256, 0, stream>>>(x1, x2, x3, Wf1, bf1, pool);

    // head
    head_bn_kernel<1024, true ><<<16, 256, 0, stream>>>((const float*)pool, Wa, ba, ga, bea, C1, 512);
    head_bn_kernel<512,  false><<<8,  256, 0, stream>>>(C1, Wb, bb, gb, beb, C2, 256);
    head3_kernel<<<1, 256, 0, stream>>>(C2, Wc, bc, (float*)d_out);
}

// Round 4
// 1150.260 us; speedup vs baseline: 2.0142x; 1.1347x over previous
//
#include <hip/hip_runtime.h>
#include <math.h>

#define NPTS 16384
#define PPB  2048
#define KNN  20

// ---------------- workspace layout (bytes), total 64 MiB ----------------
#define OFF_X0P   0u           // 16384*16*4 (dead after stage-1; reused by Bt planes)
#define OFF_N2    1048576u     // 16384*4
#define OFF_IDX   1114112u     // 16384*20*4 (dead after agg3; tail reused by Bt)
#define OFF_WUV1  2424832u
#define OFF_WUV2  2433024u
#define OFF_WUV3  2498560u
#define OFF_POOL  2760704u     // 8192*4
#define OFF_C1    2793472u
#define OFF_C2    2809856u
#define OFF_X1    4194304u     // 16384*64*4
#define OFF_X2    8388608u     // 16384*128*4
#define OFF_X3    16777216u    // 16384*256*4
#define OFF_UV    33554432u    // 32 MiB: dist scratch -> U|V -> packed-A bf16 planes
// packed A planes (after agg3): hi at OFF_UV, lo at OFF_UV+14680064 (29.4 MB total)
#define OFF_APKH  33554432u
#define OFF_APKL  48234496u
// packed B^T planes (after agg3): 448*1024*2 B each
#define OFF_BTH   0u
#define OFF_BTL   917504u

typedef __attribute__((ext_vector_type(8))) short b16x8;
typedef __attribute__((ext_vector_type(4))) float f32x4;

// order-preserving float<->uint for atomicMax-based pooling
__device__ __forceinline__ unsigned f2o(float f) {
    unsigned u = __float_as_uint(f);
    return (u & 0x80000000u) ? ~u : (u | 0x80000000u);
}
__device__ __forceinline__ float o2f(unsigned u) {
    return (u & 0x80000000u) ? __uint_as_float(u & 0x7fffffffu) : __uint_as_float(~u);
}

// split fp32 -> (hi, lo) bf16 pair, RNE both; x ~= hi + lo to ~2^-18 rel
__device__ __forceinline__ void split_bf16(float x, unsigned short& h, unsigned short& l) {
    unsigned u = __float_as_uint(x);
    unsigned rh = (u + 0x7fffu + ((u >> 16) & 1u)) & 0xffff0000u;
    h = (unsigned short)(rh >> 16);
    float r = x - __uint_as_float(rh);
    unsigned v = __float_as_uint(r);
    l = (unsigned short)((v + 0x7fffu + ((v >> 16) & 1u)) >> 16);
}

// ---------------- prep kernels ----------------
__global__ void build_x0p_kernel(const float* __restrict__ pos, float* __restrict__ x0p) {
    int e = blockIdx.x * 256 + threadIdx.x;
    int p = e >> 4, k = e & 15;
    x0p[e] = (k < 3) ? pos[p * 3 + k] : 0.f;
}

__global__ void wuv_build_kernel(const float* __restrict__ W, float* __restrict__ Wuv,
                                 int d, int dpad, int od) {
    int tot = dpad * 2 * od;
    for (int e = blockIdx.x * 256 + threadIdx.x; e < tot; e += gridDim.x * 256) {
        int r = e / (2 * od), c = e - r * (2 * od);
        float v = 0.f;
        if (r < d) v = (c < od) ? (W[r * od + c] - W[(d + r) * od + c])
                                : W[(d + r) * od + (c - od)];
        Wuv[e] = v;
    }
}

__global__ void init_pool_kernel(unsigned* __restrict__ pool) {
    pool[blockIdx.x * 256 + threadIdx.x] = 0u;
}

template<int D>
__global__ void sqnorm_kernel(const float* __restrict__ X, float* __restrict__ n2) {
    int p = blockIdx.x * 256 + threadIdx.x;
    float s = 0.f;
    #pragma unroll
    for (int k = 0; k < D; k += 4) {
        float4 v = *(const float4*)&X[(size_t)p * D + k];
        s += v.x * v.x + v.y * v.y + v.z * v.z + v.w * v.w;
    }
    n2[p] = s;
}

// pack A = concat(x1,x2,x3) [16384 x 448] into bf16 hi/lo planes (k-major rows)
__global__ void packA_kernel(const float* __restrict__ x1, const float* __restrict__ x2,
                             const float* __restrict__ x3,
                             unsigned short* __restrict__ Ah, unsigned short* __restrict__ Al) {
    int e = blockIdx.x * 256 + threadIdx.x;       // < 16384*112
    int m = e / 112, c4 = (e - m * 112) * 4;
    float4 v;
    if (c4 < 64)       v = *(const float4*)&x1[(size_t)m * 64 + c4];
    else if (c4 < 192) v = *(const float4*)&x2[(size_t)m * 128 + (c4 - 64)];
    else               v = *(const float4*)&x3[(size_t)m * 256 + (c4 - 192)];
    ushort4 h, l;
    split_bf16(v.x, h.x, l.x); split_bf16(v.y, h.y, l.y);
    split_bf16(v.z, h.z, l.z); split_bf16(v.w, h.w, l.w);
    *(ushort4*)&Ah[(size_t)m * 448 + c4] = h;
    *(ushort4*)&Al[(size_t)m * 448 + c4] = l;
}

// pack Wf1^T [1024 x 448] into bf16 hi/lo planes (k-major rows)
__global__ void packB_kernel(const float* __restrict__ Wf1,
                             unsigned short* __restrict__ Bh, unsigned short* __restrict__ Bl) {
    int e = blockIdx.x * 256 + threadIdx.x;       // < 1024*112
    int n = e / 112, k4 = (e - n * 112) * 4;
    ushort4 h, l;
    float v0 = Wf1[(size_t)(k4 + 0) * 1024 + n];
    float v1 = Wf1[(size_t)(k4 + 1) * 1024 + n];
    float v2 = Wf1[(size_t)(k4 + 2) * 1024 + n];
    float v3 = Wf1[(size_t)(k4 + 3) * 1024 + n];
    split_bf16(v0, h.x, l.x); split_bf16(v1, h.y, l.y);
    split_bf16(v2, h.z, l.z); split_bf16(v3, h.w, l.w);
    *(ushort4*)&Bh[(size_t)n * 448 + k4] = h;
    *(ushort4*)&Bl[(size_t)n * 448 + k4] = l;
}

// ---------------- distance GEMM: Dm[z][r][c] = n2[c] - 2*dot(x_r, x_c) ----------------
template<int K>
__global__ __launch_bounds__(256)
void gemm_d_kernel(const float* __restrict__ X, const float* __restrict__ n2,
                   float* __restrict__ Dm, int batch0) {
    __shared__ float As[16][132];
    __shared__ float Bs[16][132];
    const int t = threadIdx.x;
    const int tx = t & 15, ty = t >> 4;
    const int bb = batch0 + blockIdx.z;
    const int rb = blockIdx.y * 128;
    const int cb = blockIdx.x * 128;
    const float* Xr = X + (size_t)(bb * PPB + rb) * K;
    const float* Xc = X + (size_t)(bb * PPB + cb) * K;

    float acc[8][8];
    #pragma unroll
    for (int i = 0; i < 8; ++i)
        #pragma unroll
        for (int j = 0; j < 8; ++j) acc[i][j] = 0.f;

    for (int kc = 0; kc < K; kc += 16) {
        __syncthreads();
        for (int e = t; e < 512; e += 256) {
            int m = e >> 2, kq = e & 3;
            float4 v = *(const float4*)&Xr[(size_t)m * K + kc + 4 * kq];
            As[4 * kq + 0][m] = v.x; As[4 * kq + 1][m] = v.y;
            As[4 * kq + 2][m] = v.z; As[4 * kq + 3][m] = v.w;
        }
        for (int e = t; e < 512; e += 256) {
            int m = e >> 2, kq = e & 3;
            float4 v = *(const float4*)&Xc[(size_t)m * K + kc + 4 * kq];
            Bs[4 * kq + 0][m] = v.x; Bs[4 * kq + 1][m] = v.y;
            Bs[4 * kq + 2][m] = v.z; Bs[4 * kq + 3][m] = v.w;
        }
        __syncthreads();
        #pragma unroll
        for (int kk = 0; kk < 16; ++kk) {
            float4 a0 = *(const float4*)&As[kk][8 * ty];
            float4 a1 = *(const float4*)&As[kk][8 * ty + 4];
            float4 b0 = *(const float4*)&Bs[kk][4 * tx];
            float4 b1 = *(const float4*)&Bs[kk][64 + 4 * tx];
            float av[8] = {a0.x, a0.y, a0.z, a0.w, a1.x, a1.y, a1.z, a1.w};
            float bv[8] = {b0.x, b0.y, b0.z, b0.w, b1.x, b1.y, b1.z, b1.w};
            #pragma unroll
            for (int i = 0; i < 8; ++i)
                #pragma unroll
                for (int j = 0; j < 8; ++j) acc[i][j] += av[i] * bv[j];
        }
    }
    const float* n2c = n2 + bb * PPB + cb;
    float nq0[4], nq1[4];
    #pragma unroll
    for (int j = 0; j < 4; ++j) { nq0[j] = n2c[4 * tx + j]; nq1[j] = n2c[64 + 4 * tx + j]; }
    float* Dz = Dm + (size_t)blockIdx.z * PPB * PPB;
    #pragma unroll
    for (int i = 0; i < 8; ++i) {
        int r = rb + 8 * ty + i;
        float4 v0 = {nq0[0] - 2.f * acc[i][0], nq0[1] - 2.f * acc[i][1],
                     nq0[2] - 2.f * acc[i][2], nq0[3] - 2.f * acc[i][3]};
        float4 v1 = {nq1[0] - 2.f * acc[i][4], nq1[1] - 2.f * acc[i][5],
                     nq1[2] - 2.f * acc[i][6], nq1[3] - 2.f * acc[i][7]};
        *(float4*)&Dz[(size_t)r * PPB + cb + 4 * tx]      = v0;
        *(float4*)&Dz[(size_t)r * PPB + cb + 64 + 4 * tx] = v1;
    }
}

// ---------------- top-20 select: one wave per row, candidates in registers ----------------
__global__ __launch_bounds__(256)
void knn_select_kernel(const float* __restrict__ Dm, int* __restrict__ idxout, int batch0) {
    const int lane = threadIdx.x & 63;
    const int wid  = threadIdx.x >> 6;
    const int rowg = blockIdx.x * 4 + wid;
    const int z  = rowg >> 11, rl = rowg & 2047;
    const float* drow = Dm + (size_t)z * PPB * PPB + (size_t)rl * PPB;

    float c[32];
    #pragma unroll
    for (int j = 0; j < 8; ++j) {
        float4 v = *(const float4*)&drow[j * 256 + 4 * lane];
        c[4 * j + 0] = v.x; c[4 * j + 1] = v.y; c[4 * j + 2] = v.z; c[4 * j + 3] = v.w;
    }
    float mv = c[0]; int mj = 0;
    #pragma unroll
    for (int j = 1; j < 32; ++j) if (c[j] < mv) { mv = c[j]; mj = j; }
    int mq = ((mj >> 2) << 8) + 4 * lane + (mj & 3);

    int keep = 0;
    for (int round = 0; round < KNN; ++round) {
        float rv = mv; int rq = mq;
        #pragma unroll
        for (int m = 1; m < 64; m <<= 1) {
            float ov = __shfl_xor(rv, m, 64);
            int   oq = __shfl_xor(rq, m, 64);
            if (ov < rv || (ov == rv && oq < rq)) { rv = ov; rq = oq; }
        }
        if (lane == round) keep = rq;
        if (rv == mv && rq == mq) {
            #pragma unroll
            for (int j = 0; j < 32; ++j) if (j == mj) c[j] = 3.4e38f;
            mv = c[0]; mj = 0;
            #pragma unroll
            for (int j = 1; j < 32; ++j) if (c[j] < mv) { mv = c[j]; mj = j; }
            mq = ((mj >> 2) << 8) + 4 * lane + (mj & 3);
        }
    }
    const int pbase = (batch0 + z) * PPB;
    if (lane < KNN)
        idxout[(size_t)(pbase + rl) * KNN + lane] = pbase + keep;
}

// ---------------- fp32 tiled GEMM 128x128, 8x8 micro-tile ----------------
__global__ __launch_bounds__(256)
void gemm_uv_kernel(const float* __restrict__ A, const float* __restrict__ B,
                    float* __restrict__ C, int M, int N, int K) {
    __shared__ float As[16][132];
    __shared__ float Bs[16][132];
    const int t = threadIdx.x;
    const int tx = t & 15, ty = t >> 4;
    const int nb = blockIdx.x * 128;
    const int mb = blockIdx.y * 128;
    float acc[8][8];
    #pragma unroll
    for (int i = 0; i < 8; ++i)
        #pragma unroll
        for (int j = 0; j < 8; ++j) acc[i][j] = 0.f;

    for (int kc = 0; kc < K; kc += 16) {
        __syncthreads();
        for (int e = t; e < 512; e += 256) {
            int m = e >> 2, kq = e & 3;
            float4 v = *(const float4*)&A[(size_t)(mb + m) * K + kc + 4 * kq];
            As[4 * kq + 0][m] = v.x; As[4 * kq + 1][m] = v.y;
            As[4 * kq + 2][m] = v.z; As[4 * kq + 3][m] = v.w;
        }
        for (int e = t; e < 512; e += 256) {
            int kr = e >> 5, nq = e & 31;
            *(float4*)&Bs[kr][4 * nq] = *(const float4*)&B[(size_t)(kc + kr) * N + nb + 4 * nq];
        }
        __syncthreads();
        #pragma unroll
        for (int kk = 0; kk < 16; ++kk) {
            float4 a0 = *(const float4*)&As[kk][8 * ty];
            float4 a1 = *(const float4*)&As[kk][8 * ty + 4];
            float4 b0 = *(const float4*)&Bs[kk][4 * tx];
            float4 b1 = *(const float4*)&Bs[kk][64 + 4 * tx];
            float av[8] = {a0.x, a0.y, a0.z, a0.w, a1.x, a1.y, a1.z, a1.w};
            float bv[8] = {b0.x, b0.y, b0.z, b0.w, b1.x, b1.y, b1.z, b1.w};
            #pragma unroll
            for (int i = 0; i < 8; ++i)
                #pragma unroll
                for (int j = 0; j < 8; ++j) acc[i][j] += av[i] * bv[j];
        }
    }
    #pragma unroll
    for (int i = 0; i < 8; ++i) {
        float4 v0 = {acc[i][0], acc[i][1], acc[i][2], acc[i][3]};
        float4 v1 = {acc[i][4], acc[i][5], acc[i][6], acc[i][7]};
        *(float4*)&C[(size_t)(mb + 8 * ty + i) * N + nb + 4 * tx] = v0;
        *(float4*)&C[(size_t)(mb + 8 * ty + i) * N + nb + 64 + 4 * tx] = v1;
    }
}

// ---------------- fc1: split-bf16 MFMA GEMM + fused max-pool ----------------
// C = A[16384x448] * B^T[1024x448]^T via 3 MFMA products (AhBh + AhBl + AlBh).
// 128x128 block tile, 4 waves in 2x2, each wave 64x64 (4x4 16x16x32 tiles).
__global__ __launch_bounds__(256)
void gemm_fc1_mfma(const unsigned short* __restrict__ Ah, const unsigned short* __restrict__ Al,
                   const unsigned short* __restrict__ Bh, const unsigned short* __restrict__ Bl,
                   const float* __restrict__ bias, unsigned* __restrict__ pool) {
    __shared__ unsigned short sA[2][128 * 40];   // [plane][m*40 + k], stride-40 pad
    __shared__ unsigned short sB[2][128 * 40];
    const int t = threadIdx.x;
    const int nb = blockIdx.x * 128, mb = blockIdx.y * 128;
    const int w = t >> 6, l = t & 63;
    const int wm = w & 1, wn = w >> 1;
    const int lm = l & 15, lq = l >> 4;

    f32x4 acc[4][4];
    #pragma unroll
    for (int i = 0; i < 4; ++i)
        #pragma unroll
        for (int j = 0; j < 4; ++j) acc[i][j] = (f32x4){0.f, 0.f, 0.f, 0.f};

    for (int kc = 0; kc < 448; kc += 32) {
        __syncthreads();
        #pragma unroll
        for (int i = 0; i < 8; ++i) {            // 2048 16B-chunks: A hi/lo, B hi/lo
            int c = t + i * 256;
            int idx = c & 511, m = idx >> 2, q = idx & 3;
            int plane = (c >> 9) & 1;
            const unsigned short* gsrc;
            unsigned short* ldst;
            if (c < 1024) {
                gsrc = (plane ? Al : Ah) + (size_t)(mb + m) * 448 + kc + q * 8;
                ldst = &sA[plane][m * 40 + q * 8];
            } else {
                gsrc = (plane ? Bl : Bh) + (size_t)(nb + m) * 448 + kc + q * 8;
                ldst = &sB[plane][m * 40 + q * 8];
            }
            *(uint4*)ldst = *(const uint4*)gsrc;
        }
        __syncthreads();
        b16x8 ah[4], al[4], bh[4], bl[4];
        #pragma unroll
        for (int mt = 0; mt < 4; ++mt) {
            int off = (wm * 64 + mt * 16 + lm) * 40 + lq * 8;
            ah[mt] = *(const b16x8*)&sA[0][off];
            al[mt] = *(const b16x8*)&sA[1][off];
        }
        #pragma unroll
        for (int nt = 0; nt < 4; ++nt) {
            int off = (wn * 64 + nt * 16 + lm) * 40 + lq * 8;
            bh[nt] = *(const b16x8*)&sB[0][off];
            bl[nt] = *(const b16x8*)&sB[1][off];
        }
        #pragma unroll
        for (int mt = 0; mt < 4; ++mt)
            #pragma unroll
            for (int nt = 0; nt < 4; ++nt) {
                acc[mt][nt] = __builtin_amdgcn_mfma_f32_16x16x32_bf16(ah[mt], bh[nt], acc[mt][nt], 0, 0, 0);
                acc[mt][nt] = __builtin_amdgcn_mfma_f32_16x16x32_bf16(ah[mt], bl[nt], acc[mt][nt], 0, 0, 0);
                acc[mt][nt] = __builtin_amdgcn_mfma_f32_16x16x32_bf16(al[mt], bh[nt], acc[mt][nt], 0, 0, 0);
            }
    }
    // epilogue: col-max over the wave's 64 rows, then atomicMax to per-batch pool
    const int batch = blockIdx.y >> 4;           // 128-row tile within one 2048 batch
    #pragma unroll
    for (int nt = 0; nt < 4; ++nt) {
        float m0 = -3.4e38f;
        #pragma unroll
        for (int mt = 0; mt < 4; ++mt)
            #pragma unroll
            for (int r = 0; r < 4; ++r) m0 = fmaxf(m0, acc[mt][nt][r]);
        m0 = fmaxf(m0, __shfl_xor(m0, 16, 64));  // combine row-quads (C row = lq*4+r)
        m0 = fmaxf(m0, __shfl_xor(m0, 32, 64));
        if (l < 16) {
            int col = nb + wn * 64 + nt * 16 + l;
            atomicMax(&pool[batch * 1024 + col], f2o(m0 + bias[col]));
        }
    }
}

// ---------------- edge-conv aggregate: x[p] = U[p] + b + max_k V[idx] ----------------
__global__ void agg_kernel(const float* __restrict__ UV, const int* __restrict__ idx,
                           const float* __restrict__ bias, float* __restrict__ xo, int od) {
    const int p = blockIdx.x, c = threadIdx.x;
    const float u = UV[(size_t)p * 2 * od + c];
    float m = -3.4e38f;
    #pragma unroll
    for (int k = 0; k < KNN; ++k) {
        int j = idx[p * KNN + k];
        m = fmaxf(m, UV[(size_t)j * 2 * od + od + c]);
    }
    xo[(size_t)p * od + c] = u + bias[c] + m;
}

// ---------------- head: Lin + BN + ReLU (all 8 rows per block) ----------------
template<int IND, bool UNMAP>
__global__ __launch_bounds__(256)
void head_bn_kernel(const float* __restrict__ in, const float* __restrict__ W,
                    const float* __restrict__ bias, const float* __restrict__ g,
                    const float* __restrict__ be, float* __restrict__ out, int OD) {
    __shared__ float xs[8 * IND];
    __shared__ float sc[8][33];
    const int t = threadIdx.x;
    for (int e = t; e < 8 * IND; e += 256)
        xs[e] = UNMAP ? o2f(((const unsigned*)in)[e]) : in[e];
    __syncthreads();
    const int c = t & 31, r = t >> 5;
    const int cb = blockIdx.x * 32;
    float a = bias[cb + c];
    const float* xr = &xs[r * IND];
    #pragma unroll 4
    for (int k = 0; k < IND; ++k) a += xr[k] * W[(size_t)k * OD + cb + c];
    sc[r][c] = a;
    __syncthreads();
    float mu = 0.f;
    #pragma unroll
    for (int y = 0; y < 8; ++y) mu += sc[y][c];
    mu *= 0.125f;
    float vr = 0.f;
    #pragma unroll
    for (int y = 0; y < 8; ++y) { float d = sc[y][c] - mu; vr += d * d; }
    vr *= 0.125f;
    float o = g[cb + c] * (a - mu) * rsqrtf(vr + 1e-5f) + be[cb + c];
    out[r * OD + cb + c] = fmaxf(o, 0.f);
}

// final Lin [8,256]@[256,23] + log_softmax
__global__ void head3_kernel(const float* __restrict__ x, const float* __restrict__ W,
                             const float* __restrict__ b, float* __restrict__ out) {
    __shared__ float xs[8 * 256];
    __shared__ float lg[8][23];
    __shared__ float red[8][2];
    const int t = threadIdx.x;
    for (int e = t; e < 2048; e += 256) xs[e] = x[e];
    __syncthreads();
    if (t < 184) {
        int r = t / 23, c = t - 23 * r;
        float a = b[c];
        for (int k = 0; k < 256; ++k) a += xs[r * 256 + k] * W[k * 23 + c];
        lg[r][c] = a;
    }
    __syncthreads();
    if (t < 8) {
        float mx = -3.4e38f;
        for (int c = 0; c < 23; ++c) mx = fmaxf(mx, lg[t][c]);
        float s = 0.f;
        for (int c = 0; c < 23; ++c) s += expf(lg[t][c] - mx);
        red[t][0] = mx; red[t][1] = logf(s);
    }
    __syncthreads();
    if (t < 184) {
        int r = t / 23, c = t - 23 * r;
        out[t] = lg[r][c] - red[r][0] - red[r][1];
    }
}

// ---------------- launcher ----------------
extern "C" void kernel_launch(void* const* d_in, const int* in_sizes, int n_in,
                              void* d_out, int out_size, void* d_ws, size_t ws_size,
                              hipStream_t stream) {
    (void)in_sizes; (void)n_in; (void)out_size; (void)ws_size;
    const float* pos = (const float*)d_in[0];
    const float* W1  = (const float*)d_in[2];  const float* b1  = (const float*)d_in[3];
    const float* W2  = (const float*)d_in[4];  const float* b2  = (const float*)d_in[5];
    const float* W3  = (const float*)d_in[6];  const float* b3  = (const float*)d_in[7];
    const float* Wf1 = (const float*)d_in[8];  const float* bf1 = (const float*)d_in[9];
    const float* Wa  = (const float*)d_in[10]; const float* ba  = (const float*)d_in[11];
    const float* ga  = (const float*)d_in[12]; const float* bea = (const float*)d_in[13];
    const float* Wb  = (const float*)d_in[14]; const float* bb  = (const float*)d_in[15];
    const float* gb  = (const float*)d_in[16]; const float* beb = (const float*)d_in[17];
    const float* Wc  = (const float*)d_in[18]; const float* bc  = (const float*)d_in[19];

    char* ws = (char*)d_ws;
    float*    x0p  = (float*)(ws + OFF_X0P);
    float*    n2   = (float*)(ws + OFF_N2);
    int*      idx  = (int*)(ws + OFF_IDX);
    float*    wuv1 = (float*)(ws + OFF_WUV1);
    float*    wuv2 = (float*)(ws + OFF_WUV2);
    float*    wuv3 = (float*)(ws + OFF_WUV3);
    unsigned* pool = (unsigned*)(ws + OFF_POOL);
    float*    C1   = (float*)(ws + OFF_C1);
    float*    C2   = (float*)(ws + OFF_C2);
    float*    x1   = (float*)(ws + OFF_X1);
    float*    x2   = (float*)(ws + OFF_X2);
    float*    x3   = (float*)(ws + OFF_X3);
    float*    UV   = (float*)(ws + OFF_UV);
    float*    Dm   = (float*)(ws + OFF_UV);
    unsigned short* Apkh = (unsigned short*)(ws + OFF_APKH);
    unsigned short* Apkl = (unsigned short*)(ws + OFF_APKL);
    unsigned short* Bth  = (unsigned short*)(ws + OFF_BTH);
    unsigned short* Btl  = (unsigned short*)(ws + OFF_BTL);

    // prep
    build_x0p_kernel<<<1024, 256, 0, stream>>>(pos, x0p);
    wuv_build_kernel<<<8,   256, 0, stream>>>(W1, wuv1, 3,   16,  64);
    wuv_build_kernel<<<64,  256, 0, stream>>>(W2, wuv2, 64,  64,  128);
    wuv_build_kernel<<<256, 256, 0, stream>>>(W3, wuv3, 128, 128, 256);
    init_pool_kernel<<<32,  256, 0, stream>>>(pool);

    // edge conv 1 (d=3 padded to 16 -> 64)
    sqnorm_kernel<16><<<64, 256, 0, stream>>>(x0p, n2);
    for (int r0 = 0; r0 < 8; r0 += 2) {
        gemm_d_kernel<16><<<dim3(16, 16, 2), 256, 0, stream>>>(x0p, n2, Dm, r0);
        knn_select_kernel<<<1024, 256, 0, stream>>>(Dm, idx, r0);
    }
    gemm_uv_kernel<<<dim3(1, 128), 256, 0, stream>>>(x0p, wuv1, UV, NPTS, 128, 16);
    agg_kernel<<<NPTS, 64, 0, stream>>>(UV, idx, b1, x1, 64);

    // edge conv 2 (64 -> 128)
    sqnorm_kernel<64><<<64, 256, 0, stream>>>(x1, n2);
    for (int r0 = 0; r0 < 8; r0 += 2) {
        gemm_d_kernel<64><<<dim3(16, 16, 2), 256, 0, stream>>>(x1, n2, Dm, r0);
        knn_select_kernel<<<1024, 256, 0, stream>>>(Dm, idx, r0);
    }
    gemm_uv_kernel<<<dim3(2, 128), 256, 0, stream>>>(x1, wuv2, UV, NPTS, 256, 64);
    agg_kernel<<<NPTS, 128, 0, stream>>>(UV, idx, b2, x2, 128);

    // edge conv 3 (128 -> 256)
    sqnorm_kernel<128><<<64, 256, 0, stream>>>(x2, n2);
    for (int r0 = 0; r0 < 8; r0 += 2) {
        gemm_d_kernel<128><<<dim3(16, 16, 2), 256, 0, stream>>>(x2, n2, Dm, r0);
        knn_select_kernel<<<1024, 256, 0, stream>>>(Dm, idx, r0);
    }
    gemm_uv_kernel<<<dim3(4, 128), 256, 0, stream>>>(x2, wuv3, UV, NPTS, 512, 128);
    agg_kernel<<<NPTS, 256, 0, stream>>>(UV, idx, b3, x3, 256);

    // fc1: pack operands (UV/Dm and x0p/idx regions are dead now), MFMA + max-pool
    packA_kernel<<<7168, 256, 0, stream>>>(x1, x2, x3, Apkh, Apkl);
    packB_kernel<<<448,  256, 0, stream>>>(Wf1, Bth, Btl);
    gemm_fc1_mfma<<<dim3(8, 128), 256, 0, stream>>>(Apkh, Apkl, Bth, Btl, bf1, pool);

    // head
    head_bn_kernel<1024, true ><<<16, 256, 0, stream>>>((const float*)pool, Wa, ba, ga, bea, C1, 512);
    head_bn_kernel<512,  false><<<8,  256, 0, stream>>>(C1, Wb, bb, gb, beb, C2, 256);
    head3_kernel<<<1, 256, 0, stream>>>(C2, Wc, bc, (float*)d_out);
}

// Round 5
// 971.386 us; speedup vs baseline: 2.3850x; 1.1841x over previous
//
#include <hip/hip_runtime.h>
#include <math.h>

#define NPTS 16384
#define PPB  2048
#define KNN  20

// ---------------- workspace layout (bytes), total 64 MiB ----------------
#define OFF_X0P   0u           // 16384*16*4 (dead after stage-1; reused by Bt planes)
#define OFF_N2    1048576u
#define OFF_IDX   1114112u     // 16384*20*4
#define OFF_WUV1  2424832u
#define OFF_WUV2  2433024u
#define OFF_WUV3  2498560u
#define OFF_POOL  2760704u     // 8192*4
#define OFF_C1    2793472u
#define OFF_C2    2809856u
#define OFF_X1    4194304u     // 16384*64*4  (dead after packA; reused by head partials)
#define OFF_P1    4194304u     // 8*8*512*4   = 128 KB
#define OFF_P2    4325376u     // 4*8*256*4   = 32 KB
#define OFF_X2    8388608u     // 16384*128*4
#define OFF_X3    16777216u    // 16384*256*4 (free until agg-3: holds kNN bf16 planes)
#define OFF_XPH   16777216u    // X hi-plane (<= 4 MB)
#define OFF_XPL   25165824u    // X lo-plane (<= 4 MB)
#define OFF_UV    33554432u    // 32 MiB: dist scratch -> U|V -> packed-A planes
#define OFF_APKH  33554432u
#define OFF_APKL  48234496u
#define OFF_BTH   0u
#define OFF_BTL   917504u

typedef __attribute__((ext_vector_type(8))) short b16x8;
typedef __attribute__((ext_vector_type(4))) float f32x4;

__device__ __forceinline__ unsigned f2o(float f) {
    unsigned u = __float_as_uint(f);
    return (u & 0x80000000u) ? ~u : (u | 0x80000000u);
}
__device__ __forceinline__ float o2f(unsigned u) {
    return (u & 0x80000000u) ? __uint_as_float(u & 0x7fffffffu) : __uint_as_float(~u);
}

// split fp32 -> (hi, lo) bf16 pair, RNE both; x ~= hi + lo to ~2^-18 rel
__device__ __forceinline__ void split_bf16(float x, unsigned short& h, unsigned short& l) {
    unsigned u = __float_as_uint(x);
    unsigned rh = (u + 0x7fffu + ((u >> 16) & 1u)) & 0xffff0000u;
    h = (unsigned short)(rh >> 16);
    float r = x - __uint_as_float(rh);
    unsigned v = __float_as_uint(r);
    l = (unsigned short)((v + 0x7fffu + ((v >> 16) & 1u)) >> 16);
}

// ---------------- prep kernels ----------------
__global__ void build_x0p_kernel(const float* __restrict__ pos, float* __restrict__ x0p) {
    int e = blockIdx.x * 256 + threadIdx.x;
    int p = e >> 4, k = e & 15;
    x0p[e] = (k < 3) ? pos[p * 3 + k] : 0.f;
}

__global__ void wuv_build_kernel(const float* __restrict__ W, float* __restrict__ Wuv,
                                 int d, int dpad, int od) {
    int tot = dpad * 2 * od;
    for (int e = blockIdx.x * 256 + threadIdx.x; e < tot; e += gridDim.x * 256) {
        int r = e / (2 * od), c = e - r * (2 * od);
        float v = 0.f;
        if (r < d) v = (c < od) ? (W[r * od + c] - W[(d + r) * od + c])
                                : W[(d + r) * od + (c - od)];
        Wuv[e] = v;
    }
}

__global__ void init_pool_kernel(unsigned* __restrict__ pool) {
    pool[blockIdx.x * 256 + threadIdx.x] = 0u;
}

template<int D>
__global__ void sqnorm_kernel(const float* __restrict__ X, float* __restrict__ n2) {
    int p = blockIdx.x * 256 + threadIdx.x;
    float s = 0.f;
    #pragma unroll
    for (int k = 0; k < D; k += 4) {
        float4 v = *(const float4*)&X[(size_t)p * D + k];
        s += v.x * v.x + v.y * v.y + v.z * v.z + v.w * v.w;
    }
    n2[p] = s;
}

// pack X [16384 x K] fp32 -> bf16 hi/lo planes
__global__ void packX_kernel(const float* __restrict__ X,
                             unsigned short* __restrict__ Xh, unsigned short* __restrict__ Xl) {
    int e = blockIdx.x * 256 + threadIdx.x;
    float4 v = *(const float4*)&X[4 * (size_t)e];
    ushort4 h, l;
    split_bf16(v.x, h.x, l.x); split_bf16(v.y, h.y, l.y);
    split_bf16(v.z, h.z, l.z); split_bf16(v.w, h.w, l.w);
    *(ushort4*)&Xh[4 * (size_t)e] = h;
    *(ushort4*)&Xl[4 * (size_t)e] = l;
}

// pack A = concat(x1,x2,x3) [16384 x 448] into bf16 hi/lo planes
__global__ void packA_kernel(const float* __restrict__ x1, const float* __restrict__ x2,
                             const float* __restrict__ x3,
                             unsigned short* __restrict__ Ah, unsigned short* __restrict__ Al) {
    int e = blockIdx.x * 256 + threadIdx.x;
    int m = e / 112, c4 = (e - m * 112) * 4;
    float4 v;
    if (c4 < 64)       v = *(const float4*)&x1[(size_t)m * 64 + c4];
    else if (c4 < 192) v = *(const float4*)&x2[(size_t)m * 128 + (c4 - 64)];
    else               v = *(const float4*)&x3[(size_t)m * 256 + (c4 - 192)];
    ushort4 h, l;
    split_bf16(v.x, h.x, l.x); split_bf16(v.y, h.y, l.y);
    split_bf16(v.z, h.z, l.z); split_bf16(v.w, h.w, l.w);
    *(ushort4*)&Ah[(size_t)m * 448 + c4] = h;
    *(ushort4*)&Al[(size_t)m * 448 + c4] = l;
}

// pack Wf1^T [1024 x 448] into bf16 hi/lo planes
__global__ void packB_kernel(const float* __restrict__ Wf1,
                             unsigned short* __restrict__ Bh, unsigned short* __restrict__ Bl) {
    int e = blockIdx.x * 256 + threadIdx.x;
    int n = e / 112, k4 = (e - n * 112) * 4;
    ushort4 h, l;
    float v0 = Wf1[(size_t)(k4 + 0) * 1024 + n];
    float v1 = Wf1[(size_t)(k4 + 1) * 1024 + n];
    float v2 = Wf1[(size_t)(k4 + 2) * 1024 + n];
    float v3 = Wf1[(size_t)(k4 + 3) * 1024 + n];
    split_bf16(v0, h.x, l.x); split_bf16(v1, h.y, l.y);
    split_bf16(v2, h.z, l.z); split_bf16(v3, h.w, l.w);
    *(ushort4*)&Bh[(size_t)n * 448 + k4] = h;
    *(ushort4*)&Bl[(size_t)n * 448 + k4] = l;
}

// ---------------- stage-1 distance GEMM (fp32, K=16) ----------------
template<int K>
__global__ __launch_bounds__(256)
void gemm_d_kernel(const float* __restrict__ X, const float* __restrict__ n2,
                   float* __restrict__ Dm, int batch0) {
    __shared__ float As[16][132];
    __shared__ float Bs[16][132];
    const int t = threadIdx.x;
    const int tx = t & 15, ty = t >> 4;
    const int bb = batch0 + blockIdx.z;
    const int rb = blockIdx.y * 128;
    const int cb = blockIdx.x * 128;
    const float* Xr = X + (size_t)(bb * PPB + rb) * K;
    const float* Xc = X + (size_t)(bb * PPB + cb) * K;

    float acc[8][8];
    #pragma unroll
    for (int i = 0; i < 8; ++i)
        #pragma unroll
        for (int j = 0; j < 8; ++j) acc[i][j] = 0.f;

    for (int kc = 0; kc < K; kc += 16) {
        __syncthreads();
        for (int e = t; e < 512; e += 256) {
            int m = e >> 2, kq = e & 3;
            float4 v = *(const float4*)&Xr[(size_t)m * K + kc + 4 * kq];
            As[4 * kq + 0][m] = v.x; As[4 * kq + 1][m] = v.y;
            As[4 * kq + 2][m] = v.z; As[4 * kq + 3][m] = v.w;
        }
        for (int e = t; e < 512; e += 256) {
            int m = e >> 2, kq = e & 3;
            float4 v = *(const float4*)&Xc[(size_t)m * K + kc + 4 * kq];
            Bs[4 * kq + 0][m] = v.x; Bs[4 * kq + 1][m] = v.y;
            Bs[4 * kq + 2][m] = v.z; Bs[4 * kq + 3][m] = v.w;
        }
        __syncthreads();
        #pragma unroll
        for (int kk = 0; kk < 16; ++kk) {
            float4 a0 = *(const float4*)&As[kk][8 * ty];
            float4 a1 = *(const float4*)&As[kk][8 * ty + 4];
            float4 b0 = *(const float4*)&Bs[kk][4 * tx];
            float4 b1 = *(const float4*)&Bs[kk][64 + 4 * tx];
            float av[8] = {a0.x, a0.y, a0.z, a0.w, a1.x, a1.y, a1.z, a1.w};
            float bv[8] = {b0.x, b0.y, b0.z, b0.w, b1.x, b1.y, b1.z, b1.w};
            #pragma unroll
            for (int i = 0; i < 8; ++i)
                #pragma unroll
                for (int j = 0; j < 8; ++j) acc[i][j] += av[i] * bv[j];
        }
    }
    const float* n2c = n2 + bb * PPB + cb;
    float nq0[4], nq1[4];
    #pragma unroll
    for (int j = 0; j < 4; ++j) { nq0[j] = n2c[4 * tx + j]; nq1[j] = n2c[64 + 4 * tx + j]; }
    float* Dz = Dm + (size_t)blockIdx.z * PPB * PPB;
    #pragma unroll
    for (int i = 0; i < 8; ++i) {
        int r = rb + 8 * ty + i;
        float4 v0 = {nq0[0] - 2.f * acc[i][0], nq0[1] - 2.f * acc[i][1],
                     nq0[2] - 2.f * acc[i][2], nq0[3] - 2.f * acc[i][3]};
        float4 v1 = {nq1[0] - 2.f * acc[i][4], nq1[1] - 2.f * acc[i][5],
                     nq1[2] - 2.f * acc[i][6], nq1[3] - 2.f * acc[i][7]};
        *(float4*)&Dz[(size_t)r * PPB + cb + 4 * tx]      = v0;
        *(float4*)&Dz[(size_t)r * PPB + cb + 64 + 4 * tx] = v1;
    }
}

// ---------------- stage-2/3 distance GEMM: split-bf16 MFMA ----------------
// Dm[z][r][c] = n2[c] - 2*(AhBh + AhBl + AlBh). 128x128 tile, 4 waves 2x2.
template<int K>
__global__ __launch_bounds__(256)
void gemm_dm_kernel(const unsigned short* __restrict__ Xh, const unsigned short* __restrict__ Xl,
                    const float* __restrict__ n2, float* __restrict__ Dm, int batch0) {
    __shared__ unsigned short sA[2][128 * 40];
    __shared__ unsigned short sB[2][128 * 40];
    const int t = threadIdx.x;
    const int bb = batch0 + blockIdx.z;
    const int rb = blockIdx.y * 128, cb = blockIdx.x * 128;
    const size_t rowA = (size_t)(bb * PPB + rb);
    const size_t rowB = (size_t)(bb * PPB + cb);
    const int w = t >> 6, l = t & 63;
    const int wm = w & 1, wn = w >> 1;
    const int lm = l & 15, lq = l >> 4;

    f32x4 acc[4][4];
    #pragma unroll
    for (int i = 0; i < 4; ++i)
        #pragma unroll
        for (int j = 0; j < 4; ++j) acc[i][j] = (f32x4){0.f, 0.f, 0.f, 0.f};

    for (int kc = 0; kc < K; kc += 32) {
        __syncthreads();
        #pragma unroll
        for (int i = 0; i < 8; ++i) {
            int c = t + i * 256;
            int idx = c & 511, m = idx >> 2, q = idx & 3;
            int plane = (c >> 9) & 1;
            const unsigned short* gsrc;
            unsigned short* ldst;
            if (c < 1024) {
                gsrc = (plane ? Xl : Xh) + (rowA + m) * K + kc + q * 8;
                ldst = &sA[plane][m * 40 + q * 8];
            } else {
                gsrc = (plane ? Xl : Xh) + (rowB + m) * K + kc + q * 8;
                ldst = &sB[plane][m * 40 + q * 8];
            }
            *(uint4*)ldst = *(const uint4*)gsrc;
        }
        __syncthreads();
        b16x8 ah[4], al[4], bh[4], bl[4];
        #pragma unroll
        for (int mt = 0; mt < 4; ++mt) {
            int off = (wm * 64 + mt * 16 + lm) * 40 + lq * 8;
            ah[mt] = *(const b16x8*)&sA[0][off];
            al[mt] = *(const b16x8*)&sA[1][off];
        }
        #pragma unroll
        for (int nt = 0; nt < 4; ++nt) {
            int off = (wn * 64 + nt * 16 + lm) * 40 + lq * 8;
            bh[nt] = *(const b16x8*)&sB[0][off];
            bl[nt] = *(const b16x8*)&sB[1][off];
        }
        #pragma unroll
        for (int mt = 0; mt < 4; ++mt)
            #pragma unroll
            for (int nt = 0; nt < 4; ++nt) {
                acc[mt][nt] = __builtin_amdgcn_mfma_f32_16x16x32_bf16(ah[mt], bh[nt], acc[mt][nt], 0, 0, 0);
                acc[mt][nt] = __builtin_amdgcn_mfma_f32_16x16x32_bf16(ah[mt], bl[nt], acc[mt][nt], 0, 0, 0);
                acc[mt][nt] = __builtin_amdgcn_mfma_f32_16x16x32_bf16(al[mt], bh[nt], acc[mt][nt], 0, 0, 0);
            }
    }
    const float* n2c = n2 + bb * PPB + cb;
    float* Dz = Dm + (size_t)blockIdx.z * PPB * PPB;
    #pragma unroll
    for (int nt = 0; nt < 4; ++nt) {
        int col = wn * 64 + nt * 16 + lm;
        float nv = n2c[col];
        #pragma unroll
        for (int mt = 0; mt < 4; ++mt) {
            int row = rb + wm * 64 + mt * 16 + lq * 4;
            #pragma unroll
            for (int r = 0; r < 4; ++r)
                Dz[(size_t)(row + r) * PPB + cb + col] = nv - 2.f * acc[mt][nt][r];
        }
    }
}

// ---------------- top-20 select: one wave per row, candidates in registers ----------------
__global__ __launch_bounds__(256)
void knn_select_kernel(const float* __restrict__ Dm, int* __restrict__ idxout, int batch0) {
    const int lane = threadIdx.x & 63;
    const int wid  = threadIdx.x >> 6;
    const int rowg = blockIdx.x * 4 + wid;
    const int z  = rowg >> 11, rl = rowg & 2047;
    const float* drow = Dm + (size_t)z * PPB * PPB + (size_t)rl * PPB;

    float c[32];
    #pragma unroll
    for (int j = 0; j < 8; ++j) {
        float4 v = *(const float4*)&drow[j * 256 + 4 * lane];
        c[4 * j + 0] = v.x; c[4 * j + 1] = v.y; c[4 * j + 2] = v.z; c[4 * j + 3] = v.w;
    }
    float mv = c[0]; int mj = 0;
    #pragma unroll
    for (int j = 1; j < 32; ++j) if (c[j] < mv) { mv = c[j]; mj = j; }
    int mq = ((mj >> 2) << 8) + 4 * lane + (mj & 3);

    int keep = 0;
    for (int round = 0; round < KNN; ++round) {
        float rv = mv; int rq = mq;
        #pragma unroll
        for (int m = 1; m < 64; m <<= 1) {
            float ov = __shfl_xor(rv, m, 64);
            int   oq = __shfl_xor(rq, m, 64);
            if (ov < rv || (ov == rv && oq < rq)) { rv = ov; rq = oq; }
        }
        if (lane == round) keep = rq;
        if (rv == mv && rq == mq) {
            #pragma unroll
            for (int j = 0; j < 32; ++j) if (j == mj) c[j] = 3.4e38f;
            mv = c[0]; mj = 0;
            #pragma unroll
            for (int j = 1; j < 32; ++j) if (c[j] < mv) { mv = c[j]; mj = j; }
            mq = ((mj >> 2) << 8) + 4 * lane + (mj & 3);
        }
    }
    const int pbase = (batch0 + z) * PPB;
    if (lane < KNN)
        idxout[(size_t)(pbase + rl) * KNN + lane] = pbase + keep;
}

// ---------------- fp32 tiled GEMM 128x128 (UV projection) ----------------
__global__ __launch_bounds__(256)
void gemm_uv_kernel(const float* __restrict__ A, const float* __restrict__ B,
                    float* __restrict__ C, int M, int N, int K) {
    __shared__ float As[16][132];
    __shared__ float Bs[16][132];
    const int t = threadIdx.x;
    const int tx = t & 15, ty = t >> 4;
    const int nb = blockIdx.x * 128;
    const int mb = blockIdx.y * 128;
    float acc[8][8];
    #pragma unroll
    for (int i = 0; i < 8; ++i)
        #pragma unroll
        for (int j = 0; j < 8; ++j) acc[i][j] = 0.f;

    for (int kc = 0; kc < K; kc += 16) {
        __syncthreads();
        for (int e = t; e < 512; e += 256) {
            int m = e >> 2, kq = e & 3;
            float4 v = *(const float4*)&A[(size_t)(mb + m) * K + kc + 4 * kq];
            As[4 * kq + 0][m] = v.x; As[4 * kq + 1][m] = v.y;
            As[4 * kq + 2][m] = v.z; As[4 * kq + 3][m] = v.w;
        }
        for (int e = t; e < 512; e += 256) {
            int kr = e >> 5, nq = e & 31;
            *(float4*)&Bs[kr][4 * nq] = *(const float4*)&B[(size_t)(kc + kr) * N + nb + 4 * nq];
        }
        __syncthreads();
        #pragma unroll
        for (int kk = 0; kk < 16; ++kk) {
            float4 a0 = *(const float4*)&As[kk][8 * ty];
            float4 a1 = *(const float4*)&As[kk][8 * ty + 4];
            float4 b0 = *(const float4*)&Bs[kk][4 * tx];
            float4 b1 = *(const float4*)&Bs[kk][64 + 4 * tx];
            float av[8] = {a0.x, a0.y, a0.z, a0.w, a1.x, a1.y, a1.z, a1.w};
            float bv[8] = {b0.x, b0.y, b0.z, b0.w, b1.x, b1.y, b1.z, b1.w};
            #pragma unroll
            for (int i = 0; i < 8; ++i)
                #pragma unroll
                for (int j = 0; j < 8; ++j) acc[i][j] += av[i] * bv[j];
        }
    }
    #pragma unroll
    for (int i = 0; i < 8; ++i) {
        float4 v0 = {acc[i][0], acc[i][1], acc[i][2], acc[i][3]};
        float4 v1 = {acc[i][4], acc[i][5], acc[i][6], acc[i][7]};
        *(float4*)&C[(size_t)(mb + 8 * ty + i) * N + nb + 4 * tx] = v0;
        *(float4*)&C[(size_t)(mb + 8 * ty + i) * N + nb + 64 + 4 * tx] = v1;
    }
}

// ---------------- fc1: split-bf16 MFMA GEMM + fused max-pool ----------------
__global__ __launch_bounds__(256)
void gemm_fc1_mfma(const unsigned short* __restrict__ Ah, const unsigned short* __restrict__ Al,
                   const unsigned short* __restrict__ Bh, const unsigned short* __restrict__ Bl,
                   const float* __restrict__ bias, unsigned* __restrict__ pool) {
    __shared__ unsigned short sA[2][128 * 40];
    __shared__ unsigned short sB[2][128 * 40];
    const int t = threadIdx.x;
    const int nb = blockIdx.x * 128, mb = blockIdx.y * 128;
    const int w = t >> 6, l = t & 63;
    const int wm = w & 1, wn = w >> 1;
    const int lm = l & 15, lq = l >> 4;

    f32x4 acc[4][4];
    #pragma unroll
    for (int i = 0; i < 4; ++i)
        #pragma unroll
        for (int j = 0; j < 4; ++j) acc[i][j] = (f32x4){0.f, 0.f, 0.f, 0.f};

    for (int kc = 0; kc < 448; kc += 32) {
        __syncthreads();
        #pragma unroll
        for (int i = 0; i < 8; ++i) {
            int c = t + i * 256;
            int idx = c & 511, m = idx >> 2, q = idx & 3;
            int plane = (c >> 9) & 1;
            const unsigned short* gsrc;
            unsigned short* ldst;
            if (c < 1024) {
                gsrc = (plane ? Al : Ah) + (size_t)(mb + m) * 448 + kc + q * 8;
                ldst = &sA[plane][m * 40 + q * 8];
            } else {
                gsrc = (plane ? Bl : Bh) + (size_t)(nb + m) * 448 + kc + q * 8;
                ldst = &sB[plane][m * 40 + q * 8];
            }
            *(uint4*)ldst = *(const uint4*)gsrc;
        }
        __syncthreads();
        b16x8 ah[4], al[4], bh[4], bl[4];
        #pragma unroll
        for (int mt = 0; mt < 4; ++mt) {
            int off = (wm * 64 + mt * 16 + lm) * 40 + lq * 8;
            ah[mt] = *(const b16x8*)&sA[0][off];
            al[mt] = *(const b16x8*)&sA[1][off];
        }
        #pragma unroll
        for (int nt = 0; nt < 4; ++nt) {
            int off = (wn * 64 + nt * 16 + lm) * 40 + lq * 8;
            bh[nt] = *(const b16x8*)&sB[0][off];
            bl[nt] = *(const b16x8*)&sB[1][off];
        }
        #pragma unroll
        for (int mt = 0; mt < 4; ++mt)
            #pragma unroll
            for (int nt = 0; nt < 4; ++nt) {
                acc[mt][nt] = __builtin_amdgcn_mfma_f32_16x16x32_bf16(ah[mt], bh[nt], acc[mt][nt], 0, 0, 0);
                acc[mt][nt] = __builtin_amdgcn_mfma_f32_16x16x32_bf16(ah[mt], bl[nt], acc[mt][nt], 0, 0, 0);
                acc[mt][nt] = __builtin_amdgcn_mfma_f32_16x16x32_bf16(al[mt], bh[nt], acc[mt][nt], 0, 0, 0);
            }
    }
    const int batch = blockIdx.y >> 4;
    #pragma unroll
    for (int nt = 0; nt < 4; ++nt) {
        float m0 = -3.4e38f;
        #pragma unroll
        for (int mt = 0; mt < 4; ++mt)
            #pragma unroll
            for (int r = 0; r < 4; ++r) m0 = fmaxf(m0, acc[mt][nt][r]);
        m0 = fmaxf(m0, __shfl_xor(m0, 16, 64));
        m0 = fmaxf(m0, __shfl_xor(m0, 32, 64));
        if (l < 16) {
            int col = nb + wn * 64 + nt * 16 + l;
            atomicMax(&pool[batch * 1024 + col], f2o(m0 + bias[col]));
        }
    }
}

// ---------------- edge-conv aggregate ----------------
__global__ void agg_kernel(const float* __restrict__ UV, const int* __restrict__ idx,
                           const float* __restrict__ bias, float* __restrict__ xo, int od) {
    const int p = blockIdx.x, c = threadIdx.x;
    const float u = UV[(size_t)p * 2 * od + c];
    float m = -3.4e38f;
    #pragma unroll
    for (int k = 0; k < KNN; ++k) {
        int j = idx[p * KNN + k];
        m = fmaxf(m, UV[(size_t)j * 2 * od + od + c]);
    }
    xo[(size_t)p * od + c] = u + bias[c] + m;
}

// ---------------- head: split-k GEMM + per-column BN ----------------
// grid (OD/64, KSEG); 256 thr = 64 cols x 4 row-pairs; KL = IND/KSEG k per block
template<int IND, int OD, int KSEG, bool UNMAP>
__global__ __launch_bounds__(256)
void head_gemm_k(const float* __restrict__ in, const float* __restrict__ W,
                 float* __restrict__ P) {
    const int KL = IND / KSEG;
    __shared__ float xs[8][IND / KSEG];
    const int t = threadIdx.x;
    const int kb = blockIdx.y * KL;
    const int cb = blockIdx.x * 64;
    for (int e = t; e < 8 * KL; e += 256) {
        int r = e / KL, k = e - r * KL;
        if (UNMAP) xs[r][k] = o2f(((const unsigned*)in)[r * IND + kb + k]);
        else       xs[r][k] = in[r * IND + kb + k];
    }
    __syncthreads();
    const int c = t & 63, rr = t >> 6;
    float a0 = 0.f, a1 = 0.f;
    #pragma unroll 4
    for (int k = 0; k < KL; ++k) {
        float wv = W[(size_t)(kb + k) * OD + cb + c];
        a0 += xs[2 * rr][k] * wv;
        a1 += xs[2 * rr + 1][k] * wv;
    }
    P[(size_t)(blockIdx.y * 8 + 2 * rr) * OD + cb + c]     = a0;
    P[(size_t)(blockIdx.y * 8 + 2 * rr + 1) * OD + cb + c] = a1;
}

// one thread per column: sum KSEG partials for all 8 rows, BN + ReLU
template<int OD, int KSEG>
__global__ void head_bn2(const float* __restrict__ P, const float* __restrict__ bias,
                         const float* __restrict__ g, const float* __restrict__ be,
                         float* __restrict__ out) {
    const int c = blockIdx.x * 256 + threadIdx.x;
    float a[8];
    #pragma unroll
    for (int r = 0; r < 8; ++r) {
        float s = bias[c];
        #pragma unroll
        for (int ks = 0; ks < KSEG; ++ks) s += P[(size_t)(ks * 8 + r) * OD + c];
        a[r] = s;
    }
    float mu = 0.f;
    #pragma unroll
    for (int r = 0; r < 8; ++r) mu += a[r];
    mu *= 0.125f;
    float vr = 0.f;
    #pragma unroll
    for (int r = 0; r < 8; ++r) { float d = a[r] - mu; vr += d * d; }
    vr *= 0.125f;
    float is = rsqrtf(vr + 1e-5f) * g[c];
    #pragma unroll
    for (int r = 0; r < 8; ++r)
        out[r * OD + c] = fmaxf(is * (a[r] - mu) + be[c], 0.f);
}

// final Lin [8,256]@[256,23] + log_softmax
__global__ void head3_kernel(const float* __restrict__ x, const float* __restrict__ W,
                             const float* __restrict__ b, float* __restrict__ out) {
    __shared__ float xs[8 * 256];
    __shared__ float lg[8][23];
    __shared__ float red[8][2];
    const int t = threadIdx.x;
    for (int e = t; e < 2048; e += 256) xs[e] = x[e];
    __syncthreads();
    if (t < 184) {
        int r = t / 23, c = t - 23 * r;
        float a = b[c];
        for (int k = 0; k < 256; ++k) a += xs[r * 256 + k] * W[k * 23 + c];
        lg[r][c] = a;
    }
    __syncthreads();
    if (t < 8) {
        float mx = -3.4e38f;
        for (int c = 0; c < 23; ++c) mx = fmaxf(mx, lg[t][c]);
        float s = 0.f;
        for (int c = 0; c < 23; ++c) s += expf(lg[t][c] - mx);
        red[t][0] = mx; red[t][1] = logf(s);
    }
    __syncthreads();
    if (t < 184) {
        int r = t / 23, c = t - 23 * r;
        out[t] = lg[r][c] - red[r][0] - red[r][1];
    }
}

// ---------------- launcher ----------------
extern "C" void kernel_launch(void* const* d_in, const int* in_sizes, int n_in,
                              void* d_out, int out_size, void* d_ws, size_t ws_size,
                              hipStream_t stream) {
    (void)in_sizes; (void)n_in; (void)out_size; (void)ws_size;
    const float* pos = (const float*)d_in[0];
    const float* W1  = (const float*)d_in[2];  const float* b1  = (const float*)d_in[3];
    const float* W2  = (const float*)d_in[4];  const float* b2  = (const float*)d_in[5];
    const float* W3  = (const float*)d_in[6];  const float* b3  = (const float*)d_in[7];
    const float* Wf1 = (const float*)d_in[8];  const float* bf1 = (const float*)d_in[9];
    const float* Wa  = (const float*)d_in[10]; const float* ba  = (const float*)d_in[11];
    const float* ga  = (const float*)d_in[12]; const float* bea = (const float*)d_in[13];
    const float* Wb  = (const float*)d_in[14]; const float* bb  = (const float*)d_in[15];
    const float* gb  = (const float*)d_in[16]; const float* beb = (const float*)d_in[17];
    const float* Wc  = (const float*)d_in[18]; const float* bc  = (const float*)d_in[19];

    char* ws = (char*)d_ws;
    float*    x0p  = (float*)(ws + OFF_X0P);
    float*    n2   = (float*)(ws + OFF_N2);
    int*      idx  = (int*)(ws + OFF_IDX);
    float*    wuv1 = (float*)(ws + OFF_WUV1);
    float*    wuv2 = (float*)(ws + OFF_WUV2);
    float*    wuv3 = (float*)(ws + OFF_WUV3);
    unsigned* pool = (unsigned*)(ws + OFF_POOL);
    float*    C1   = (float*)(ws + OFF_C1);
    float*    C2   = (float*)(ws + OFF_C2);
    float*    x1   = (float*)(ws + OFF_X1);
    float*    x2   = (float*)(ws + OFF_X2);
    float*    x3   = (float*)(ws + OFF_X3);
    float*    UV   = (float*)(ws + OFF_UV);
    float*    Dm   = (float*)(ws + OFF_UV);
    float*    P1   = (float*)(ws + OFF_P1);
    float*    P2   = (float*)(ws + OFF_P2);
    unsigned short* Xph  = (unsigned short*)(ws + OFF_XPH);
    unsigned short* Xpl  = (unsigned short*)(ws + OFF_XPL);
    unsigned short* Apkh = (unsigned short*)(ws + OFF_APKH);
    unsigned short* Apkl = (unsigned short*)(ws + OFF_APKL);
    unsigned short* Bth  = (unsigned short*)(ws + OFF_BTH);
    unsigned short* Btl  = (unsigned short*)(ws + OFF_BTL);

    // prep
    build_x0p_kernel<<<1024, 256, 0, stream>>>(pos, x0p);
    wuv_build_kernel<<<8,   256, 0, stream>>>(W1, wuv1, 3,   16,  64);
    wuv_build_kernel<<<64,  256, 0, stream>>>(W2, wuv2, 64,  64,  128);
    wuv_build_kernel<<<256, 256, 0, stream>>>(W3, wuv3, 128, 128, 256);
    init_pool_kernel<<<32,  256, 0, stream>>>(pool);

    // edge conv 1 (d=3 padded to 16 -> 64), fp32 distance GEMM
    sqnorm_kernel<16><<<64, 256, 0, stream>>>(x0p, n2);
    for (int r0 = 0; r0 < 8; r0 += 2) {
        gemm_d_kernel<16><<<dim3(16, 16, 2), 256, 0, stream>>>(x0p, n2, Dm, r0);
        knn_select_kernel<<<1024, 256, 0, stream>>>(Dm, idx, r0);
    }
    gemm_uv_kernel<<<dim3(1, 128), 256, 0, stream>>>(x0p, wuv1, UV, NPTS, 128, 16);
    agg_kernel<<<NPTS, 64, 0, stream>>>(UV, idx, b1, x1, 64);

    // edge conv 2 (64 -> 128), MFMA distance GEMM
    sqnorm_kernel<64><<<64, 256, 0, stream>>>(x1, n2);
    packX_kernel<<<1024, 256, 0, stream>>>(x1, Xph, Xpl);
    for (int r0 = 0; r0 < 8; r0 += 2) {
        gemm_dm_kernel<64><<<dim3(16, 16, 2), 256, 0, stream>>>(Xph, Xpl, n2, Dm, r0);
        knn_select_kernel<<<1024, 256, 0, stream>>>(Dm, idx, r0);
    }
    gemm_uv_kernel<<<dim3(2, 128), 256, 0, stream>>>(x1, wuv2, UV, NPTS, 256, 64);
    agg_kernel<<<NPTS, 128, 0, stream>>>(UV, idx, b2, x2, 128);

    // edge conv 3 (128 -> 256), MFMA distance GEMM
    sqnorm_kernel<128><<<64, 256, 0, stream>>>(x2, n2);
    packX_kernel<<<2048, 256, 0, stream>>>(x2, Xph, Xpl);
    for (int r0 = 0; r0 < 8; r0 += 2) {
        gemm_dm_kernel<128><<<dim3(16, 16, 2), 256, 0, stream>>>(Xph, Xpl, n2, Dm, r0);
        knn_select_kernel<<<1024, 256, 0, stream>>>(Dm, idx, r0);
    }
    gemm_uv_kernel<<<dim3(4, 128), 256, 0, stream>>>(x2, wuv3, UV, NPTS, 512, 128);
    agg_kernel<<<NPTS, 256, 0, stream>>>(UV, idx, b3, x3, 256);

    // fc1 (MFMA) + fused max pool
    packA_kernel<<<7168, 256, 0, stream>>>(x1, x2, x3, Apkh, Apkl);
    packB_kernel<<<448,  256, 0, stream>>>(Wf1, Bth, Btl);
    gemm_fc1_mfma<<<dim3(8, 128), 256, 0, stream>>>(Apkh, Apkl, Bth, Btl, bf1, pool);

    // head: split-k GEMM + BN (x1 region is dead -> partials)
    head_gemm_k<1024, 512, 8, true ><<<dim3(8, 8), 256, 0, stream>>>((const float*)pool, Wa, P1);
    head_bn2<512, 8><<<2, 256, 0, stream>>>(P1, ba, ga, bea, C1);
    head_gemm_k<512, 256, 4, false><<<dim3(4, 4), 256, 0, stream>>>(C1, Wb, P2);
    head_bn2<256, 4><<<1, 256, 0, stream>>>(P2, bb, gb, beb, C2);
    head3_kernel<<<1, 256, 0, stream>>>(C2, Wc, bc, (float*)d_out);
}

// Round 6
// 968.327 us; speedup vs baseline: 2.3926x; 1.0032x over previous
//
#include <hip/hip_runtime.h>
#include <math.h>

#define NPTS 16384
#define PPB  2048
#define KNN  20

// ---------------- workspace layout (bytes), total 64 MiB ----------------
#define OFF_X0P   0u           // 16384*16*4 (dead after stage-1; reused by Bt planes)
#define OFF_N2    1048576u
#define OFF_IDX   1114112u     // 16384*20*4
#define OFF_WUV1  2424832u
#define OFF_WUV2  2433024u
#define OFF_WUV3  2498560u
#define OFF_POOL  2760704u     // 8192*4
#define OFF_C1    2793472u
#define OFF_C2    2809856u
#define OFF_X1    4194304u     // 16384*64*4  (dead after packA; reused by head partials)
#define OFF_P1    4194304u     // 8*8*512*4   = 128 KB
#define OFF_P2    4325376u     // 4*8*256*4   = 32 KB
#define OFF_X2    8388608u     // 16384*128*4
#define OFF_X3    16777216u    // 16384*256*4 (free until agg-3: holds kNN bf16 planes)
#define OFF_XPH   16777216u    // X hi-plane (<= 4 MB)
#define OFF_XPL   25165824u    // X lo-plane (<= 4 MB)
#define OFF_UV    33554432u    // 32 MiB: dist scratch -> U|V -> packed-A planes
#define OFF_APKH  33554432u
#define OFF_APKL  48234496u
#define OFF_BTH   0u
#define OFF_BTL   917504u

typedef __attribute__((ext_vector_type(8))) short b16x8;
typedef __attribute__((ext_vector_type(4))) float f32x4;

__device__ __forceinline__ unsigned f2o(float f) {
    unsigned u = __float_as_uint(f);
    return (u & 0x80000000u) ? ~u : (u | 0x80000000u);
}
__device__ __forceinline__ float o2f(unsigned u) {
    return (u & 0x80000000u) ? __uint_as_float(u & 0x7fffffffu) : __uint_as_float(~u);
}

// split fp32 -> (hi, lo) bf16 pair, RNE both; x ~= hi + lo to ~2^-18 rel
__device__ __forceinline__ void split_bf16(float x, unsigned short& h, unsigned short& l) {
    unsigned u = __float_as_uint(x);
    unsigned rh = (u + 0x7fffu + ((u >> 16) & 1u)) & 0xffff0000u;
    h = (unsigned short)(rh >> 16);
    float r = x - __uint_as_float(rh);
    unsigned v = __float_as_uint(r);
    l = (unsigned short)((v + 0x7fffu + ((v >> 16) & 1u)) >> 16);
}

// ---------------- prep kernels ----------------
__global__ void build_x0p_kernel(const float* __restrict__ pos, float* __restrict__ x0p) {
    int e = blockIdx.x * 256 + threadIdx.x;
    int p = e >> 4, k = e & 15;
    x0p[e] = (k < 3) ? pos[p * 3 + k] : 0.f;
}

__global__ void wuv_build_kernel(const float* __restrict__ W, float* __restrict__ Wuv,
                                 int d, int dpad, int od) {
    int tot = dpad * 2 * od;
    for (int e = blockIdx.x * 256 + threadIdx.x; e < tot; e += gridDim.x * 256) {
        int r = e / (2 * od), c = e - r * (2 * od);
        float v = 0.f;
        if (r < d) v = (c < od) ? (W[r * od + c] - W[(d + r) * od + c])
                                : W[(d + r) * od + (c - od)];
        Wuv[e] = v;
    }
}

__global__ void init_pool_kernel(unsigned* __restrict__ pool) {
    pool[blockIdx.x * 256 + threadIdx.x] = 0u;
}

template<int D>
__global__ void sqnorm_kernel(const float* __restrict__ X, float* __restrict__ n2) {
    int p = blockIdx.x * 256 + threadIdx.x;
    float s = 0.f;
    #pragma unroll
    for (int k = 0; k < D; k += 4) {
        float4 v = *(const float4*)&X[(size_t)p * D + k];
        s += v.x * v.x + v.y * v.y + v.z * v.z + v.w * v.w;
    }
    n2[p] = s;
}

// pack X [16384 x K] fp32 -> bf16 hi/lo planes
__global__ void packX_kernel(const float* __restrict__ X,
                             unsigned short* __restrict__ Xh, unsigned short* __restrict__ Xl) {
    int e = blockIdx.x * 256 + threadIdx.x;
    float4 v = *(const float4*)&X[4 * (size_t)e];
    ushort4 h, l;
    split_bf16(v.x, h.x, l.x); split_bf16(v.y, h.y, l.y);
    split_bf16(v.z, h.z, l.z); split_bf16(v.w, h.w, l.w);
    *(ushort4*)&Xh[4 * (size_t)e] = h;
    *(ushort4*)&Xl[4 * (size_t)e] = l;
}

// pack A = concat(x1,x2,x3) [16384 x 448] into bf16 hi/lo planes
__global__ void packA_kernel(const float* __restrict__ x1, const float* __restrict__ x2,
                             const float* __restrict__ x3,
                             unsigned short* __restrict__ Ah, unsigned short* __restrict__ Al) {
    int e = blockIdx.x * 256 + threadIdx.x;
    int m = e / 112, c4 = (e - m * 112) * 4;
    float4 v;
    if (c4 < 64)       v = *(const float4*)&x1[(size_t)m * 64 + c4];
    else if (c4 < 192) v = *(const float4*)&x2[(size_t)m * 128 + (c4 - 64)];
    else               v = *(const float4*)&x3[(size_t)m * 256 + (c4 - 192)];
    ushort4 h, l;
    split_bf16(v.x, h.x, l.x); split_bf16(v.y, h.y, l.y);
    split_bf16(v.z, h.z, l.z); split_bf16(v.w, h.w, l.w);
    *(ushort4*)&Ah[(size_t)m * 448 + c4] = h;
    *(ushort4*)&Al[(size_t)m * 448 + c4] = l;
}

// pack Wf1^T [1024 x 448] into bf16 hi/lo planes
__global__ void packB_kernel(const float* __restrict__ Wf1,
                             unsigned short* __restrict__ Bh, unsigned short* __restrict__ Bl) {
    int e = blockIdx.x * 256 + threadIdx.x;
    int n = e / 112, k4 = (e - n * 112) * 4;
    ushort4 h, l;
    float v0 = Wf1[(size_t)(k4 + 0) * 1024 + n];
    float v1 = Wf1[(size_t)(k4 + 1) * 1024 + n];
    float v2 = Wf1[(size_t)(k4 + 2) * 1024 + n];
    float v3 = Wf1[(size_t)(k4 + 3) * 1024 + n];
    split_bf16(v0, h.x, l.x); split_bf16(v1, h.y, l.y);
    split_bf16(v2, h.z, l.z); split_bf16(v3, h.w, l.w);
    *(ushort4*)&Bh[(size_t)n * 448 + k4] = h;
    *(ushort4*)&Bl[(size_t)n * 448 + k4] = l;
}

// ---------------- stage-1 distance GEMM (fp32, K=16) ----------------
template<int K>
__global__ __launch_bounds__(256)
void gemm_d_kernel(const float* __restrict__ X, const float* __restrict__ n2,
                   float* __restrict__ Dm, int batch0) {
    __shared__ float As[16][132];
    __shared__ float Bs[16][132];
    const int t = threadIdx.x;
    const int tx = t & 15, ty = t >> 4;
    const int bb = batch0 + blockIdx.z;
    const int rb = blockIdx.y * 128;
    const int cb = blockIdx.x * 128;
    const float* Xr = X + (size_t)(bb * PPB + rb) * K;
    const float* Xc = X + (size_t)(bb * PPB + cb) * K;

    float acc[8][8];
    #pragma unroll
    for (int i = 0; i < 8; ++i)
        #pragma unroll
        for (int j = 0; j < 8; ++j) acc[i][j] = 0.f;

    for (int kc = 0; kc < K; kc += 16) {
        __syncthreads();
        for (int e = t; e < 512; e += 256) {
            int m = e >> 2, kq = e & 3;
            float4 v = *(const float4*)&Xr[(size_t)m * K + kc + 4 * kq];
            As[4 * kq + 0][m] = v.x; As[4 * kq + 1][m] = v.y;
            As[4 * kq + 2][m] = v.z; As[4 * kq + 3][m] = v.w;
        }
        for (int e = t; e < 512; e += 256) {
            int m = e >> 2, kq = e & 3;
            float4 v = *(const float4*)&Xc[(size_t)m * K + kc + 4 * kq];
            Bs[4 * kq + 0][m] = v.x; Bs[4 * kq + 1][m] = v.y;
            Bs[4 * kq + 2][m] = v.z; Bs[4 * kq + 3][m] = v.w;
        }
        __syncthreads();
        #pragma unroll
        for (int kk = 0; kk < 16; ++kk) {
            float4 a0 = *(const float4*)&As[kk][8 * ty];
            float4 a1 = *(const float4*)&As[kk][8 * ty + 4];
            float4 b0 = *(const float4*)&Bs[kk][4 * tx];
            float4 b1 = *(const float4*)&Bs[kk][64 + 4 * tx];
            float av[8] = {a0.x, a0.y, a0.z, a0.w, a1.x, a1.y, a1.z, a1.w};
            float bv[8] = {b0.x, b0.y, b0.z, b0.w, b1.x, b1.y, b1.z, b1.w};
            #pragma unroll
            for (int i = 0; i < 8; ++i)
                #pragma unroll
                for (int j = 0; j < 8; ++j) acc[i][j] += av[i] * bv[j];
        }
    }
    const float* n2c = n2 + bb * PPB + cb;
    float nq0[4], nq1[4];
    #pragma unroll
    for (int j = 0; j < 4; ++j) { nq0[j] = n2c[4 * tx + j]; nq1[j] = n2c[64 + 4 * tx + j]; }
    float* Dz = Dm + (size_t)blockIdx.z * PPB * PPB;
    #pragma unroll
    for (int i = 0; i < 8; ++i) {
        int r = rb + 8 * ty + i;
        float4 v0 = {nq0[0] - 2.f * acc[i][0], nq0[1] - 2.f * acc[i][1],
                     nq0[2] - 2.f * acc[i][2], nq0[3] - 2.f * acc[i][3]};
        float4 v1 = {nq1[0] - 2.f * acc[i][4], nq1[1] - 2.f * acc[i][5],
                     nq1[2] - 2.f * acc[i][6], nq1[3] - 2.f * acc[i][7]};
        *(float4*)&Dz[(size_t)r * PPB + cb + 4 * tx]      = v0;
        *(float4*)&Dz[(size_t)r * PPB + cb + 64 + 4 * tx] = v1;
    }
}

// ---------------- stage-2/3 distance GEMM: split-bf16 MFMA ----------------
template<int K>
__global__ __launch_bounds__(256)
void gemm_dm_kernel(const unsigned short* __restrict__ Xh, const unsigned short* __restrict__ Xl,
                    const float* __restrict__ n2, float* __restrict__ Dm, int batch0) {
    __shared__ unsigned short sA[2][128 * 40];
    __shared__ unsigned short sB[2][128 * 40];
    const int t = threadIdx.x;
    const int bb = batch0 + blockIdx.z;
    const int rb = blockIdx.y * 128, cb = blockIdx.x * 128;
    const size_t rowA = (size_t)(bb * PPB + rb);
    const size_t rowB = (size_t)(bb * PPB + cb);
    const int w = t >> 6, l = t & 63;
    const int wm = w & 1, wn = w >> 1;
    const int lm = l & 15, lq = l >> 4;

    f32x4 acc[4][4];
    #pragma unroll
    for (int i = 0; i < 4; ++i)
        #pragma unroll
        for (int j = 0; j < 4; ++j) acc[i][j] = (f32x4){0.f, 0.f, 0.f, 0.f};

    for (int kc = 0; kc < K; kc += 32) {
        __syncthreads();
        #pragma unroll
        for (int i = 0; i < 8; ++i) {
            int c = t + i * 256;
            int idx = c & 511, m = idx >> 2, q = idx & 3;
            int plane = (c >> 9) & 1;
            const unsigned short* gsrc;
            unsigned short* ldst;
            if (c < 1024) {
                gsrc = (plane ? Xl : Xh) + (rowA + m) * K + kc + q * 8;
                ldst = &sA[plane][m * 40 + q * 8];
            } else {
                gsrc = (plane ? Xl : Xh) + (rowB + m) * K + kc + q * 8;
                ldst = &sB[plane][m * 40 + q * 8];
            }
            *(uint4*)ldst = *(const uint4*)gsrc;
        }
        __syncthreads();
        b16x8 ah[4], al[4], bh[4], bl[4];
        #pragma unroll
        for (int mt = 0; mt < 4; ++mt) {
            int off = (wm * 64 + mt * 16 + lm) * 40 + lq * 8;
            ah[mt] = *(const b16x8*)&sA[0][off];
            al[mt] = *(const b16x8*)&sA[1][off];
        }
        #pragma unroll
        for (int nt = 0; nt < 4; ++nt) {
            int off = (wn * 64 + nt * 16 + lm) * 40 + lq * 8;
            bh[nt] = *(const b16x8*)&sB[0][off];
            bl[nt] = *(const b16x8*)&sB[1][off];
        }
        #pragma unroll
        for (int mt = 0; mt < 4; ++mt)
            #pragma unroll
            for (int nt = 0; nt < 4; ++nt) {
                acc[mt][nt] = __builtin_amdgcn_mfma_f32_16x16x32_bf16(ah[mt], bh[nt], acc[mt][nt], 0, 0, 0);
                acc[mt][nt] = __builtin_amdgcn_mfma_f32_16x16x32_bf16(ah[mt], bl[nt], acc[mt][nt], 0, 0, 0);
                acc[mt][nt] = __builtin_amdgcn_mfma_f32_16x16x32_bf16(al[mt], bh[nt], acc[mt][nt], 0, 0, 0);
            }
    }
    const float* n2c = n2 + bb * PPB + cb;
    float* Dz = Dm + (size_t)blockIdx.z * PPB * PPB;
    #pragma unroll
    for (int nt = 0; nt < 4; ++nt) {
        int col = wn * 64 + nt * 16 + lm;
        float nv = n2c[col];
        #pragma unroll
        for (int mt = 0; mt < 4; ++mt) {
            int row = rb + wm * 64 + mt * 16 + lq * 4;
            #pragma unroll
            for (int r = 0; r < 4; ++r)
                Dz[(size_t)(row + r) * PPB + cb + col] = nv - 2.f * acc[mt][nt][r];
        }
    }
}

// ---------------- top-20 select: one wave per row, candidates in registers ----------------
__global__ __launch_bounds__(256)
void knn_select_kernel(const float* __restrict__ Dm, int* __restrict__ idxout, int batch0) {
    const int lane = threadIdx.x & 63;
    const int wid  = threadIdx.x >> 6;
    const int rowg = blockIdx.x * 4 + wid;
    const int z  = rowg >> 11, rl = rowg & 2047;
    const float* drow = Dm + (size_t)z * PPB * PPB + (size_t)rl * PPB;

    float c[32];
    #pragma unroll
    for (int j = 0; j < 8; ++j) {
        float4 v = *(const float4*)&drow[j * 256 + 4 * lane];
        c[4 * j + 0] = v.x; c[4 * j + 1] = v.y; c[4 * j + 2] = v.z; c[4 * j + 3] = v.w;
    }
    float mv = c[0]; int mj = 0;
    #pragma unroll
    for (int j = 1; j < 32; ++j) if (c[j] < mv) { mv = c[j]; mj = j; }
    int mq = ((mj >> 2) << 8) + 4 * lane + (mj & 3);

    int keep = 0;
    for (int round = 0; round < KNN; ++round) {
        float rv = mv; int rq = mq;
        #pragma unroll
        for (int m = 1; m < 64; m <<= 1) {
            float ov = __shfl_xor(rv, m, 64);
            int   oq = __shfl_xor(rq, m, 64);
            if (ov < rv || (ov == rv && oq < rq)) { rv = ov; rq = oq; }
        }
        if (lane == round) keep = rq;
        if (rv == mv && rq == mq) {
            #pragma unroll
            for (int j = 0; j < 32; ++j) if (j == mj) c[j] = 3.4e38f;
            mv = c[0]; mj = 0;
            #pragma unroll
            for (int j = 1; j < 32; ++j) if (c[j] < mv) { mv = c[j]; mj = j; }
            mq = ((mj >> 2) << 8) + 4 * lane + (mj & 3);
        }
    }
    const int pbase = (batch0 + z) * PPB;
    if (lane < KNN)
        idxout[(size_t)(pbase + rl) * KNN + lane] = pbase + keep;
}

// ---------------- fp32 tiled GEMM 128x128 (UV projection) ----------------
// grid (M/128, N/128): x = row tile (XCD-locality: col-siblings share XCD)
__global__ __launch_bounds__(256)
void gemm_uv_kernel(const float* __restrict__ A, const float* __restrict__ B,
                    float* __restrict__ C, int M, int N, int K) {
    __shared__ float As[16][132];
    __shared__ float Bs[16][132];
    const int t = threadIdx.x;
    const int tx = t & 15, ty = t >> 4;
    const int nb = blockIdx.y * 128;
    const int mb = blockIdx.x * 128;
    float acc[8][8];
    #pragma unroll
    for (int i = 0; i < 8; ++i)
        #pragma unroll
        for (int j = 0; j < 8; ++j) acc[i][j] = 0.f;

    for (int kc = 0; kc < K; kc += 16) {
        __syncthreads();
        for (int e = t; e < 512; e += 256) {
            int m = e >> 2, kq = e & 3;
            float4 v = *(const float4*)&A[(size_t)(mb + m) * K + kc + 4 * kq];
            As[4 * kq + 0][m] = v.x; As[4 * kq + 1][m] = v.y;
            As[4 * kq + 2][m] = v.z; As[4 * kq + 3][m] = v.w;
        }
        for (int e = t; e < 512; e += 256) {
            int kr = e >> 5, nq = e & 31;
            *(float4*)&Bs[kr][4 * nq] = *(const float4*)&B[(size_t)(kc + kr) * N + nb + 4 * nq];
        }
        __syncthreads();
        #pragma unroll
        for (int kk = 0; kk < 16; ++kk) {
            float4 a0 = *(const float4*)&As[kk][8 * ty];
            float4 a1 = *(const float4*)&As[kk][8 * ty + 4];
            float4 b0 = *(const float4*)&Bs[kk][4 * tx];
            float4 b1 = *(const float4*)&Bs[kk][64 + 4 * tx];
            float av[8] = {a0.x, a0.y, a0.z, a0.w, a1.x, a1.y, a1.z, a1.w};
            float bv[8] = {b0.x, b0.y, b0.z, b0.w, b1.x, b1.y, b1.z, b1.w};
            #pragma unroll
            for (int i = 0; i < 8; ++i)
                #pragma unroll
                for (int j = 0; j < 8; ++j) acc[i][j] += av[i] * bv[j];
        }
    }
    #pragma unroll
    for (int i = 0; i < 8; ++i) {
        float4 v0 = {acc[i][0], acc[i][1], acc[i][2], acc[i][3]};
        float4 v1 = {acc[i][4], acc[i][5], acc[i][6], acc[i][7]};
        *(float4*)&C[(size_t)(mb + 8 * ty + i) * N + nb + 4 * tx] = v0;
        *(float4*)&C[(size_t)(mb + 8 * ty + i) * N + nb + 64 + 4 * tx] = v1;
    }
}

// ---------------- fc1: split-bf16 MFMA GEMM + fused max-pool ----------------
// grid (128, 8): x = row tile -> the 8 col-siblings of an A-tile land on one XCD
__global__ __launch_bounds__(256)
void gemm_fc1_mfma(const unsigned short* __restrict__ Ah, const unsigned short* __restrict__ Al,
                   const unsigned short* __restrict__ Bh, const unsigned short* __restrict__ Bl,
                   const float* __restrict__ bias, unsigned* __restrict__ pool) {
    __shared__ unsigned short sA[2][128 * 40];
    __shared__ unsigned short sB[2][128 * 40];
    const int t = threadIdx.x;
    const int nb = blockIdx.y * 128, mb = blockIdx.x * 128;
    const int w = t >> 6, l = t & 63;
    const int wm = w & 1, wn = w >> 1;
    const int lm = l & 15, lq = l >> 4;

    f32x4 acc[4][4];
    #pragma unroll
    for (int i = 0; i < 4; ++i)
        #pragma unroll
        for (int j = 0; j < 4; ++j) acc[i][j] = (f32x4){0.f, 0.f, 0.f, 0.f};

    for (int kc = 0; kc < 448; kc += 32) {
        __syncthreads();
        #pragma unroll
        for (int i = 0; i < 8; ++i) {
            int c = t + i * 256;
            int idx = c & 511, m = idx >> 2, q = idx & 3;
            int plane = (c >> 9) & 1;
            const unsigned short* gsrc;
            unsigned short* ldst;
            if (c < 1024) {
                gsrc = (plane ? Al : Ah) + (size_t)(mb + m) * 448 + kc + q * 8;
                ldst = &sA[plane][m * 40 + q * 8];
            } else {
                gsrc = (plane ? Bl : Bh) + (size_t)(nb + m) * 448 + kc + q * 8;
                ldst = &sB[plane][m * 40 + q * 8];
            }
            *(uint4*)ldst = *(const uint4*)gsrc;
        }
        __syncthreads();
        b16x8 ah[4], al[4], bh[4], bl[4];
        #pragma unroll
        for (int mt = 0; mt < 4; ++mt) {
            int off = (wm * 64 + mt * 16 + lm) * 40 + lq * 8;
            ah[mt] = *(const b16x8*)&sA[0][off];
            al[mt] = *(const b16x8*)&sA[1][off];
        }
        #pragma unroll
        for (int nt = 0; nt < 4; ++nt) {
            int off = (wn * 64 + nt * 16 + lm) * 40 + lq * 8;
            bh[nt] = *(const b16x8*)&sB[0][off];
            bl[nt] = *(const b16x8*)&sB[1][off];
        }
        #pragma unroll
        for (int mt = 0; mt < 4; ++mt)
            #pragma unroll
            for (int nt = 0; nt < 4; ++nt) {
                acc[mt][nt] = __builtin_amdgcn_mfma_f32_16x16x32_bf16(ah[mt], bh[nt], acc[mt][nt], 0, 0, 0);
                acc[mt][nt] = __builtin_amdgcn_mfma_f32_16x16x32_bf16(ah[mt], bl[nt], acc[mt][nt], 0, 0, 0);
                acc[mt][nt] = __builtin_amdgcn_mfma_f32_16x16x32_bf16(al[mt], bh[nt], acc[mt][nt], 0, 0, 0);
            }
    }
    const int batch = blockIdx.x >> 4;
    #pragma unroll
    for (int nt = 0; nt < 4; ++nt) {
        float m0 = -3.4e38f;
        #pragma unroll
        for (int mt = 0; mt < 4; ++mt)
            #pragma unroll
            for (int r = 0; r < 4; ++r) m0 = fmaxf(m0, acc[mt][nt][r]);
        m0 = fmaxf(m0, __shfl_xor(m0, 16, 64));
        m0 = fmaxf(m0, __shfl_xor(m0, 32, 64));
        if (l < 16) {
            int col = nb + wn * 64 + nt * 16 + l;
            atomicMax(&pool[batch * 1024 + col], f2o(m0 + bias[col]));
        }
    }
}

// ---------------- edge-conv aggregate ----------------
// block -> point swizzle pins batch b to XCD b: per-XCD V working set ~2 MB = L2-resident
__global__ void agg_kernel(const float* __restrict__ UV, const int* __restrict__ idx,
                           const float* __restrict__ bias, float* __restrict__ xo, int od) {
    const int p = ((blockIdx.x & 7) << 11) + (blockIdx.x >> 3);
    const int c = threadIdx.x;
    const float u = UV[(size_t)p * 2 * od + c];
    float m = -3.4e38f;
    #pragma unroll
    for (int k = 0; k < KNN; ++k) {
        int j = idx[p * KNN + k];
        m = fmaxf(m, UV[(size_t)j * 2 * od + od + c]);
    }
    xo[(size_t)p * od + c] = u + bias[c] + m;
}

// ---------------- head: split-k GEMM + per-column BN ----------------
template<int IND, int OD, int KSEG, bool UNMAP>
__global__ __launch_bounds__(256)
void head_gemm_k(const float* __restrict__ in, const float* __restrict__ W,
                 float* __restrict__ P) {
    const int KL = IND / KSEG;
    __shared__ float xs[8][IND / KSEG];
    const int t = threadIdx.x;
    const int kb = blockIdx.y * KL;
    const int cb = blockIdx.x * 64;
    for (int e = t; e < 8 * KL; e += 256) {
        int r = e / KL, k = e - r * KL;
        if (UNMAP) xs[r][k] = o2f(((const unsigned*)in)[r * IND + kb + k]);
        else       xs[r][k] = in[r * IND + kb + k];
    }
    __syncthreads();
    const int c = t & 63, rr = t >> 6;
    float a0 = 0.f, a1 = 0.f;
    #pragma unroll 4
    for (int k = 0; k < KL; ++k) {
        float wv = W[(size_t)(kb + k) * OD + cb + c];
        a0 += xs[2 * rr][k] * wv;
        a1 += xs[2 * rr + 1][k] * wv;
    }
    P[(size_t)(blockIdx.y * 8 + 2 * rr) * OD + cb + c]     = a0;
    P[(size_t)(blockIdx.y * 8 + 2 * rr + 1) * OD + cb + c] = a1;
}

template<int OD, int KSEG>
__global__ void head_bn2(const float* __restrict__ P, const float* __restrict__ bias,
                         const float* __restrict__ g, const float* __restrict__ be,
                         float* __restrict__ out) {
    const int c = blockIdx.x * 256 + threadIdx.x;
    float a[8];
    #pragma unroll
    for (int r = 0; r < 8; ++r) {
        float s = bias[c];
        #pragma unroll
        for (int ks = 0; ks < KSEG; ++ks) s += P[(size_t)(ks * 8 + r) * OD + c];
        a[r] = s;
    }
    float mu = 0.f;
    #pragma unroll
    for (int r = 0; r < 8; ++r) mu += a[r];
    mu *= 0.125f;
    float vr = 0.f;
    #pragma unroll
    for (int r = 0; r < 8; ++r) { float d = a[r] - mu; vr += d * d; }
    vr *= 0.125f;
    float is = rsqrtf(vr + 1e-5f) * g[c];
    #pragma unroll
    for (int r = 0; r < 8; ++r)
        out[r * OD + c] = fmaxf(is * (a[r] - mu) + be[c], 0.f);
}

// final Lin [8,256]@[256,23] + log_softmax
__global__ void head3_kernel(const float* __restrict__ x, const float* __restrict__ W,
                             const float* __restrict__ b, float* __restrict__ out) {
    __shared__ float xs[8 * 256];
    __shared__ float lg[8][23];
    __shared__ float red[8][2];
    const int t = threadIdx.x;
    for (int e = t; e < 2048; e += 256) xs[e] = x[e];
    __syncthreads();
    if (t < 184) {
        int r = t / 23, c = t - 23 * r;
        float a = b[c];
        for (int k = 0; k < 256; ++k) a += xs[r * 256 + k] * W[k * 23 + c];
        lg[r][c] = a;
    }
    __syncthreads();
    if (t < 8) {
        float mx = -3.4e38f;
        for (int c = 0; c < 23; ++c) mx = fmaxf(mx, lg[t][c]);
        float s = 0.f;
        for (int c = 0; c < 23; ++c) s += expf(lg[t][c] - mx);
        red[t][0] = mx; red[t][1] = logf(s);
    }
    __syncthreads();
    if (t < 184) {
        int r = t / 23, c = t - 23 * r;
        out[t] = lg[r][c] - red[r][0] - red[r][1];
    }
}

// ---------------- launcher ----------------
extern "C" void kernel_launch(void* const* d_in, const int* in_sizes, int n_in,
                              void* d_out, int out_size, void* d_ws, size_t ws_size,
                              hipStream_t stream) {
    (void)in_sizes; (void)n_in; (void)out_size; (void)ws_size;
    const float* pos = (const float*)d_in[0];
    const float* W1  = (const float*)d_in[2];  const float* b1  = (const float*)d_in[3];
    const float* W2  = (const float*)d_in[4];  const float* b2  = (const float*)d_in[5];
    const float* W3  = (const float*)d_in[6];  const float* b3  = (const float*)d_in[7];
    const float* Wf1 = (const float*)d_in[8];  const float* bf1 = (const float*)d_in[9];
    const float* Wa  = (const float*)d_in[10]; const float* ba  = (const float*)d_in[11];
    const float* ga  = (const float*)d_in[12]; const float* bea = (const float*)d_in[13];
    const float* Wb  = (const float*)d_in[14]; const float* bb  = (const float*)d_in[15];
    const float* gb  = (const float*)d_in[16]; const float* beb = (const float*)d_in[17];
    const float* Wc  = (const float*)d_in[18]; const float* bc  = (const float*)d_in[19];

    char* ws = (char*)d_ws;
    float*    x0p  = (float*)(ws + OFF_X0P);
    float*    n2   = (float*)(ws + OFF_N2);
    int*      idx  = (int*)(ws + OFF_IDX);
    float*    wuv1 = (float*)(ws + OFF_WUV1);
    float*    wuv2 = (float*)(ws + OFF_WUV2);
    float*    wuv3 = (float*)(ws + OFF_WUV3);
    unsigned* pool = (unsigned*)(ws + OFF_POOL);
    float*    C1   = (float*)(ws + OFF_C1);
    float*    C2   = (float*)(ws + OFF_C2);
    float*    x1   = (float*)(ws + OFF_X1);
    float*    x2   = (float*)(ws + OFF_X2);
    float*    x3   = (float*)(ws + OFF_X3);
    float*    UV   = (float*)(ws + OFF_UV);
    float*    Dm   = (float*)(ws + OFF_UV);
    float*    P1   = (float*)(ws + OFF_P1);
    float*    P2   = (float*)(ws + OFF_P2);
    unsigned short* Xph  = (unsigned short*)(ws + OFF_XPH);
    unsigned short* Xpl  = (unsigned short*)(ws + OFF_XPL);
    unsigned short* Apkh = (unsigned short*)(ws + OFF_APKH);
    unsigned short* Apkl = (unsigned short*)(ws + OFF_APKL);
    unsigned short* Bth  = (unsigned short*)(ws + OFF_BTH);
    unsigned short* Btl  = (unsigned short*)(ws + OFF_BTL);

    // prep
    build_x0p_kernel<<<1024, 256, 0, stream>>>(pos, x0p);
    wuv_build_kernel<<<8,   256, 0, stream>>>(W1, wuv1, 3,   16,  64);
    wuv_build_kernel<<<64,  256, 0, stream>>>(W2, wuv2, 64,  64,  128);
    wuv_build_kernel<<<256, 256, 0, stream>>>(W3, wuv3, 128, 128, 256);
    init_pool_kernel<<<32,  256, 0, stream>>>(pool);

    // edge conv 1 (d=3 padded to 16 -> 64), fp32 distance GEMM
    sqnorm_kernel<16><<<64, 256, 0, stream>>>(x0p, n2);
    for (int r0 = 0; r0 < 8; r0 += 2) {
        gemm_d_kernel<16><<<dim3(16, 16, 2), 256, 0, stream>>>(x0p, n2, Dm, r0);
        knn_select_kernel<<<1024, 256, 0, stream>>>(Dm, idx, r0);
    }
    gemm_uv_kernel<<<dim3(128, 1), 256, 0, stream>>>(x0p, wuv1, UV, NPTS, 128, 16);
    agg_kernel<<<NPTS, 64, 0, stream>>>(UV, idx, b1, x1, 64);

    // edge conv 2 (64 -> 128), MFMA distance GEMM
    sqnorm_kernel<64><<<64, 256, 0, stream>>>(x1, n2);
    packX_kernel<<<1024, 256, 0, stream>>>(x1, Xph, Xpl);
    for (int r0 = 0; r0 < 8; r0 += 2) {
        gemm_dm_kernel<64><<<dim3(16, 16, 2), 256, 0, stream>>>(Xph, Xpl, n2, Dm, r0);
        knn_select_kernel<<<1024, 256, 0, stream>>>(Dm, idx, r0);
    }
    gemm_uv_kernel<<<dim3(128, 2), 256, 0, stream>>>(x1, wuv2, UV, NPTS, 256, 64);
    agg_kernel<<<NPTS, 128, 0, stream>>>(UV, idx, b2, x2, 128);

    // edge conv 3 (128 -> 256), MFMA distance GEMM
    sqnorm_kernel<128><<<64, 256, 0, stream>>>(x2, n2);
    packX_kernel<<<2048, 256, 0, stream>>>(x2, Xph, Xpl);
    for (int r0 = 0; r0 < 8; r0 += 2) {
        gemm_dm_kernel<128><<<dim3(16, 16, 2), 256, 0, stream>>>(Xph, Xpl, n2, Dm, r0);
        knn_select_kernel<<<1024, 256, 0, stream>>>(Dm, idx, r0);
    }
    gemm_uv_kernel<<<dim3(128, 4), 256, 0, stream>>>(x2, wuv3, UV, NPTS, 512, 128);
    agg_kernel<<<NPTS, 256, 0, stream>>>(UV, idx, b3, x3, 256);

    // fc1 (MFMA) + fused max pool
    packA_kernel<<<7168, 256, 0, stream>>>(x1, x2, x3, Apkh, Apkl);
    packB_kernel<<<448,  256, 0, stream>>>(Wf1, Bth, Btl);
    gemm_fc1_mfma<<<dim3(128, 8), 256, 0, stream>>>(Apkh, Apkl, Bth, Btl, bf1, pool);

    // head: split-k GEMM + BN
    head_gemm_k<1024, 512, 8, true ><<<dim3(8, 8), 256, 0, stream>>>((const float*)pool, Wa, P1);
    head_bn2<512, 8><<<2, 256, 0, stream>>>(P1, ba, ga, bea, C1);
    head_gemm_k<512, 256, 4, false><<<dim3(4, 4), 256, 0, stream>>>(C1, Wb, P2);
    head_bn2<256, 4><<<1, 256, 0, stream>>>(P2, bb, gb, beb, C2);
    head3_kernel<<<1, 256, 0, stream>>>(C2, Wc, bc, (float*)d_out);
}

// Round 7
// 957.305 us; speedup vs baseline: 2.4201x; 1.0115x over previous
//
#include <hip/hip_runtime.h>
#include <math.h>

#define NPTS 16384
#define PPB  2048
#define KNN  20

// ---------------- workspace layout (bytes), total 64 MiB ----------------
#define OFF_X0P   0u           // 16384*16*4 (dead after stage-1 gemm_uv; reused: Wt planes, then Bt planes)
#define OFF_N2    1048576u
#define OFF_IDX   1114112u     // 16384*20*4
#define OFF_WUV1  2424832u
#define OFF_POOL  2760704u     // 8192*4
#define OFF_C1    2793472u
#define OFF_C2    2809856u
#define OFF_X1    4194304u     // 16384*64*4  (dead after packA; reused by head partials)
#define OFF_P1    4194304u
#define OFF_P2    4325376u
#define OFF_X2    8388608u     // 16384*128*4
#define OFF_X3    16777216u    // 16384*256*4 (free until agg-3: holds kNN/UV bf16 planes)
#define OFF_XPH   16777216u
#define OFF_XPL   25165824u
#define OFF_UV    33554432u    // 32 MiB: dist scratch -> U|V -> packed-A planes
#define OFF_APKH  33554432u
#define OFF_APKL  48234496u
// Wt planes (W^T hi/lo, [n][k]) in dead x0p region during stages 2/3:
#define OFF_WT2H  0u
#define OFF_WT2L  32768u
#define OFF_WT3H  65536u
#define OFF_WT3L  196608u
// Bt planes for fc1 (after Wt dead):
#define OFF_BTH   0u
#define OFF_BTL   917504u

typedef __attribute__((ext_vector_type(8))) short b16x8;
typedef __attribute__((ext_vector_type(4))) float f32x4;

__device__ __forceinline__ unsigned f2o(float f) {
    unsigned u = __float_as_uint(f);
    return (u & 0x80000000u) ? ~u : (u | 0x80000000u);
}
__device__ __forceinline__ float o2f(unsigned u) {
    return (u & 0x80000000u) ? __uint_as_float(u & 0x7fffffffu) : __uint_as_float(~u);
}

// split fp32 -> (hi, lo) bf16 pair, RNE both; x ~= hi + lo to ~2^-18 rel
__device__ __forceinline__ void split_bf16(float x, unsigned short& h, unsigned short& l) {
    unsigned u = __float_as_uint(x);
    unsigned rh = (u + 0x7fffu + ((u >> 16) & 1u)) & 0xffff0000u;
    h = (unsigned short)(rh >> 16);
    float r = x - __uint_as_float(rh);
    unsigned v = __float_as_uint(r);
    l = (unsigned short)((v + 0x7fffu + ((v >> 16) & 1u)) >> 16);
}

// ---------------- prep kernels ----------------
__global__ void build_x0p_kernel(const float* __restrict__ pos, float* __restrict__ x0p) {
    int e = blockIdx.x * 256 + threadIdx.x;
    int p = e >> 4, k = e & 15;
    x0p[e] = (k < 3) ? pos[p * 3 + k] : 0.f;
}

__global__ void wuv_build_kernel(const float* __restrict__ W, float* __restrict__ Wuv,
                                 int d, int dpad, int od) {
    int tot = dpad * 2 * od;
    for (int e = blockIdx.x * 256 + threadIdx.x; e < tot; e += gridDim.x * 256) {
        int r = e / (2 * od), c = e - r * (2 * od);
        float v = 0.f;
        if (r < d) v = (c < od) ? (W[r * od + c] - W[(d + r) * od + c])
                                : W[(d + r) * od + (c - od)];
        Wuv[e] = v;
    }
}

// W [2d][od] -> W^T hi/lo planes [2od][dpad]: n<od: U = W_top - W_bot; else V = W_bot
__global__ void packWt_kernel(const float* __restrict__ W,
                              unsigned short* __restrict__ Bh, unsigned short* __restrict__ Bl,
                              int d, int dpad, int od) {
    int e = blockIdx.x * 256 + threadIdx.x;       // < 2*od*dpad
    int n = e / dpad, k = e - n * dpad;
    float v = 0.f;
    if (k < d) v = (n < od) ? (W[k * od + n] - W[(d + k) * od + n])
                            : W[(d + k) * od + (n - od)];
    unsigned short h, l;
    split_bf16(v, h, l);
    Bh[e] = h; Bl[e] = l;
}

__global__ void init_pool_kernel(unsigned* __restrict__ pool) {
    pool[blockIdx.x * 256 + threadIdx.x] = 0u;
}

template<int D>
__global__ void sqnorm_kernel(const float* __restrict__ X, float* __restrict__ n2) {
    int p = blockIdx.x * 256 + threadIdx.x;
    float s = 0.f;
    #pragma unroll
    for (int k = 0; k < D; k += 4) {
        float4 v = *(const float4*)&X[(size_t)p * D + k];
        s += v.x * v.x + v.y * v.y + v.z * v.z + v.w * v.w;
    }
    n2[p] = s;
}

// pack X [16384 x K] fp32 -> bf16 hi/lo planes
__global__ void packX_kernel(const float* __restrict__ X,
                             unsigned short* __restrict__ Xh, unsigned short* __restrict__ Xl) {
    int e = blockIdx.x * 256 + threadIdx.x;
    float4 v = *(const float4*)&X[4 * (size_t)e];
    ushort4 h, l;
    split_bf16(v.x, h.x, l.x); split_bf16(v.y, h.y, l.y);
    split_bf16(v.z, h.z, l.z); split_bf16(v.w, h.w, l.w);
    *(ushort4*)&Xh[4 * (size_t)e] = h;
    *(ushort4*)&Xl[4 * (size_t)e] = l;
}

// pack A = concat(x1,x2,x3) [16384 x 448] into bf16 hi/lo planes
__global__ void packA_kernel(const float* __restrict__ x1, const float* __restrict__ x2,
                             const float* __restrict__ x3,
                             unsigned short* __restrict__ Ah, unsigned short* __restrict__ Al) {
    int e = blockIdx.x * 256 + threadIdx.x;
    int m = e / 112, c4 = (e - m * 112) * 4;
    float4 v;
    if (c4 < 64)       v = *(const float4*)&x1[(size_t)m * 64 + c4];
    else if (c4 < 192) v = *(const float4*)&x2[(size_t)m * 128 + (c4 - 64)];
    else               v = *(const float4*)&x3[(size_t)m * 256 + (c4 - 192)];
    ushort4 h, l;
    split_bf16(v.x, h.x, l.x); split_bf16(v.y, h.y, l.y);
    split_bf16(v.z, h.z, l.z); split_bf16(v.w, h.w, l.w);
    *(ushort4*)&Ah[(size_t)m * 448 + c4] = h;
    *(ushort4*)&Al[(size_t)m * 448 + c4] = l;
}

// pack Wf1^T [1024 x 448] into bf16 hi/lo planes
__global__ void packB_kernel(const float* __restrict__ Wf1,
                             unsigned short* __restrict__ Bh, unsigned short* __restrict__ Bl) {
    int e = blockIdx.x * 256 + threadIdx.x;
    int n = e / 112, k4 = (e - n * 112) * 4;
    ushort4 h, l;
    float v0 = Wf1[(size_t)(k4 + 0) * 1024 + n];
    float v1 = Wf1[(size_t)(k4 + 1) * 1024 + n];
    float v2 = Wf1[(size_t)(k4 + 2) * 1024 + n];
    float v3 = Wf1[(size_t)(k4 + 3) * 1024 + n];
    split_bf16(v0, h.x, l.x); split_bf16(v1, h.y, l.y);
    split_bf16(v2, h.z, l.z); split_bf16(v3, h.w, l.w);
    *(ushort4*)&Bh[(size_t)n * 448 + k4] = h;
    *(ushort4*)&Bl[(size_t)n * 448 + k4] = l;
}

// ---------------- stage-1 distance GEMM (fp32, K=16) ----------------
template<int K>
__global__ __launch_bounds__(256)
void gemm_d_kernel(const float* __restrict__ X, const float* __restrict__ n2,
                   float* __restrict__ Dm, int batch0) {
    __shared__ float As[16][132];
    __shared__ float Bs[16][132];
    const int t = threadIdx.x;
    const int tx = t & 15, ty = t >> 4;
    const int bb = batch0 + blockIdx.z;
    const int rb = blockIdx.y * 128;
    const int cb = blockIdx.x * 128;
    const float* Xr = X + (size_t)(bb * PPB + rb) * K;
    const float* Xc = X + (size_t)(bb * PPB + cb) * K;

    float acc[8][8];
    #pragma unroll
    for (int i = 0; i < 8; ++i)
        #pragma unroll
        for (int j = 0; j < 8; ++j) acc[i][j] = 0.f;

    for (int kc = 0; kc < K; kc += 16) {
        __syncthreads();
        for (int e = t; e < 512; e += 256) {
            int m = e >> 2, kq = e & 3;
            float4 v = *(const float4*)&Xr[(size_t)m * K + kc + 4 * kq];
            As[4 * kq + 0][m] = v.x; As[4 * kq + 1][m] = v.y;
            As[4 * kq + 2][m] = v.z; As[4 * kq + 3][m] = v.w;
        }
        for (int e = t; e < 512; e += 256) {
            int m = e >> 2, kq = e & 3;
            float4 v = *(const float4*)&Xc[(size_t)m * K + kc + 4 * kq];
            Bs[4 * kq + 0][m] = v.x; Bs[4 * kq + 1][m] = v.y;
            Bs[4 * kq + 2][m] = v.z; Bs[4 * kq + 3][m] = v.w;
        }
        __syncthreads();
        #pragma unroll
        for (int kk = 0; kk < 16; ++kk) {
            float4 a0 = *(const float4*)&As[kk][8 * ty];
            float4 a1 = *(const float4*)&As[kk][8 * ty + 4];
            float4 b0 = *(const float4*)&Bs[kk][4 * tx];
            float4 b1 = *(const float4*)&Bs[kk][64 + 4 * tx];
            float av[8] = {a0.x, a0.y, a0.z, a0.w, a1.x, a1.y, a1.z, a1.w};
            float bv[8] = {b0.x, b0.y, b0.z, b0.w, b1.x, b1.y, b1.z, b1.w};
            #pragma unroll
            for (int i = 0; i < 8; ++i)
                #pragma unroll
                for (int j = 0; j < 8; ++j) acc[i][j] += av[i] * bv[j];
        }
    }
    const float* n2c = n2 + bb * PPB + cb;
    float nq0[4], nq1[4];
    #pragma unroll
    for (int j = 0; j < 4; ++j) { nq0[j] = n2c[4 * tx + j]; nq1[j] = n2c[64 + 4 * tx + j]; }
    float* Dz = Dm + (size_t)blockIdx.z * PPB * PPB;
    #pragma unroll
    for (int i = 0; i < 8; ++i) {
        int r = rb + 8 * ty + i;
        float4 v0 = {nq0[0] - 2.f * acc[i][0], nq0[1] - 2.f * acc[i][1],
                     nq0[2] - 2.f * acc[i][2], nq0[3] - 2.f * acc[i][3]};
        float4 v1 = {nq1[0] - 2.f * acc[i][4], nq1[1] - 2.f * acc[i][5],
                     nq1[2] - 2.f * acc[i][6], nq1[3] - 2.f * acc[i][7]};
        *(float4*)&Dz[(size_t)r * PPB + cb + 4 * tx]      = v0;
        *(float4*)&Dz[(size_t)r * PPB + cb + 64 + 4 * tx] = v1;
    }
}

// ---------------- stage-2/3 distance GEMM: split-bf16 MFMA, LDS-staged stores ----------------
template<int K>
__global__ __launch_bounds__(256)
void gemm_dm_kernel(const unsigned short* __restrict__ Xh, const unsigned short* __restrict__ Xl,
                    const float* __restrict__ n2, float* __restrict__ Dm, int batch0) {
    __shared__ __align__(16) unsigned char smem[40960];
    unsigned short (*sA)[5120] = (unsigned short (*)[5120])smem;            // [2][128*40]
    unsigned short (*sB)[5120] = (unsigned short (*)[5120])(smem + 20480);  // [2][128*40]
    float* tile = (float*)smem;                                             // 32x132 chunk

    const int t = threadIdx.x;
    const int bb = batch0 + blockIdx.z;
    const int rb = blockIdx.y * 128, cb = blockIdx.x * 128;
    const size_t rowA = (size_t)(bb * PPB + rb);
    const size_t rowB = (size_t)(bb * PPB + cb);
    const int w = t >> 6, l = t & 63;
    const int wm = w & 1, wn = w >> 1;
    const int lm = l & 15, lq = l >> 4;

    f32x4 acc[4][4];
    #pragma unroll
    for (int i = 0; i < 4; ++i)
        #pragma unroll
        for (int j = 0; j < 4; ++j) acc[i][j] = (f32x4){0.f, 0.f, 0.f, 0.f};

    for (int kc = 0; kc < K; kc += 32) {
        __syncthreads();
        #pragma unroll
        for (int i = 0; i < 8; ++i) {
            int c = t + i * 256;
            int idx = c & 511, m = idx >> 2, q = idx & 3;
            int plane = (c >> 9) & 1;
            const unsigned short* gsrc;
            unsigned short* ldst;
            if (c < 1024) {
                gsrc = (plane ? Xl : Xh) + (rowA + m) * K + kc + q * 8;
                ldst = &sA[plane][m * 40 + q * 8];
            } else {
                gsrc = (plane ? Xl : Xh) + (rowB + m) * K + kc + q * 8;
                ldst = &sB[plane][m * 40 + q * 8];
            }
            *(uint4*)ldst = *(const uint4*)gsrc;
        }
        __syncthreads();
        b16x8 ah[4], al[4], bh[4], bl[4];
        #pragma unroll
        for (int mt = 0; mt < 4; ++mt) {
            int off = (wm * 64 + mt * 16 + lm) * 40 + lq * 8;
            ah[mt] = *(const b16x8*)&sA[0][off];
            al[mt] = *(const b16x8*)&sA[1][off];
        }
        #pragma unroll
        for (int nt = 0; nt < 4; ++nt) {
            int off = (wn * 64 + nt * 16 + lm) * 40 + lq * 8;
            bh[nt] = *(const b16x8*)&sB[0][off];
            bl[nt] = *(const b16x8*)&sB[1][off];
        }
        #pragma unroll
        for (int mt = 0; mt < 4; ++mt)
            #pragma unroll
            for (int nt = 0; nt < 4; ++nt) {
                acc[mt][nt] = __builtin_amdgcn_mfma_f32_16x16x32_bf16(ah[mt], bh[nt], acc[mt][nt], 0, 0, 0);
                acc[mt][nt] = __builtin_amdgcn_mfma_f32_16x16x32_bf16(ah[mt], bl[nt], acc[mt][nt], 0, 0, 0);
                acc[mt][nt] = __builtin_amdgcn_mfma_f32_16x16x32_bf16(al[mt], bh[nt], acc[mt][nt], 0, 0, 0);
            }
    }
    // epilogue: n2[c] - 2*acc through LDS (32-row chunks) -> coalesced dwordx4 stores
    const float* n2c = n2 + bb * PPB + cb;
    float nv[4];
    #pragma unroll
    for (int nt = 0; nt < 4; ++nt) nv[nt] = n2c[wn * 64 + nt * 16 + lm];
    float* Dz = Dm + (size_t)blockIdx.z * PPB * PPB;
    #pragma unroll
    for (int ch = 0; ch < 4; ++ch) {
        __syncthreads();                         // staging / previous chunk consumed
        if (wm == (ch >> 1)) {
            const int mt0 = (ch & 1) * 2;
            #pragma unroll
            for (int mm = 0; mm < 2; ++mm) {
                #pragma unroll
                for (int nt = 0; nt < 4; ++nt)
                    #pragma unroll
                    for (int r = 0; r < 4; ++r)
                        tile[(mm * 16 + lq * 4 + r) * 132 + wn * 64 + nt * 16 + lm] =
                            nv[nt] - 2.f * acc[mt0 + mm][nt][r];
            }
        }
        __syncthreads();
        const int rowbase = rb + ch * 32;
        #pragma unroll
        for (int i = 0; i < 4; ++i) {
            int e = t + i * 256;
            int lr = e >> 5, c4 = (e & 31) * 4;
            *(float4*)&Dz[(size_t)(rowbase + lr) * PPB + cb + c4] = *(const float4*)&tile[lr * 132 + c4];
        }
    }
}

// ---------------- UV projection: split-bf16 MFMA (stages 2/3) ----------------
// C[16384 x N] = A(planes,[m][K]) @ Wt(planes,[n][K])^T; grid (128, N/128)
template<int K>
__global__ __launch_bounds__(256)
void gemm_uv_mfma(const unsigned short* __restrict__ Ah, const unsigned short* __restrict__ Al,
                  const unsigned short* __restrict__ Bh, const unsigned short* __restrict__ Bl,
                  float* __restrict__ C, int N) {
    __shared__ __align__(16) unsigned char smem[40960];
    unsigned short (*sA)[5120] = (unsigned short (*)[5120])smem;
    unsigned short (*sB)[5120] = (unsigned short (*)[5120])(smem + 20480);
    float* tile = (float*)smem;

    const int t = threadIdx.x;
    const int rb = blockIdx.x * 128, nb = blockIdx.y * 128;
    const int w = t >> 6, l = t & 63;
    const int wm = w & 1, wn = w >> 1;
    const int lm = l & 15, lq = l >> 4;

    f32x4 acc[4][4];
    #pragma unroll
    for (int i = 0; i < 4; ++i)
        #pragma unroll
        for (int j = 0; j < 4; ++j) acc[i][j] = (f32x4){0.f, 0.f, 0.f, 0.f};

    for (int kc = 0; kc < K; kc += 32) {
        __syncthreads();
        #pragma unroll
        for (int i = 0; i < 8; ++i) {
            int c = t + i * 256;
            int idx = c & 511, m = idx >> 2, q = idx & 3;
            int plane = (c >> 9) & 1;
            const unsigned short* gsrc;
            unsigned short* ldst;
            if (c < 1024) {
                gsrc = (plane ? Al : Ah) + (size_t)(rb + m) * K + kc + q * 8;
                ldst = &sA[plane][m * 40 + q * 8];
            } else {
                gsrc = (plane ? Bl : Bh) + (size_t)(nb + m) * K + kc + q * 8;
                ldst = &sB[plane][m * 40 + q * 8];
            }
            *(uint4*)ldst = *(const uint4*)gsrc;
        }
        __syncthreads();
        b16x8 ah[4], al[4], bh[4], bl[4];
        #pragma unroll
        for (int mt = 0; mt < 4; ++mt) {
            int off = (wm * 64 + mt * 16 + lm) * 40 + lq * 8;
            ah[mt] = *(const b16x8*)&sA[0][off];
            al[mt] = *(const b16x8*)&sA[1][off];
        }
        #pragma unroll
        for (int nt = 0; nt < 4; ++nt) {
            int off = (wn * 64 + nt * 16 + lm) * 40 + lq * 8;
            bh[nt] = *(const b16x8*)&sB[0][off];
            bl[nt] = *(const b16x8*)&sB[1][off];
        }
        #pragma unroll
        for (int mt = 0; mt < 4; ++mt)
            #pragma unroll
            for (int nt = 0; nt < 4; ++nt) {
                acc[mt][nt] = __builtin_amdgcn_mfma_f32_16x16x32_bf16(ah[mt], bh[nt], acc[mt][nt], 0, 0, 0);
                acc[mt][nt] = __builtin_amdgcn_mfma_f32_16x16x32_bf16(ah[mt], bl[nt], acc[mt][nt], 0, 0, 0);
                acc[mt][nt] = __builtin_amdgcn_mfma_f32_16x16x32_bf16(al[mt], bh[nt], acc[mt][nt], 0, 0, 0);
            }
    }
    #pragma unroll
    for (int ch = 0; ch < 4; ++ch) {
        __syncthreads();
        if (wm == (ch >> 1)) {
            const int mt0 = (ch & 1) * 2;
            #pragma unroll
            for (int mm = 0; mm < 2; ++mm) {
                #pragma unroll
                for (int nt = 0; nt < 4; ++nt)
                    #pragma unroll
                    for (int r = 0; r < 4; ++r)
                        tile[(mm * 16 + lq * 4 + r) * 132 + wn * 64 + nt * 16 + lm] =
                            acc[mt0 + mm][nt][r];
            }
        }
        __syncthreads();
        const int rowbase = rb + ch * 32;
        #pragma unroll
        for (int i = 0; i < 4; ++i) {
            int e = t + i * 256;
            int lr = e >> 5, c4 = (e & 31) * 4;
            *(float4*)&C[(size_t)(rowbase + lr) * N + nb + c4] = *(const float4*)&tile[lr * 132 + c4];
        }
    }
}

// ---------------- top-20 select: one wave per row, candidates in registers ----------------
__global__ __launch_bounds__(256)
void knn_select_kernel(const float* __restrict__ Dm, int* __restrict__ idxout, int batch0) {
    const int lane = threadIdx.x & 63;
    const int wid  = threadIdx.x >> 6;
    const int rowg = blockIdx.x * 4 + wid;
    const int z  = rowg >> 11, rl = rowg & 2047;
    const float* drow = Dm + (size_t)z * PPB * PPB + (size_t)rl * PPB;

    float c[32];
    #pragma unroll
    for (int j = 0; j < 8; ++j) {
        float4 v = *(const float4*)&drow[j * 256 + 4 * lane];
        c[4 * j + 0] = v.x; c[4 * j + 1] = v.y; c[4 * j + 2] = v.z; c[4 * j + 3] = v.w;
    }
    float mv = c[0]; int mj = 0;
    #pragma unroll
    for (int j = 1; j < 32; ++j) if (c[j] < mv) { mv = c[j]; mj = j; }
    int mq = ((mj >> 2) << 8) + 4 * lane + (mj & 3);

    int keep = 0;
    for (int round = 0; round < KNN; ++round) {
        float rv = mv; int rq = mq;
        #pragma unroll
        for (int m = 1; m < 64; m <<= 1) {
            float ov = __shfl_xor(rv, m, 64);
            int   oq = __shfl_xor(rq, m, 64);
            if (ov < rv || (ov == rv && oq < rq)) { rv = ov; rq = oq; }
        }
        if (lane == round) keep = rq;
        if (rv == mv && rq == mq) {
            #pragma unroll
            for (int j = 0; j < 32; ++j) if (j == mj) c[j] = 3.4e38f;
            mv = c[0]; mj = 0;
            #pragma unroll
            for (int j = 1; j < 32; ++j) if (c[j] < mv) { mv = c[j]; mj = j; }
            mq = ((mj >> 2) << 8) + 4 * lane + (mj & 3);
        }
    }
    const int pbase = (batch0 + z) * PPB;
    if (lane < KNN)
        idxout[(size_t)(pbase + rl) * KNN + lane] = pbase + keep;
}

// ---------------- fp32 tiled GEMM 128x128 (stage-1 UV only) ----------------
__global__ __launch_bounds__(256)
void gemm_uv_kernel(const float* __restrict__ A, const float* __restrict__ B,
                    float* __restrict__ C, int M, int N, int K) {
    __shared__ float As[16][132];
    __shared__ float Bs[16][132];
    const int t = threadIdx.x;
    const int tx = t & 15, ty = t >> 4;
    const int nb = blockIdx.y * 128;
    const int mb = blockIdx.x * 128;
    float acc[8][8];
    #pragma unroll
    for (int i = 0; i < 8; ++i)
        #pragma unroll
        for (int j = 0; j < 8; ++j) acc[i][j] = 0.f;

    for (int kc = 0; kc < K; kc += 16) {
        __syncthreads();
        for (int e = t; e < 512; e += 256) {
            int m = e >> 2, kq = e & 3;
            float4 v = *(const float4*)&A[(size_t)(mb + m) * K + kc + 4 * kq];
            As[4 * kq + 0][m] = v.x; As[4 * kq + 1][m] = v.y;
            As[4 * kq + 2][m] = v.z; As[4 * kq + 3][m] = v.w;
        }
        for (int e = t; e < 512; e += 256) {
            int kr = e >> 5, nq = e & 31;
            *(float4*)&Bs[kr][4 * nq] = *(const float4*)&B[(size_t)(kc + kr) * N + nb + 4 * nq];
        }
        __syncthreads();
        #pragma unroll
        for (int kk = 0; kk < 16; ++kk) {
            float4 a0 = *(const float4*)&As[kk][8 * ty];
            float4 a1 = *(const float4*)&As[kk][8 * ty + 4];
            float4 b0 = *(const float4*)&Bs[kk][4 * tx];
            float4 b1 = *(const float4*)&Bs[kk][64 + 4 * tx];
            float av[8] = {a0.x, a0.y, a0.z, a0.w, a1.x, a1.y, a1.z, a1.w};
            float bv[8] = {b0.x, b0.y, b0.z, b0.w, b1.x, b1.y, b1.z, b1.w};
            #pragma unroll
            for (int i = 0; i < 8; ++i)
                #pragma unroll
                for (int j = 0; j < 8; ++j) acc[i][j] += av[i] * bv[j];
        }
    }
    #pragma unroll
    for (int i = 0; i < 8; ++i) {
        float4 v0 = {acc[i][0], acc[i][1], acc[i][2], acc[i][3]};
        float4 v1 = {acc[i][4], acc[i][5], acc[i][6], acc[i][7]};
        *(float4*)&C[(size_t)(mb + 8 * ty + i) * N + nb + 4 * tx] = v0;
        *(float4*)&C[(size_t)(mb + 8 * ty + i) * N + nb + 64 + 4 * tx] = v1;
    }
}

// ---------------- fc1: split-bf16 MFMA GEMM + fused max-pool ----------------
__global__ __launch_bounds__(256)
void gemm_fc1_mfma(const unsigned short* __restrict__ Ah, const unsigned short* __restrict__ Al,
                   const unsigned short* __restrict__ Bh, const unsigned short* __restrict__ Bl,
                   const float* __restrict__ bias, unsigned* __restrict__ pool) {
    __shared__ unsigned short sA[2][128 * 40];
    __shared__ unsigned short sB[2][128 * 40];
    const int t = threadIdx.x;
    const int nb = blockIdx.y * 128, mb = blockIdx.x * 128;
    const int w = t >> 6, l = t & 63;
    const int wm = w & 1, wn = w >> 1;
    const int lm = l & 15, lq = l >> 4;

    f32x4 acc[4][4];
    #pragma unroll
    for (int i = 0; i < 4; ++i)
        #pragma unroll
        for (int j = 0; j < 4; ++j) acc[i][j] = (f32x4){0.f, 0.f, 0.f, 0.f};

    for (int kc = 0; kc < 448; kc += 32) {
        __syncthreads();
        #pragma unroll
        for (int i = 0; i < 8; ++i) {
            int c = t + i * 256;
            int idx = c & 511, m = idx >> 2, q = idx & 3;
            int plane = (c >> 9) & 1;
            const unsigned short* gsrc;
            unsigned short* ldst;
            if (c < 1024) {
                gsrc = (plane ? Al : Ah) + (size_t)(mb + m) * 448 + kc + q * 8;
                ldst = &sA[plane][m * 40 + q * 8];
            } else {
                gsrc = (plane ? Bl : Bh) + (size_t)(nb + m) * 448 + kc + q * 8;
                ldst = &sB[plane][m * 40 + q * 8];
            }
            *(uint4*)ldst = *(const uint4*)gsrc;
        }
        __syncthreads();
        b16x8 ah[4], al[4], bh[4], bl[4];
        #pragma unroll
        for (int mt = 0; mt < 4; ++mt) {
            int off = (wm * 64 + mt * 16 + lm) * 40 + lq * 8;
            ah[mt] = *(const b16x8*)&sA[0][off];
            al[mt] = *(const b16x8*)&sA[1][off];
        }
        #pragma unroll
        for (int nt = 0; nt < 4; ++nt) {
            int off = (wn * 64 + nt * 16 + lm) * 40 + lq * 8;
            bh[nt] = *(const b16x8*)&sB[0][off];
            bl[nt] = *(const b16x8*)&sB[1][off];
        }
        #pragma unroll
        for (int mt = 0; mt < 4; ++mt)
            #pragma unroll
            for (int nt = 0; nt < 4; ++nt) {
                acc[mt][nt] = __builtin_amdgcn_mfma_f32_16x16x32_bf16(ah[mt], bh[nt], acc[mt][nt], 0, 0, 0);
                acc[mt][nt] = __builtin_amdgcn_mfma_f32_16x16x32_bf16(ah[mt], bl[nt], acc[mt][nt], 0, 0, 0);
                acc[mt][nt] = __builtin_amdgcn_mfma_f32_16x16x32_bf16(al[mt], bh[nt], acc[mt][nt], 0, 0, 0);
            }
    }
    const int batch = blockIdx.x >> 4;
    #pragma unroll
    for (int nt = 0; nt < 4; ++nt) {
        float m0 = -3.4e38f;
        #pragma unroll
        for (int mt = 0; mt < 4; ++mt)
            #pragma unroll
            for (int r = 0; r < 4; ++r) m0 = fmaxf(m0, acc[mt][nt][r]);
        m0 = fmaxf(m0, __shfl_xor(m0, 16, 64));
        m0 = fmaxf(m0, __shfl_xor(m0, 32, 64));
        if (l < 16) {
            int col = nb + wn * 64 + nt * 16 + l;
            atomicMax(&pool[batch * 1024 + col], f2o(m0 + bias[col]));
        }
    }
}

// ---------------- edge-conv aggregate ----------------
__global__ void agg_kernel(const float* __restrict__ UV, const int* __restrict__ idx,
                           const float* __restrict__ bias, float* __restrict__ xo, int od) {
    const int p = ((blockIdx.x & 7) << 11) + (blockIdx.x >> 3);
    const int c = threadIdx.x;
    const float u = UV[(size_t)p * 2 * od + c];
    float m = -3.4e38f;
    #pragma unroll
    for (int k = 0; k < KNN; ++k) {
        int j = idx[p * KNN + k];
        m = fmaxf(m, UV[(size_t)j * 2 * od + od + c]);
    }
    xo[(size_t)p * od + c] = u + bias[c] + m;
}

// ---------------- head: split-k GEMM + per-column BN ----------------
template<int IND, int OD, int KSEG, bool UNMAP>
__global__ __launch_bounds__(256)
void head_gemm_k(const float* __restrict__ in, const float* __restrict__ W,
                 float* __restrict__ P) {
    const int KL = IND / KSEG;
    __shared__ float xs[8][IND / KSEG];
    const int t = threadIdx.x;
    const int kb = blockIdx.y * KL;
    const int cb = blockIdx.x * 64;
    for (int e = t; e < 8 * KL; e += 256) {
        int r = e / KL, k = e - r * KL;
        if (UNMAP) xs[r][k] = o2f(((const unsigned*)in)[r * IND + kb + k]);
        else       xs[r][k] = in[r * IND + kb + k];
    }
    __syncthreads();
    const int c = t & 63, rr = t >> 6;
    float a0 = 0.f, a1 = 0.f;
    #pragma unroll 4
    for (int k = 0; k < KL; ++k) {
        float wv = W[(size_t)(kb + k) * OD + cb + c];
        a0 += xs[2 * rr][k] * wv;
        a1 += xs[2 * rr + 1][k] * wv;
    }
    P[(size_t)(blockIdx.y * 8 + 2 * rr) * OD + cb + c]     = a0;
    P[(size_t)(blockIdx.y * 8 + 2 * rr + 1) * OD + cb + c] = a1;
}

template<int OD, int KSEG>
__global__ void head_bn2(const float* __restrict__ P, const float* __restrict__ bias,
                         const float* __restrict__ g, const float* __restrict__ be,
                         float* __restrict__ out) {
    const int c = blockIdx.x * 256 + threadIdx.x;
    float a[8];
    #pragma unroll
    for (int r = 0; r < 8; ++r) {
        float s = bias[c];
        #pragma unroll
        for (int ks = 0; ks < KSEG; ++ks) s += P[(size_t)(ks * 8 + r) * OD + c];
        a[r] = s;
    }
    float mu = 0.f;
    #pragma unroll
    for (int r = 0; r < 8; ++r) mu += a[r];
    mu *= 0.125f;
    float vr = 0.f;
    #pragma unroll
    for (int r = 0; r < 8; ++r) { float d = a[r] - mu; vr += d * d; }
    vr *= 0.125f;
    float is = rsqrtf(vr + 1e-5f) * g[c];
    #pragma unroll
    for (int r = 0; r < 8; ++r)
        out[r * OD + c] = fmaxf(is * (a[r] - mu) + be[c], 0.f);
}

// final Lin [8,256]@[256,23] + log_softmax
__global__ void head3_kernel(const float* __restrict__ x, const float* __restrict__ W,
                             const float* __restrict__ b, float* __restrict__ out) {
    __shared__ float xs[8 * 256];
    __shared__ float lg[8][23];
    __shared__ float red[8][2];
    const int t = threadIdx.x;
    for (int e = t; e < 2048; e += 256) xs[e] = x[e];
    __syncthreads();
    if (t < 184) {
        int r = t / 23, c = t - 23 * r;
        float a = b[c];
        for (int k = 0; k < 256; ++k) a += xs[r * 256 + k] * W[k * 23 + c];
        lg[r][c] = a;
    }
    __syncthreads();
    if (t < 8) {
        float mx = -3.4e38f;
        for (int c = 0; c < 23; ++c) mx = fmaxf(mx, lg[t][c]);
        float s = 0.f;
        for (int c = 0; c < 23; ++c) s += expf(lg[t][c] - mx);
        red[t][0] = mx; red[t][1] = logf(s);
    }
    __syncthreads();
    if (t < 184) {
        int r = t / 23, c = t - 23 * r;
        out[t] = lg[r][c] - red[r][0] - red[r][1];
    }
}

// ---------------- launcher ----------------
extern "C" void kernel_launch(void* const* d_in, const int* in_sizes, int n_in,
                              void* d_out, int out_size, void* d_ws, size_t ws_size,
                              hipStream_t stream) {
    (void)in_sizes; (void)n_in; (void)out_size; (void)ws_size;
    const float* pos = (const float*)d_in[0];
    const float* W1  = (const float*)d_in[2];  const float* b1  = (const float*)d_in[3];
    const float* W2  = (const float*)d_in[4];  const float* b2  = (const float*)d_in[5];
    const float* W3  = (const float*)d_in[6];  const float* b3  = (const float*)d_in[7];
    const float* Wf1 = (const float*)d_in[8];  const float* bf1 = (const float*)d_in[9];
    const float* Wa  = (const float*)d_in[10]; const float* ba  = (const float*)d_in[11];
    const float* ga  = (const float*)d_in[12]; const float* bea = (const float*)d_in[13];
    const float* Wb  = (const float*)d_in[14]; const float* bb  = (const float*)d_in[15];
    const float* gb  = (const float*)d_in[16]; const float* beb = (const float*)d_in[17];
    const float* Wc  = (const float*)d_in[18]; const float* bc  = (const float*)d_in[19];

    char* ws = (char*)d_ws;
    float*    x0p  = (float*)(ws + OFF_X0P);
    float*    n2   = (float*)(ws + OFF_N2);
    int*      idx  = (int*)(ws + OFF_IDX);
    float*    wuv1 = (float*)(ws + OFF_WUV1);
    unsigned* pool = (unsigned*)(ws + OFF_POOL);
    float*    C1   = (float*)(ws + OFF_C1);
    float*    C2   = (float*)(ws + OFF_C2);
    float*    x1   = (float*)(ws + OFF_X1);
    float*    x2   = (float*)(ws + OFF_X2);
    float*    x3   = (float*)(ws + OFF_X3);
    float*    UV   = (float*)(ws + OFF_UV);
    float*    Dm   = (float*)(ws + OFF_UV);
    float*    P1   = (float*)(ws + OFF_P1);
    float*    P2   = (float*)(ws + OFF_P2);
    unsigned short* Xph  = (unsigned short*)(ws + OFF_XPH);
    unsigned short* Xpl  = (unsigned short*)(ws + OFF_XPL);
    unsigned short* Apkh = (unsigned short*)(ws + OFF_APKH);
    unsigned short* Apkl = (unsigned short*)(ws + OFF_APKL);
    unsigned short* Bth  = (unsigned short*)(ws + OFF_BTH);
    unsigned short* Btl  = (unsigned short*)(ws + OFF_BTL);
    unsigned short* Wt2h = (unsigned short*)(ws + OFF_WT2H);
    unsigned short* Wt2l = (unsigned short*)(ws + OFF_WT2L);
    unsigned short* Wt3h = (unsigned short*)(ws + OFF_WT3H);
    unsigned short* Wt3l = (unsigned short*)(ws + OFF_WT3L);

    // prep
    build_x0p_kernel<<<1024, 256, 0, stream>>>(pos, x0p);
    wuv_build_kernel<<<8, 256, 0, stream>>>(W1, wuv1, 3, 16, 64);
    init_pool_kernel<<<32, 256, 0, stream>>>(pool);

    // edge conv 1 (d=3 padded to 16 -> 64), fp32 distance GEMM
    sqnorm_kernel<16><<<64, 256, 0, stream>>>(x0p, n2);
    for (int r0 = 0; r0 < 8; r0 += 2) {
        gemm_d_kernel<16><<<dim3(16, 16, 2), 256, 0, stream>>>(x0p, n2, Dm, r0);
        knn_select_kernel<<<1024, 256, 0, stream>>>(Dm, idx, r0);
    }
    gemm_uv_kernel<<<dim3(128, 1), 256, 0, stream>>>(x0p, wuv1, UV, NPTS, 128, 16);
    agg_kernel<<<NPTS, 64, 0, stream>>>(UV, idx, b1, x1, 64);

    // x0p region dead from here: pack W^T planes for stages 2/3
    packWt_kernel<<<64,  256, 0, stream>>>(W2, Wt2h, Wt2l, 64,  64,  128);
    packWt_kernel<<<256, 256, 0, stream>>>(W3, Wt3h, Wt3l, 128, 128, 256);

    // edge conv 2 (64 -> 128), MFMA distance GEMM + MFMA UV
    sqnorm_kernel<64><<<64, 256, 0, stream>>>(x1, n2);
    packX_kernel<<<1024, 256, 0, stream>>>(x1, Xph, Xpl);
    for (int r0 = 0; r0 < 8; r0 += 2) {
        gemm_dm_kernel<64><<<dim3(16, 16, 2), 256, 0, stream>>>(Xph, Xpl, n2, Dm, r0);
        knn_select_kernel<<<1024, 256, 0, stream>>>(Dm, idx, r0);
    }
    gemm_uv_mfma<64><<<dim3(128, 2), 256, 0, stream>>>(Xph, Xpl, Wt2h, Wt2l, UV, 256);
    agg_kernel<<<NPTS, 128, 0, stream>>>(UV, idx, b2, x2, 128);

    // edge conv 3 (128 -> 256), MFMA distance GEMM + MFMA UV
    sqnorm_kernel<128><<<64, 256, 0, stream>>>(x2, n2);
    packX_kernel<<<2048, 256, 0, stream>>>(x2, Xph, Xpl);
    for (int r0 = 0; r0 < 8; r0 += 2) {
        gemm_dm_kernel<128><<<dim3(16, 16, 2), 256, 0, stream>>>(Xph, Xpl, n2, Dm, r0);
        knn_select_kernel<<<1024, 256, 0, stream>>>(Dm, idx, r0);
    }
    gemm_uv_mfma<128><<<dim3(128, 4), 256, 0, stream>>>(Xph, Xpl, Wt3h, Wt3l, UV, 512);
    agg_kernel<<<NPTS, 256, 0, stream>>>(UV, idx, b3, x3, 256);

    // fc1 (MFMA) + fused max pool
    packA_kernel<<<7168, 256, 0, stream>>>(x1, x2, x3, Apkh, Apkl);
    packB_kernel<<<448,  256, 0, stream>>>(Wf1, Bth, Btl);
    gemm_fc1_mfma<<<dim3(128, 8), 256, 0, stream>>>(Apkh, Apkl, Bth, Btl, bf1, pool);

    // head: split-k GEMM + BN
    head_gemm_k<1024, 512, 8, true ><<<dim3(8, 8), 256, 0, stream>>>((const float*)pool, Wa, P1);
    head_bn2<512, 8><<<2, 256, 0, stream>>>(P1, ba, ga, bea, C1);
    head_gemm_k<512, 256, 4, false><<<dim3(4, 4), 256, 0, stream>>>(C1, Wb, P2);
    head_bn2<256, 4><<<1, 256, 0, stream>>>(P2, bb, gb, beb, C2);
    head3_kernel<<<1, 256, 0, stream>>>(C2, Wc, bc, (float*)d_out);
}

// Round 8
// 885.053 us; speedup vs baseline: 2.6177x; 1.0816x over previous
//
#include <hip/hip_runtime.h>
#include <math.h>

#define NPTS 16384
#define PPB  2048
#define KNN  20

// ---------------- workspace layout (bytes), total 64 MiB ----------------
// region [0, 1 MB): Wt planes (stages 1-3), later fc1 Bt planes (overlap into n2/idx ok, dead then)
#define OFF_WT1H  0u
#define OFF_WT1L  8192u
#define OFF_WT2H  16384u
#define OFF_WT2L  49152u
#define OFF_WT3H  81920u
#define OFF_WT3L  212992u
#define OFF_N2    1048576u
#define OFF_IDX   1114112u     // 16384*20*4
#define OFF_POOL  2760704u     // 8192*4
#define OFF_C1    2793472u
#define OFF_C2    2809856u
#define OFF_X1    4194304u     // 16384*64*4  (dead after packA; reused by head partials)
#define OFF_P1    4194304u
#define OFF_P2    4325376u
#define OFF_X2    8388608u     // 16384*128*4
#define OFF_X3    16777216u    // 16384*256*4 (holds X bf16 planes until agg-3 writes x3)
#define OFF_XPH   16777216u
#define OFF_XPL   25165824u
#define OFF_UV    33554432u    // U|V per stage -> packed-A planes for fc1
#define OFF_APKH  33554432u
#define OFF_APKL  48234496u
#define OFF_BTH   0u
#define OFF_BTL   917504u

typedef __attribute__((ext_vector_type(8))) short b16x8;
typedef __attribute__((ext_vector_type(4))) float f32x4;

__device__ __forceinline__ unsigned f2o(float f) {
    unsigned u = __float_as_uint(f);
    return (u & 0x80000000u) ? ~u : (u | 0x80000000u);
}
__device__ __forceinline__ float o2f(unsigned u) {
    return (u & 0x80000000u) ? __uint_as_float(u & 0x7fffffffu) : __uint_as_float(~u);
}

// split fp32 -> (hi, lo) bf16 pair, RNE both; x ~= hi + lo to ~2^-18 rel
__device__ __forceinline__ void split_bf16(float x, unsigned short& h, unsigned short& l) {
    unsigned u = __float_as_uint(x);
    unsigned rh = (u + 0x7fffu + ((u >> 16) & 1u)) & 0xffff0000u;
    h = (unsigned short)(rh >> 16);
    float r = x - __uint_as_float(rh);
    unsigned v = __float_as_uint(r);
    l = (unsigned short)((v + 0x7fffu + ((v >> 16) & 1u)) >> 16);
}

// register top-20 insert (R0-verified): replace worst slot, rescan for new worst
__device__ __forceinline__ void topk_insert(float (&bd)[KNN], int (&bi)[KNN],
                                            float& worst, int& wslot, float v, int q) {
    #pragma unroll
    for (int s = 0; s < KNN; ++s) if (s == wslot) { bd[s] = v; bi[s] = q; }
    float w = bd[0]; int sl = 0;
    #pragma unroll
    for (int s = 1; s < KNN; ++s) if (bd[s] > w) { w = bd[s]; sl = s; }
    worst = w; wslot = sl;
}

// ---------------- prep kernels ----------------
__global__ void init_pool_kernel(unsigned* __restrict__ pool) {
    pool[blockIdx.x * 256 + threadIdx.x] = 0u;
}

template<int D>
__global__ void sqnorm_kernel(const float* __restrict__ X, float* __restrict__ n2) {
    int p = blockIdx.x * 256 + threadIdx.x;
    float s = 0.f;
    #pragma unroll
    for (int k = 0; k < D; k += 4) {
        float4 v = *(const float4*)&X[(size_t)p * D + k];
        s += v.x * v.x + v.y * v.y + v.z * v.z + v.w * v.w;
    }
    n2[p] = s;
}

// stage-1: pos [16384][3] -> bf16 hi/lo planes [16384][32] (cols 3..31 zero) + n2
__global__ void packX0_kernel(const float* __restrict__ pos,
                              unsigned short* __restrict__ Xh, unsigned short* __restrict__ Xl,
                              float* __restrict__ n2) {
    int p = blockIdx.x * 256 + threadIdx.x;
    float x = pos[p * 3 + 0], y = pos[p * 3 + 1], z = pos[p * 3 + 2];
    n2[p] = x * x + y * y + z * z;
    ushort4 h = {0, 0, 0, 0}, l = {0, 0, 0, 0};
    split_bf16(x, h.x, l.x); split_bf16(y, h.y, l.y); split_bf16(z, h.z, l.z);
    ushort4 zed = {0, 0, 0, 0};
    *(ushort4*)&Xh[(size_t)p * 32] = h;
    *(ushort4*)&Xl[(size_t)p * 32] = l;
    #pragma unroll
    for (int c = 4; c < 32; c += 4) {
        *(ushort4*)&Xh[(size_t)p * 32 + c] = zed;
        *(ushort4*)&Xl[(size_t)p * 32 + c] = zed;
    }
}

// pack X [16384 x K] fp32 -> bf16 hi/lo planes
__global__ void packX_kernel(const float* __restrict__ X,
                             unsigned short* __restrict__ Xh, unsigned short* __restrict__ Xl) {
    int e = blockIdx.x * 256 + threadIdx.x;
    float4 v = *(const float4*)&X[4 * (size_t)e];
    ushort4 h, l;
    split_bf16(v.x, h.x, l.x); split_bf16(v.y, h.y, l.y);
    split_bf16(v.z, h.z, l.z); split_bf16(v.w, h.w, l.w);
    *(ushort4*)&Xh[4 * (size_t)e] = h;
    *(ushort4*)&Xl[4 * (size_t)e] = l;
}

// W [2d][od] -> W^T hi/lo planes [2od][dpad]: n<od: U = W_top - W_bot; else V = W_bot
__global__ void packWt_kernel(const float* __restrict__ W,
                              unsigned short* __restrict__ Bh, unsigned short* __restrict__ Bl,
                              int d, int dpad, int od) {
    int e = blockIdx.x * 256 + threadIdx.x;       // < 2*od*dpad
    int n = e / dpad, k = e - n * dpad;
    float v = 0.f;
    if (k < d) v = (n < od) ? (W[k * od + n] - W[(d + k) * od + n])
                            : W[(d + k) * od + (n - od)];
    unsigned short h, l;
    split_bf16(v, h, l);
    Bh[e] = h; Bl[e] = l;
}

// pack A = concat(x1,x2,x3) [16384 x 448] into bf16 hi/lo planes
__global__ void packA_kernel(const float* __restrict__ x1, const float* __restrict__ x2,
                             const float* __restrict__ x3,
                             unsigned short* __restrict__ Ah, unsigned short* __restrict__ Al) {
    int e = blockIdx.x * 256 + threadIdx.x;
    int m = e / 112, c4 = (e - m * 112) * 4;
    float4 v;
    if (c4 < 64)       v = *(const float4*)&x1[(size_t)m * 64 + c4];
    else if (c4 < 192) v = *(const float4*)&x2[(size_t)m * 128 + (c4 - 64)];
    else               v = *(const float4*)&x3[(size_t)m * 256 + (c4 - 192)];
    ushort4 h, l;
    split_bf16(v.x, h.x, l.x); split_bf16(v.y, h.y, l.y);
    split_bf16(v.z, h.z, l.z); split_bf16(v.w, h.w, l.w);
    *(ushort4*)&Ah[(size_t)m * 448 + c4] = h;
    *(ushort4*)&Al[(size_t)m * 448 + c4] = l;
}

// pack Wf1^T [1024 x 448] into bf16 hi/lo planes
__global__ void packB_kernel(const float* __restrict__ Wf1,
                             unsigned short* __restrict__ Bh, unsigned short* __restrict__ Bl) {
    int e = blockIdx.x * 256 + threadIdx.x;
    int n = e / 112, k4 = (e - n * 112) * 4;
    ushort4 h, l;
    float v0 = Wf1[(size_t)(k4 + 0) * 1024 + n];
    float v1 = Wf1[(size_t)(k4 + 1) * 1024 + n];
    float v2 = Wf1[(size_t)(k4 + 2) * 1024 + n];
    float v3 = Wf1[(size_t)(k4 + 3) * 1024 + n];
    split_bf16(v0, h.x, l.x); split_bf16(v1, h.y, l.y);
    split_bf16(v2, h.z, l.z); split_bf16(v3, h.w, l.w);
    *(ushort4*)&Bh[(size_t)n * 448 + k4] = h;
    *(ushort4*)&Bl[(size_t)n * 448 + k4] = l;
}

// ---------------- fused kNN: MFMA distances + register top-20, one dispatch/stage ----------------
// block: 32 rows x 2048 candidates. 16 col-chunks of 128. 4 waves: wave w owns cols
// [w*32, w*32+32) (2 col-tiles) x 32 rows (2 row-tiles). Select: 8 threads/row,
// each scans 16 cols/chunk from the LDS distance tile into a register top-20.
template<int K>
__global__ __launch_bounds__(256)
void knn_fused_kernel(const unsigned short* __restrict__ Xh, const unsigned short* __restrict__ Xl,
                      const float* __restrict__ n2, int* __restrict__ idxout) {
    __shared__ __align__(16) unsigned char smem[42496];
    unsigned short (*sA)[1280] = (unsigned short (*)[1280])smem;             // [2][32*40]
    unsigned short (*sB)[5120] = (unsigned short (*)[5120])(smem + 5120);    // [2][128*40]
    float* Ds = (float*)(smem + 25600);                                      // 32 x 132

    const int t = threadIdx.x;
    const int rb = blockIdx.x * 32;
    const int qbase = (rb >> 11) << 11;             // batch-local candidates
    const int w = t >> 6, l = t & 63;
    const int lm = l & 15, lq = l >> 4;
    const int r = t >> 3, sub = t & 7;              // select mapping

    float bd[KNN]; int bi[KNN];
    #pragma unroll
    for (int s = 0; s < KNN; ++s) { bd[s] = 3.0e38f; bi[s] = 0; }
    float worst = 3.0e38f; int wslot = 0;

    for (int qt = 0; qt < 16; ++qt) {
        const int qb = qbase + qt * 128;
        f32x4 acc[2][2];
        #pragma unroll
        for (int i = 0; i < 2; ++i)
            #pragma unroll
            for (int j = 0; j < 2; ++j) acc[i][j] = (f32x4){0.f, 0.f, 0.f, 0.f};

        for (int kc = 0; kc < K; kc += 32) {
            __syncthreads();                        // sB consumers done
            #pragma unroll
            for (int i = 0; i < 5; ++i) {           // 1280 16B chunks: A 256, B 1024
                int c = t + i * 256;
                const unsigned short* gsrc;
                unsigned short* ldst;
                if (c < 256) {
                    int idx = c & 127, m = idx >> 2, q = idx & 3;
                    int plane = (c >> 7) & 1;
                    gsrc = (plane ? Xl : Xh) + (size_t)(rb + m) * K + kc + q * 8;
                    ldst = &sA[plane][m * 40 + q * 8];
                } else {
                    int c2 = c - 256;
                    int idx = c2 & 511, m = idx >> 2, q = idx & 3;
                    int plane = c2 >> 9;
                    gsrc = (plane ? Xl : Xh) + (size_t)(qb + m) * K + kc + q * 8;
                    ldst = &sB[plane][m * 40 + q * 8];
                }
                *(uint4*)ldst = *(const uint4*)gsrc;
            }
            __syncthreads();
            b16x8 ah[2], al[2], bh[2], bl[2];
            #pragma unroll
            for (int rt = 0; rt < 2; ++rt) {
                int off = (rt * 16 + lm) * 40 + lq * 8;
                ah[rt] = *(const b16x8*)&sA[0][off];
                al[rt] = *(const b16x8*)&sA[1][off];
            }
            #pragma unroll
            for (int ct = 0; ct < 2; ++ct) {
                int off = (w * 32 + ct * 16 + lm) * 40 + lq * 8;
                bh[ct] = *(const b16x8*)&sB[0][off];
                bl[ct] = *(const b16x8*)&sB[1][off];
            }
            #pragma unroll
            for (int rt = 0; rt < 2; ++rt)
                #pragma unroll
                for (int ct = 0; ct < 2; ++ct) {
                    acc[rt][ct] = __builtin_amdgcn_mfma_f32_16x16x32_bf16(ah[rt], bh[ct], acc[rt][ct], 0, 0, 0);
                    acc[rt][ct] = __builtin_amdgcn_mfma_f32_16x16x32_bf16(ah[rt], bl[ct], acc[rt][ct], 0, 0, 0);
                    acc[rt][ct] = __builtin_amdgcn_mfma_f32_16x16x32_bf16(al[rt], bh[ct], acc[rt][ct], 0, 0, 0);
                }
        }
        float nv[2];
        #pragma unroll
        for (int ct = 0; ct < 2; ++ct) nv[ct] = n2[qb + w * 32 + ct * 16 + lm];
        __syncthreads();                            // previous select done reading Ds
        #pragma unroll
        for (int rt = 0; rt < 2; ++rt)
            #pragma unroll
            for (int ct = 0; ct < 2; ++ct)
                #pragma unroll
                for (int rr = 0; rr < 4; ++rr)
                    Ds[(rt * 16 + lq * 4 + rr) * 132 + w * 32 + ct * 16 + lm] =
                        nv[ct] - 2.f * acc[rt][ct][rr];
        __syncthreads();
        // select: thread (r, sub) scans cols [16*sub, 16*sub+16) of row r
        const int q0 = qt * 128 + 16 * sub;
        #pragma unroll
        for (int c4 = 0; c4 < 4; ++c4) {
            float4 v = *(const float4*)&Ds[r * 132 + 16 * sub + 4 * c4];
            float vv[4] = {v.x, v.y, v.z, v.w};
            #pragma unroll
            for (int j = 0; j < 4; ++j)
                if (vv[j] < worst) topk_insert(bd, bi, worst, wslot, vv[j], q0 + 4 * c4 + j);
        }
    }

    // merge 8 register lists of 20 -> top-20 per row (R1-verified pattern)
    __syncthreads();
    int* DsI = (int*)Ds;                            // row stride 132 ints
    float mv = 3.3e38f; int mq = 1 << 20, mj = 0;
    #pragma unroll
    for (int s = 0; s < KNN; ++s) {
        float x = bd[s]; int q = bi[s];
        if (x < mv || (x == mv && q < mq)) { mv = x; mq = q; mj = s; }
    }
    for (int round = 0; round < KNN; ++round) {
        float rv = mv; int rq = mq;
        #pragma unroll
        for (int m = 1; m < 8; m <<= 1) {
            float ov = __shfl_xor(rv, m, 64);
            int   oq = __shfl_xor(rq, m, 64);
            if (ov < rv || (ov == rv && oq < rq)) { rv = ov; rq = oq; }
        }
        if (sub == 0) DsI[r * 132 + round] = rq;
        if (mv == rv && mq == rq) {                 // I own the winner: consume + rescan
            #pragma unroll
            for (int s = 0; s < KNN; ++s) if (s == mj) bd[s] = 3.3e38f;
            mv = 3.3e38f; mq = 1 << 20; mj = 0;
            #pragma unroll
            for (int s = 0; s < KNN; ++s) {
                float x = bd[s]; int q = bi[s];
                if (x < mv || (x == mv && q < mq)) { mv = x; mq = q; mj = s; }
            }
        }
    }
    // same-wave visibility within each 8-lane row group: no barrier needed
    for (int s = sub; s < KNN; s += 8)
        idxout[(size_t)(rb + r) * KNN + s] = qbase + DsI[r * 132 + s];
}

// ---------------- UV projection: split-bf16 MFMA (all stages) ----------------
// C[16384 x N] = A(planes,[m][K]) @ Wt(planes,[n][K])^T; grid (128, N/128)
template<int K>
__global__ __launch_bounds__(256)
void gemm_uv_mfma(const unsigned short* __restrict__ Ah, const unsigned short* __restrict__ Al,
                  const unsigned short* __restrict__ Bh, const unsigned short* __restrict__ Bl,
                  float* __restrict__ C, int N) {
    __shared__ __align__(16) unsigned char smem[40960];
    unsigned short (*sA)[5120] = (unsigned short (*)[5120])smem;
    unsigned short (*sB)[5120] = (unsigned short (*)[5120])(smem + 20480);
    float* tile = (float*)smem;

    const int t = threadIdx.x;
    const int rb = blockIdx.x * 128, nb = blockIdx.y * 128;
    const int w = t >> 6, l = t & 63;
    const int wm = w & 1, wn = w >> 1;
    const int lm = l & 15, lq = l >> 4;

    f32x4 acc[4][4];
    #pragma unroll
    for (int i = 0; i < 4; ++i)
        #pragma unroll
        for (int j = 0; j < 4; ++j) acc[i][j] = (f32x4){0.f, 0.f, 0.f, 0.f};

    for (int kc = 0; kc < K; kc += 32) {
        __syncthreads();
        #pragma unroll
        for (int i = 0; i < 8; ++i) {
            int c = t + i * 256;
            int idx = c & 511, m = idx >> 2, q = idx & 3;
            int plane = (c >> 9) & 1;
            const unsigned short* gsrc;
            unsigned short* ldst;
            if (c < 1024) {
                gsrc = (plane ? Al : Ah) + (size_t)(rb + m) * K + kc + q * 8;
                ldst = &sA[plane][m * 40 + q * 8];
            } else {
                gsrc = (plane ? Bl : Bh) + (size_t)(nb + m) * K + kc + q * 8;
                ldst = &sB[plane][m * 40 + q * 8];
            }
            *(uint4*)ldst = *(const uint4*)gsrc;
        }
        __syncthreads();
        b16x8 ah[4], al[4], bh[4], bl[4];
        #pragma unroll
        for (int mt = 0; mt < 4; ++mt) {
            int off = (wm * 64 + mt * 16 + lm) * 40 + lq * 8;
            ah[mt] = *(const b16x8*)&sA[0][off];
            al[mt] = *(const b16x8*)&sA[1][off];
        }
        #pragma unroll
        for (int nt = 0; nt < 4; ++nt) {
            int off = (wn * 64 + nt * 16 + lm) * 40 + lq * 8;
            bh[nt] = *(const b16x8*)&sB[0][off];
            bl[nt] = *(const b16x8*)&sB[1][off];
        }
        #pragma unroll
        for (int mt = 0; mt < 4; ++mt)
            #pragma unroll
            for (int nt = 0; nt < 4; ++nt) {
                acc[mt][nt] = __builtin_amdgcn_mfma_f32_16x16x32_bf16(ah[mt], bh[nt], acc[mt][nt], 0, 0, 0);
                acc[mt][nt] = __builtin_amdgcn_mfma_f32_16x16x32_bf16(ah[mt], bl[nt], acc[mt][nt], 0, 0, 0);
                acc[mt][nt] = __builtin_amdgcn_mfma_f32_16x16x32_bf16(al[mt], bh[nt], acc[mt][nt], 0, 0, 0);
            }
    }
    #pragma unroll
    for (int ch = 0; ch < 4; ++ch) {
        __syncthreads();
        if (wm == (ch >> 1)) {
            const int mt0 = (ch & 1) * 2;
            #pragma unroll
            for (int mm = 0; mm < 2; ++mm) {
                #pragma unroll
                for (int nt = 0; nt < 4; ++nt)
                    #pragma unroll
                    for (int rr = 0; rr < 4; ++rr)
                        tile[(mm * 16 + lq * 4 + rr) * 132 + wn * 64 + nt * 16 + lm] =
                            acc[mt0 + mm][nt][rr];
            }
        }
        __syncthreads();
        const int rowbase = rb + ch * 32;
        #pragma unroll
        for (int i = 0; i < 4; ++i) {
            int e = t + i * 256;
            int lr = e >> 5, c4 = (e & 31) * 4;
            *(float4*)&C[(size_t)(rowbase + lr) * N + nb + c4] = *(const float4*)&tile[lr * 132 + c4];
        }
    }
}

// ---------------- fc1: split-bf16 MFMA GEMM + fused max-pool ----------------
__global__ __launch_bounds__(256)
void gemm_fc1_mfma(const unsigned short* __restrict__ Ah, const unsigned short* __restrict__ Al,
                   const unsigned short* __restrict__ Bh, const unsigned short* __restrict__ Bl,
                   const float* __restrict__ bias, unsigned* __restrict__ pool) {
    __shared__ unsigned short sA[2][128 * 40];
    __shared__ unsigned short sB[2][128 * 40];
    const int t = threadIdx.x;
    const int nb = blockIdx.y * 128, mb = blockIdx.x * 128;
    const int w = t >> 6, l = t & 63;
    const int wm = w & 1, wn = w >> 1;
    const int lm = l & 15, lq = l >> 4;

    f32x4 acc[4][4];
    #pragma unroll
    for (int i = 0; i < 4; ++i)
        #pragma unroll
        for (int j = 0; j < 4; ++j) acc[i][j] = (f32x4){0.f, 0.f, 0.f, 0.f};

    for (int kc = 0; kc < 448; kc += 32) {
        __syncthreads();
        #pragma unroll
        for (int i = 0; i < 8; ++i) {
            int c = t + i * 256;
            int idx = c & 511, m = idx >> 2, q = idx & 3;
            int plane = (c >> 9) & 1;
            const unsigned short* gsrc;
            unsigned short* ldst;
            if (c < 1024) {
                gsrc = (plane ? Al : Ah) + (size_t)(mb + m) * 448 + kc + q * 8;
                ldst = &sA[plane][m * 40 + q * 8];
            } else {
                gsrc = (plane ? Bl : Bh) + (size_t)(nb + m) * 448 + kc + q * 8;
                ldst = &sB[plane][m * 40 + q * 8];
            }
            *(uint4*)ldst = *(const uint4*)gsrc;
        }
        __syncthreads();
        b16x8 ah[4], al[4], bh[4], bl[4];
        #pragma unroll
        for (int mt = 0; mt < 4; ++mt) {
            int off = (wm * 64 + mt * 16 + lm) * 40 + lq * 8;
            ah[mt] = *(const b16x8*)&sA[0][off];
            al[mt] = *(const b16x8*)&sA[1][off];
        }
        #pragma unroll
        for (int nt = 0; nt < 4; ++nt) {
            int off = (wn * 64 + nt * 16 + lm) * 40 + lq * 8;
            bh[nt] = *(const b16x8*)&sB[0][off];
            bl[nt] = *(const b16x8*)&sB[1][off];
        }
        #pragma unroll
        for (int mt = 0; mt < 4; ++mt)
            #pragma unroll
            for (int nt = 0; nt < 4; ++nt) {
                acc[mt][nt] = __builtin_amdgcn_mfma_f32_16x16x32_bf16(ah[mt], bh[nt], acc[mt][nt], 0, 0, 0);
                acc[mt][nt] = __builtin_amdgcn_mfma_f32_16x16x32_bf16(ah[mt], bl[nt], acc[mt][nt], 0, 0, 0);
                acc[mt][nt] = __builtin_amdgcn_mfma_f32_16x16x32_bf16(al[mt], bh[nt], acc[mt][nt], 0, 0, 0);
            }
    }
    const int batch = blockIdx.x >> 4;
    #pragma unroll
    for (int nt = 0; nt < 4; ++nt) {
        float m0 = -3.4e38f;
        #pragma unroll
        for (int mt = 0; mt < 4; ++mt)
            #pragma unroll
            for (int rr = 0; rr < 4; ++rr) m0 = fmaxf(m0, acc[mt][nt][rr]);
        m0 = fmaxf(m0, __shfl_xor(m0, 16, 64));
        m0 = fmaxf(m0, __shfl_xor(m0, 32, 64));
        if (l < 16) {
            int col = nb + wn * 64 + nt * 16 + l;
            atomicMax(&pool[batch * 1024 + col], f2o(m0 + bias[col]));
        }
    }
}

// ---------------- edge-conv aggregate ----------------
__global__ void agg_kernel(const float* __restrict__ UV, const int* __restrict__ idx,
                           const float* __restrict__ bias, float* __restrict__ xo, int od) {
    const int p = ((blockIdx.x & 7) << 11) + (blockIdx.x >> 3);
    const int c = threadIdx.x;
    const float u = UV[(size_t)p * 2 * od + c];
    float m = -3.4e38f;
    #pragma unroll
    for (int k = 0; k < KNN; ++k) {
        int j = idx[p * KNN + k];
        m = fmaxf(m, UV[(size_t)j * 2 * od + od + c]);
    }
    xo[(size_t)p * od + c] = u + bias[c] + m;
}

// ---------------- head: split-k GEMM + per-column BN ----------------
template<int IND, int OD, int KSEG, bool UNMAP>
__global__ __launch_bounds__(256)
void head_gemm_k(const float* __restrict__ in, const float* __restrict__ W,
                 float* __restrict__ P) {
    const int KL = IND / KSEG;
    __shared__ float xs[8][IND / KSEG];
    const int t = threadIdx.x;
    const int kb = blockIdx.y * KL;
    const int cb = blockIdx.x * 64;
    for (int e = t; e < 8 * KL; e += 256) {
        int r = e / KL, k = e - r * KL;
        if (UNMAP) xs[r][k] = o2f(((const unsigned*)in)[r * IND + kb + k]);
        else       xs[r][k] = in[r * IND + kb + k];
    }
    __syncthreads();
    const int c = t & 63, rr = t >> 6;
    float a0 = 0.f, a1 = 0.f;
    #pragma unroll 4
    for (int k = 0; k < KL; ++k) {
        float wv = W[(size_t)(kb + k) * OD + cb + c];
        a0 += xs[2 * rr][k] * wv;
        a1 += xs[2 * rr + 1][k] * wv;
    }
    P[(size_t)(blockIdx.y * 8 + 2 * rr) * OD + cb + c]     = a0;
    P[(size_t)(blockIdx.y * 8 + 2 * rr + 1) * OD + cb + c] = a1;
}

template<int OD, int KSEG>
__global__ void head_bn2(const float* __restrict__ P, const float* __restrict__ bias,
                         const float* __restrict__ g, const float* __restrict__ be,
                         float* __restrict__ out) {
    const int c = blockIdx.x * 256 + threadIdx.x;
    float a[8];
    #pragma unroll
    for (int r = 0; r < 8; ++r) {
        float s = bias[c];
        #pragma unroll
        for (int ks = 0; ks < KSEG; ++ks) s += P[(size_t)(ks * 8 + r) * OD + c];
        a[r] = s;
    }
    float mu = 0.f;
    #pragma unroll
    for (int r = 0; r < 8; ++r) mu += a[r];
    mu *= 0.125f;
    float vr = 0.f;
    #pragma unroll
    for (int r = 0; r < 8; ++r) { float d = a[r] - mu; vr += d * d; }
    vr *= 0.125f;
    float is = rsqrtf(vr + 1e-5f) * g[c];
    #pragma unroll
    for (int r = 0; r < 8; ++r)
        out[r * OD + c] = fmaxf(is * (a[r] - mu) + be[c], 0.f);
}

// final Lin [8,256]@[256,23] + log_softmax
__global__ void head3_kernel(const float* __restrict__ x, const float* __restrict__ W,
                             const float* __restrict__ b, float* __restrict__ out) {
    __shared__ float xs[8 * 256];
    __shared__ float lg[8][23];
    __shared__ float red[8][2];
    const int t = threadIdx.x;
    for (int e = t; e < 2048; e += 256) xs[e] = x[e];
    __syncthreads();
    if (t < 184) {
        int r = t / 23, c = t - 23 * r;
        float a = b[c];
        for (int k = 0; k < 256; ++k) a += xs[r * 256 + k] * W[k * 23 + c];
        lg[r][c] = a;
    }
    __syncthreads();
    if (t < 8) {
        float mx = -3.4e38f;
        for (int c = 0; c < 23; ++c) mx = fmaxf(mx, lg[t][c]);
        float s = 0.f;
        for (int c = 0; c < 23; ++c) s += expf(lg[t][c] - mx);
        red[t][0] = mx; red[t][1] = logf(s);
    }
    __syncthreads();
    if (t < 184) {
        int r = t / 23, c = t - 23 * r;
        out[t] = lg[r][c] - red[r][0] - red[r][1];
    }
}

// ---------------- launcher ----------------
extern "C" void kernel_launch(void* const* d_in, const int* in_sizes, int n_in,
                              void* d_out, int out_size, void* d_ws, size_t ws_size,
                              hipStream_t stream) {
    (void)in_sizes; (void)n_in; (void)out_size; (void)ws_size;
    const float* pos = (const float*)d_in[0];
    const float* W1  = (const float*)d_in[2];  const float* b1  = (const float*)d_in[3];
    const float* W2  = (const float*)d_in[4];  const float* b2  = (const float*)d_in[5];
    const float* W3  = (const float*)d_in[6];  const float* b3  = (const float*)d_in[7];
    const float* Wf1 = (const float*)d_in[8];  const float* bf1 = (const float*)d_in[9];
    const float* Wa  = (const float*)d_in[10]; const float* ba  = (const float*)d_in[11];
    const float* ga  = (const float*)d_in[12]; const float* bea = (const float*)d_in[13];
    const float* Wb  = (const float*)d_in[14]; const float* bb  = (const float*)d_in[15];
    const float* gb  = (const float*)d_in[16]; const float* beb = (const float*)d_in[17];
    const float* Wc  = (const float*)d_in[18]; const float* bc  = (const float*)d_in[19];

    char* ws = (char*)d_ws;
    float*    n2   = (float*)(ws + OFF_N2);
    int*      idx  = (int*)(ws + OFF_IDX);
    unsigned* pool = (unsigned*)(ws + OFF_POOL);
    float*    C1   = (float*)(ws + OFF_C1);
    float*    C2   = (float*)(ws + OFF_C2);
    float*    x1   = (float*)(ws + OFF_X1);
    float*    x2   = (float*)(ws + OFF_X2);
    float*    x3   = (float*)(ws + OFF_X3);
    float*    UV   = (float*)(ws + OFF_UV);
    float*    P1   = (float*)(ws + OFF_P1);
    float*    P2   = (float*)(ws + OFF_P2);
    unsigned short* Xph  = (unsigned short*)(ws + OFF_XPH);
    unsigned short* Xpl  = (unsigned short*)(ws + OFF_XPL);
    unsigned short* Apkh = (unsigned short*)(ws + OFF_APKH);
    unsigned short* Apkl = (unsigned short*)(ws + OFF_APKL);
    unsigned short* Bth  = (unsigned short*)(ws + OFF_BTH);
    unsigned short* Btl  = (unsigned short*)(ws + OFF_BTL);
    unsigned short* Wt1h = (unsigned short*)(ws + OFF_WT1H);
    unsigned short* Wt1l = (unsigned short*)(ws + OFF_WT1L);
    unsigned short* Wt2h = (unsigned short*)(ws + OFF_WT2H);
    unsigned short* Wt2l = (unsigned short*)(ws + OFF_WT2L);
    unsigned short* Wt3h = (unsigned short*)(ws + OFF_WT3H);
    unsigned short* Wt3l = (unsigned short*)(ws + OFF_WT3L);

    // prep
    init_pool_kernel<<<32, 256, 0, stream>>>(pool);
    packWt_kernel<<<16,  256, 0, stream>>>(W1, Wt1h, Wt1l, 3,   32,  64);
    packWt_kernel<<<64,  256, 0, stream>>>(W2, Wt2h, Wt2l, 64,  64,  128);
    packWt_kernel<<<256, 256, 0, stream>>>(W3, Wt3h, Wt3l, 128, 128, 256);

    // edge conv 1 (d=3 padded to 32)
    packX0_kernel<<<64, 256, 0, stream>>>(pos, Xph, Xpl, n2);
    knn_fused_kernel<32><<<512, 256, 0, stream>>>(Xph, Xpl, n2, idx);
    gemm_uv_mfma<32><<<dim3(128, 1), 256, 0, stream>>>(Xph, Xpl, Wt1h, Wt1l, UV, 128);
    agg_kernel<<<NPTS, 64, 0, stream>>>(UV, idx, b1, x1, 64);

    // edge conv 2 (64 -> 128)
    sqnorm_kernel<64><<<64, 256, 0, stream>>>(x1, n2);
    packX_kernel<<<1024, 256, 0, stream>>>(x1, Xph, Xpl);
    knn_fused_kernel<64><<<512, 256, 0, stream>>>(Xph, Xpl, n2, idx);
    gemm_uv_mfma<64><<<dim3(128, 2), 256, 0, stream>>>(Xph, Xpl, Wt2h, Wt2l, UV, 256);
    agg_kernel<<<NPTS, 128, 0, stream>>>(UV, idx, b2, x2, 128);

    // edge conv 3 (128 -> 256)
    sqnorm_kernel<128><<<64, 256, 0, stream>>>(x2, n2);
    packX_kernel<<<2048, 256, 0, stream>>>(x2, Xph, Xpl);
    knn_fused_kernel<128><<<512, 256, 0, stream>>>(Xph, Xpl, n2, idx);
    gemm_uv_mfma<128><<<dim3(128, 4), 256, 0, stream>>>(Xph, Xpl, Wt3h, Wt3l, UV, 512);
    agg_kernel<<<NPTS, 256, 0, stream>>>(UV, idx, b3, x3, 256);

    // fc1 (MFMA) + fused max pool
    packA_kernel<<<7168, 256, 0, stream>>>(x1, x2, x3, Apkh, Apkl);
    packB_kernel<<<448,  256, 0, stream>>>(Wf1, Bth, Btl);
    gemm_fc1_mfma<<<dim3(128, 8), 256, 0, stream>>>(Apkh, Apkl, Bth, Btl, bf1, pool);

    // head: split-k GEMM + BN
    head_gemm_k<1024, 512, 8, true ><<<dim3(8, 8), 256, 0, stream>>>((const float*)pool, Wa, P1);
    head_bn2<512, 8><<<2, 256, 0, stream>>>(P1, ba, ga, bea, C1);
    head_gemm_k<512, 256, 4, false><<<dim3(4, 4), 256, 0, stream>>>(C1, Wb, P2);
    head_bn2<256, 4><<<1, 256, 0, stream>>>(P2, bb, gb, beb, C2);
    head3_kernel<<<1, 256, 0, stream>>>(C2, Wc, bc, (float*)d_out);
}